// Round 10
// baseline (724.613 us; speedup 1.0000x reference)
//
#include <hip/hip_runtime.h>
#include <hip/hip_bf16.h>

typedef __attribute__((ext_vector_type(8))) short short8;
typedef __attribute__((ext_vector_type(4))) float f32x4;
typedef unsigned short ushort_t;

static constexpr int Bc = 2, Sc = 2048, HIDc = 4096, Hc = 32;
static constexpr int NOPEc = 128, ROPEc = 64, VDc = 128, QHDc = 192;
static constexpr int QLRc = 1536, KVLRc = 512;
static constexpr int CKVS = 640;   // padded ckv row stride (576 -> 640)

#define CDIV(a,b) (((a)+(b)-1)/(b))

__device__ __forceinline__ float bf2f(ushort_t u){
  union { unsigned u32; float f; } x; x.u32 = ((unsigned)u) << 16; return x.f;
}
__device__ __forceinline__ ushort_t f2bf(float f){
  union { float f; unsigned u32; } x; x.f = f;
  unsigned r = x.u32 + 0x7FFFu + ((x.u32 >> 16) & 1u);
  return (ushort_t)(r >> 16);
}
__device__ __forceinline__ void gload16(const void* g, void* l){
  __builtin_amdgcn_global_load_lds((const __attribute__((address_space(1))) void*)g,
                                   (__attribute__((address_space(3))) void*)l, 16, 0, 0);
}

// ---------------- f32 -> bf16 convert (vectorized, grid-stride) ----------------
__global__ __launch_bounds__(256)
void f32_to_bf16(const float* __restrict__ in, ushort_t* __restrict__ out, long long n){
  long long stride = (long long)gridDim.x * 256 * 4;
  for (long long i = ((long long)blockIdx.x*256 + threadIdx.x)*4; i < n; i += stride){
    float4 v = *(const float4*)(in + i);
    unsigned long long pk = (unsigned long long)f2bf(v.x)
                          | ((unsigned long long)f2bf(v.y) << 16)
                          | ((unsigned long long)f2bf(v.z) << 32)
                          | ((unsigned long long)f2bf(v.w) << 48);
    *(unsigned long long*)(out + i) = pk;
  }
}

// ---------------- batched 5-segment f32->bf16 (hidden + 4 weights) ----------------
__global__ __launch_bounds__(256)
void conv_all(const float* __restrict__ s0, const float* __restrict__ s1,
              const float* __restrict__ s2, const float* __restrict__ s3,
              const float* __restrict__ s4,
              ushort_t* __restrict__ d0, ushort_t* __restrict__ d1,
              ushort_t* __restrict__ d2, ushort_t* __restrict__ d3,
              ushort_t* __restrict__ d4){
  constexpr long long C0 = 16777216, C1 = 23068672, C2 = 32505856, C3 = 34865152, C4 = 39059456;
  long long stride = (long long)gridDim.x * 256 * 4;
  for (long long e = ((long long)blockIdx.x*256 + threadIdx.x)*4; e < C4; e += stride){
    const float* sp; ushort_t* dp; long long o;
    if      (e < C0){ sp = s0; dp = d0; o = e; }
    else if (e < C1){ sp = s1; dp = d1; o = e - C0; }
    else if (e < C2){ sp = s2; dp = d2; o = e - C1; }
    else if (e < C3){ sp = s3; dp = d3; o = e - C2; }
    else            { sp = s4; dp = d4; o = e - C3; }
    float4 v = *(const float4*)(sp + o);
    unsigned long long pk = (unsigned long long)f2bf(v.x)
                          | ((unsigned long long)f2bf(v.y) << 16)
                          | ((unsigned long long)f2bf(v.z) << 32)
                          | ((unsigned long long)f2bf(v.w) << 48);
    *(unsigned long long*)(dp + o) = pk;
  }
}

// ======== GEMM 256x256 tile, BK=64, 8 waves, dbuf LDS, swizzled, counted vmcnt ======
template<bool OUTBF>
__global__ __launch_bounds__(512, 2)
void gemm256(const ushort_t* __restrict__ A, const ushort_t* __restrict__ Bw,
             void* __restrict__ Cp, int M, int N, int K, int lda)
{
  __shared__ __attribute__((aligned(16))) ushort_t sm[65536];
  const int tid = threadIdx.x, lane = tid & 63, w = tid >> 6;
  const int wr = w >> 2, wc = w & 3;
  const int fr = lane & 15, kq = lane >> 4;

  const int nwg = gridDim.x, nx = N >> 8;
  const int bid = blockIdx.x;
  const int swz = (bid & 7) * (nwg >> 3) + (bid >> 3);
  const int m0 = (swz / nx) << 8, n0 = (swz % nx) << 8;

  f32x4 acc[8][4];
  #pragma unroll
  for (int m=0;m<8;m++)
    #pragma unroll
    for (int n=0;n<4;n++) acc[m][n] = (f32x4){0.f,0.f,0.f,0.f};

  const int srow = tid >> 3;
  const int gch  = (tid & 7) ^ (srow & 7);

  auto stage = [&](int c, int kt){
    const int k0 = kt << 6;
    ushort_t* Al = sm + c*16384;
    ushort_t* Bl = sm + 32768 + c*16384;
    const ushort_t* Ag = A  + (size_t)(m0 + srow)*lda + k0 + gch*8;
    const ushort_t* Bg = Bw + (size_t)(n0 + srow)*K   + k0 + gch*8;
    #pragma unroll
    for (int i=0;i<4;i++) gload16(Ag + (size_t)(i*64)*lda, Al + i*4096 + tid*8);
    #pragma unroll
    for (int i=0;i<4;i++) gload16(Bg + (size_t)(i*64)*K,   Bl + i*4096 + tid*8);
  };

  auto compute = [&](int c){
    const ushort_t* Al = sm + c*16384;
    const ushort_t* Bl = sm + 32768 + c*16384;
    const int s = fr & 7;
    short8 bfr[4][2];
    #pragma unroll
    for (int n=0;n<4;n++){
      const int row = wc*64 + n*16 + fr;
      bfr[n][0] = *(const short8*)(Bl + row*64 + ((kq    ) ^ s)*8);
      bfr[n][1] = *(const short8*)(Bl + row*64 + ((kq + 4) ^ s)*8);
    }
    #pragma unroll
    for (int m=0;m<8;m++){
      const int row = wr*128 + m*16 + fr;
      short8 a0 = *(const short8*)(Al + row*64 + ((kq    ) ^ s)*8);
      short8 a1 = *(const short8*)(Al + row*64 + ((kq + 4) ^ s)*8);
      #pragma unroll
      for (int n=0;n<4;n++){
        acc[m][n] = __builtin_amdgcn_mfma_f32_16x16x32_bf16(a0, bfr[n][0], acc[m][n], 0,0,0);
        acc[m][n] = __builtin_amdgcn_mfma_f32_16x16x32_bf16(a1, bfr[n][1], acc[m][n], 0,0,0);
      }
    }
  };

  const int nkt = K >> 6;
  stage(0, 0);
  stage(1, 1);
  asm volatile("s_waitcnt vmcnt(8)" ::: "memory");
  __builtin_amdgcn_s_barrier();
  __builtin_amdgcn_sched_barrier(0);

  int cur = 0;
  for (int kt = 0; kt < nkt; ++kt){
    compute(cur);
    __builtin_amdgcn_s_barrier();
    __builtin_amdgcn_sched_barrier(0);
    if (kt + 2 < nkt){
      stage(cur, kt + 2);
      asm volatile("s_waitcnt vmcnt(8)" ::: "memory");
    } else {
      asm volatile("s_waitcnt vmcnt(0)" ::: "memory");
    }
    __builtin_amdgcn_s_barrier();
    __builtin_amdgcn_sched_barrier(0);
    cur ^= 1;
  }

  const int rb = m0 + wr*128 + kq*4;
  const int cb = n0 + wc*64 + fr;
  #pragma unroll
  for (int m=0;m<8;m++)
    #pragma unroll
    for (int n=0;n<4;n++){
      const int col = cb + n*16;
      #pragma unroll
      for (int j=0;j<4;j++){
        const int row = rb + m*16 + j;
        float v = acc[m][n][j];
        if (OUTBF) ((ushort_t*)Cp)[(size_t)row*N + col] = f2bf(v);
        else       ((float*)  Cp)[(size_t)row*N + col] = v;
      }
    }
}

// ======== GEMM 256x128 tile, BK=64, 8 waves (4Mx2N), dbuf, counted vmcnt ======
template<bool OUTBF>
__global__ __launch_bounds__(512, 2)
void gemm256x128(const ushort_t* __restrict__ A, const ushort_t* __restrict__ Bw,
                 void* __restrict__ Cp, int M, int N, int K, int lda)
{
  __shared__ __attribute__((aligned(16))) ushort_t sm[49152];
  const int tid = threadIdx.x, lane = tid & 63, w = tid >> 6;
  const int wr = w >> 1, wc = w & 1;
  const int fr = lane & 15, kq = lane >> 4;

  const int nwg = gridDim.x, nx = N >> 7;
  const int bid = blockIdx.x;
  const int swz = (bid & 7) * (nwg >> 3) + (bid >> 3);
  const int m0 = (swz / nx) << 8, n0 = (swz % nx) << 7;

  f32x4 acc[4][4];
  #pragma unroll
  for (int m=0;m<4;m++)
    #pragma unroll
    for (int n=0;n<4;n++) acc[m][n] = (f32x4){0.f,0.f,0.f,0.f};

  const int srow = tid >> 3;
  const int gch  = (tid & 7) ^ (srow & 7);

  auto stage = [&](int c, int kt){
    const int k0 = kt << 6;
    ushort_t* Al = sm + c*16384;
    ushort_t* Bl = sm + 32768 + c*8192;
    const ushort_t* Ag = A  + (size_t)(m0 + srow)*lda + k0 + gch*8;
    const ushort_t* Bg = Bw + (size_t)(n0 + srow)*K   + k0 + gch*8;
    #pragma unroll
    for (int i=0;i<4;i++) gload16(Ag + (size_t)(i*64)*lda, Al + i*4096 + tid*8);
    #pragma unroll
    for (int i=0;i<2;i++) gload16(Bg + (size_t)(i*64)*K,   Bl + i*4096 + tid*8);
  };

  auto compute = [&](int c){
    const ushort_t* Al = sm + c*16384;
    const ushort_t* Bl = sm + 32768 + c*8192;
    const int s = fr & 7;
    short8 bfr[4][2];
    #pragma unroll
    for (int n=0;n<4;n++){
      const int row = wc*64 + n*16 + fr;
      bfr[n][0] = *(const short8*)(Bl + row*64 + ((kq    ) ^ s)*8);
      bfr[n][1] = *(const short8*)(Bl + row*64 + ((kq + 4) ^ s)*8);
    }
    #pragma unroll
    for (int m=0;m<4;m++){
      const int row = wr*64 + m*16 + fr;
      short8 a0 = *(const short8*)(Al + row*64 + ((kq    ) ^ s)*8);
      short8 a1 = *(const short8*)(Al + row*64 + ((kq + 4) ^ s)*8);
      #pragma unroll
      for (int n=0;n<4;n++){
        acc[m][n] = __builtin_amdgcn_mfma_f32_16x16x32_bf16(a0, bfr[n][0], acc[m][n], 0,0,0);
        acc[m][n] = __builtin_amdgcn_mfma_f32_16x16x32_bf16(a1, bfr[n][1], acc[m][n], 0,0,0);
      }
    }
  };

  const int nkt = K >> 6;
  stage(0, 0);
  stage(1, 1);
  asm volatile("s_waitcnt vmcnt(6)" ::: "memory");
  __builtin_amdgcn_s_barrier();
  __builtin_amdgcn_sched_barrier(0);

  int cur = 0;
  for (int kt = 0; kt < nkt; ++kt){
    compute(cur);
    __builtin_amdgcn_s_barrier();
    __builtin_amdgcn_sched_barrier(0);
    if (kt + 2 < nkt){
      stage(cur, kt + 2);
      asm volatile("s_waitcnt vmcnt(6)" ::: "memory");
    } else {
      asm volatile("s_waitcnt vmcnt(0)" ::: "memory");
    }
    __builtin_amdgcn_s_barrier();
    __builtin_amdgcn_sched_barrier(0);
    cur ^= 1;
  }

  const int rb = m0 + wr*64 + kq*4;
  const int cb = n0 + wc*64 + fr;
  #pragma unroll
  for (int m=0;m<4;m++)
    #pragma unroll
    for (int n=0;n<4;n++){
      const int col = cb + n*16;
      #pragma unroll
      for (int j=0;j<4;j++){
        const int row = rb + m*16 + j;
        float v = acc[m][n][j];
        if (OUTBF) ((ushort_t*)Cp)[(size_t)row*N + col] = f2bf(v);
        else       ((float*)  Cp)[(size_t)row*N + col] = v;
      }
    }
}

// ---------------- merged RMSNorm (qa rows then ckv rows) ----------------
__global__ __launch_bounds__(256)
void rmsnorm2(ushort_t* __restrict__ xa, const float* __restrict__ wa,
              ushort_t* __restrict__ xb, const float* __restrict__ wb){
  const int row = blockIdx.x;
  ushort_t* p; const float* w; int D;
  if (row < Bc*Sc){ p = xa + (size_t)row*QLRc; w = wa; D = QLRc; }
  else            { p = xb + (size_t)(row - Bc*Sc)*CKVS; w = wb; D = KVLRc; }
  float ss = 0.f;
  for (int c = threadIdx.x*8; c < D; c += 2048) {
    short8 v = *(const short8*)(p + c);
    #pragma unroll
    for (int j=0;j<8;j++){ float f = bf2f((ushort_t)v[j]); ss += f*f; }
  }
  #pragma unroll
  for (int m=1;m<64;m<<=1) ss += __shfl_xor(ss, m, 64);
  __shared__ float red[4];
  if ((threadIdx.x & 63)==0) red[threadIdx.x>>6] = ss;
  __syncthreads();
  float tot = red[0]+red[1]+red[2]+red[3];
  float inv = rsqrtf(tot/(float)D + 1e-6f);
  for (int c = threadIdx.x*8; c < D; c += 2048) {
    short8 v = *(const short8*)(p + c);
    short8 o;
    #pragma unroll
    for (int j=0;j<8;j++) o[j] = (short)f2bf(bf2f((ushort_t)v[j]) * inv * w[c+j]);
    *(short8*)(p + c) = o;
  }
}

// ---------------- RoPE tables ----------------
__global__ void rope_tab(float* __restrict__ ct, float* __restrict__ st){
  int i = blockIdx.x*256 + threadIdx.x;
  if (i >= Sc*32) return;
  int t = i >> 5, p = i & 31;
  float invf = exp2f(-(float)p * (13.287712379549449f / 32.f));
  float ang = (float)t * invf;
  ct[i] = cosf(ang);
  st[i] = sinf(ang);
}

// ---------------- merged RoPE for q and k ----------------
__global__ void rope_qk(ushort_t* __restrict__ q, ushort_t* __restrict__ ckv,
                        const float* __restrict__ ct, const float* __restrict__ st){
  const int NQ = Bc*Sc*Hc*32;
  int i = blockIdx.x*256 + threadIdx.x;
  if (i < NQ) {
    int p = i & 31, h = (i >> 5) & (Hc-1);
    int bs = i >> 10;
    int t = bs & (Sc-1);
    ushort_t* base = q + (size_t)bs*Hc*QHDc + h*QHDc + NOPEc + 2*p;
    unsigned u = *(const unsigned*)base;
    float a = bf2f((ushort_t)(u & 0xFFFFu)), bb = bf2f((ushort_t)(u >> 16));
    float c = ct[t*32+p], s = st[t*32+p];
    unsigned o = (unsigned)f2bf(a*c - bb*s) | ((unsigned)f2bf(bb*c + a*s) << 16);
    *(unsigned*)base = o;
  } else {
    int k = i - NQ;
    if (k >= Bc*Sc*32) return;
    int p = k & 31;
    int bs = k >> 5;
    int t = bs & (Sc-1);
    ushort_t* base = ckv + (size_t)bs*CKVS + 512 + 2*p;
    unsigned u = *(const unsigned*)base;
    float a = bf2f((ushort_t)(u & 0xFFFFu)), bb = bf2f((ushort_t)(u >> 16));
    float c = ct[t*32+p], s = st[t*32+p];
    unsigned o = (unsigned)f2bf(a*c - bb*s) | ((unsigned)f2bf(bb*c + a*s) << 16);
    *(unsigned*)base = o;
  }
}

// ---------------- V transpose: kv[bs][h][256](+128) -> vt[bh][vd][s] ----------------
__global__ __launch_bounds__(256)
void vtrans(const ushort_t* __restrict__ kv, ushort_t* __restrict__ vt){
  const int s0 = blockIdx.x * 64;
  const int bh = blockIdx.y;
  const int batch = bh >> 5, h = bh & 31;
  __shared__ __attribute__((aligned(16))) ushort_t L[64][136];
  #pragma unroll
  for (int i = 0; i < 4; i++) {
    int chunk = i*256 + threadIdx.x;
    int r = chunk >> 4;
    int c = (chunk & 15) * 8;
    short8 v = *(const short8*)(kv + ((size_t)(batch*Sc + s0 + r)*Hc + h)*256 + 128 + c);
    *(short8*)&L[r][c] = v;
  }
  __syncthreads();
  #pragma unroll
  for (int i = 0; i < 4; i++) {
    int chunk = i*256 + threadIdx.x;
    int vd = chunk >> 3;
    int sc2 = (chunk & 7) * 8;
    short8 o;
    #pragma unroll
    for (int j=0;j<8;j++) o[j] = (short)L[sc2+j][vd];
    *(short8*)(vt + ((size_t)bh*VDc + vd)*Sc + s0 + sc2) = o;
  }
}

// ---------------- Flash attention (causal), 2 waves x 32 q-rows ----------------
// Same grid (64 bh x 16), diagonal pairing {31-y, y}, KVBLK=32, reg-staged
// prefetch — identical memory streams to the proven 211us kernel. Change: each
// wave owns 32 q rows as TWO 16-row fragment groups sharing every K/V B-fragment
// LDS read -> ~2x less LDS port traffic per unit of work. Block = 128 threads.
__global__ __launch_bounds__(128)
void attn_fwd(const ushort_t* __restrict__ qb, const ushort_t* __restrict__ kvb,
              const ushort_t* __restrict__ ckv, const ushort_t* __restrict__ vt,
              ushort_t* __restrict__ out)
{
  constexpr int KP = 200, VP = 40;   // padded strides: 2-way-bank-conflict only
  __shared__ __attribute__((aligned(16))) ushort_t Ks[32*KP];     // 12.5 KB
  __shared__ __attribute__((aligned(16))) ushort_t Vs[128*VP];    // 10 KB
  __shared__ __attribute__((aligned(16))) ushort_t Ps[2][32*VP];  // 5 KB
  const int tid = threadIdx.x, lane = tid & 63, w = tid >> 6;     // w in {0,1}
  const int fr = lane & 15, kq = lane >> 4;
  const int y = (int)blockIdx.y;                      // 0..15
  const int bh = blockIdx.x, batch = bh >> 5, h = bh & 31;

  const float scl = 0.07216878364870323f * 1.4426950408889634f; // 192^-0.5 * log2(e)
  const float THR = 8.0f;

  const int ksr = tid >> 2, ksub = tid & 3;   // K staging: 32 rows x 4 subs x 6 chunks
  const int vvd = tid;                        // V staging: 128 rows x 4 chunks/thread

  const ushort_t* kbase  = kvb + ((size_t)batch*Sc + ksr)*((size_t)Hc*256) + (size_t)h*256;
  const ushort_t* pebase = ckv + (size_t)(batch*Sc + ksr)*CKVS + 512;
  const ushort_t* vbase  = vt + ((size_t)bh*VDc + vvd)*Sc;

  for (int seg = 0; seg < 2; ++seg) {
    const int qt = seg == 0 ? (31 - y) : y;           // heavy tile first
    const int q0 = qt * 64;
    const int wq0 = q0 + w*32;                        // this wave's 32 rows

    // Q fragments: two 16-row groups
    const ushort_t* qp0 = qb + ((size_t)(batch*Sc + wq0 + fr)*Hc + h)*QHDc;
    const ushort_t* qp1 = qb + ((size_t)(batch*Sc + wq0 + 16 + fr)*Hc + h)*QHDc;
    short8 qf0[6], qf1[6];
    #pragma unroll
    for (int kk=0;kk<6;kk++){
      qf0[kk] = *(const short8*)(qp0 + kk*32 + kq*8);
      qf1[kk] = *(const short8*)(qp1 + kk*32 + kq*8);
    }

    f32x4 acc0[8], acc1[8];
    #pragma unroll
    for (int i=0;i<8;i++){ acc0[i] = (f32x4){0.f,0.f,0.f,0.f}; acc1[i] = (f32x4){0.f,0.f,0.f,0.f}; }
    float mr0[4], mr1[4], lp0[4], lp1[4];
    #pragma unroll
    for (int j=0;j<4;j++){ mr0[j]=-3e38f; mr1[j]=-3e38f; lp0[j]=0.f; lp1[j]=0.f; }

    const int ktiles = q0/32 + 2;

    short8 kreg[6], vreg[4];
    {
      #pragma unroll
      for (int i=0;i<6;i++){
        int c = (ksub*6 + i)*8;
        kreg[i] = (c < 128) ? *(const short8*)(kbase + c)
                            : *(const short8*)(pebase + (c - 128));
      }
      #pragma unroll
      for (int i=0;i<4;i++) vreg[i] = *(const short8*)(vbase + i*8);
    }

    for (int kt = 0; kt < ktiles; kt++) {
      const int j0 = kt*32;
      #pragma unroll
      for (int i=0;i<6;i++) *(short8*)&Ks[ksr*KP + (ksub*6 + i)*8] = kreg[i];
      #pragma unroll
      for (int i=0;i<4;i++) *(short8*)&Vs[vvd*VP + i*8] = vreg[i];
      __syncthreads();

      if (kt + 1 < ktiles) {
        const size_t roff = (size_t)(j0 + 32);
        #pragma unroll
        for (int i=0;i<6;i++){
          int c = (ksub*6 + i)*8;
          kreg[i] = (c < 128) ? *(const short8*)(kbase + roff*((size_t)Hc*256) + c)
                              : *(const short8*)(pebase + roff*CKVS + (c - 128));
        }
        #pragma unroll
        for (int i=0;i<4;i++) vreg[i] = *(const short8*)(vbase + roff + i*8);
      }

      if (j0 <= wq0 + 31) {          // wave-uniform: skip fully-masked tile
        // QK^T: both row-groups share each K B-fragment read
        f32x4 s00 = (f32x4){0.f,0.f,0.f,0.f}, s01 = s00, s10 = s00, s11 = s00;
        __builtin_amdgcn_s_setprio(1);
        #pragma unroll
        for (int kk=0;kk<6;kk++){
          short8 b0 = *(const short8*)&Ks[fr*KP + kk*32 + kq*8];
          short8 b1 = *(const short8*)&Ks[(16+fr)*KP + kk*32 + kq*8];
          s00 = __builtin_amdgcn_mfma_f32_16x16x32_bf16(qf0[kk], b0, s00, 0,0,0);
          s01 = __builtin_amdgcn_mfma_f32_16x16x32_bf16(qf0[kk], b1, s01, 0,0,0);
          s10 = __builtin_amdgcn_mfma_f32_16x16x32_bf16(qf1[kk], b0, s10, 0,0,0);
          s11 = __builtin_amdgcn_mfma_f32_16x16x32_bf16(qf1[kk], b1, s11, 0,0,0);
        }
        __builtin_amdgcn_s_setprio(0);

        const bool full0 = (j0 + 31 <= wq0);
        const bool full1 = (j0 + 31 <= wq0 + 16);
        float x00[4], x01[4], x10[4], x11[4];
        int okl = 1;
        #pragma unroll
        for (int j=0;j<4;j++){
          float a0 = s00[j]*scl, c0 = s01[j]*scl;
          float a1 = s10[j]*scl, c1 = s11[j]*scl;
          if (!full0) {
            int qp = wq0 + kq*4 + j;
            if (j0 + fr      > qp) a0 = -3e38f;
            if (j0 + 16 + fr > qp) c0 = -3e38f;
          }
          if (!full1) {
            int qp = wq0 + 16 + kq*4 + j;
            if (j0 + fr      > qp) a1 = -3e38f;
            if (j0 + 16 + fr > qp) c1 = -3e38f;
          }
          x00[j]=a0; x01[j]=c0; x10[j]=a1; x11[j]=c1;
          okl &= (fmaxf(a0, c0) <= mr0[j] + THR) ? 1 : 0;
          okl &= (fmaxf(a1, c1) <= mr1[j] + THR) ? 1 : 0;
        }
        if (!__all(okl)) {
          float t0[4], t1[4];
          #pragma unroll
          for (int j=0;j<4;j++){ t0[j] = fmaxf(x00[j], x01[j]); t1[j] = fmaxf(x10[j], x11[j]); }
          #pragma unroll
          for (int m=1;m<16;m<<=1){
            #pragma unroll
            for (int j=0;j<4;j++){
              t0[j] = fmaxf(t0[j], __shfl_xor(t0[j], m, 64));
              t1[j] = fmaxf(t1[j], __shfl_xor(t1[j], m, 64));
            }
          }
          #pragma unroll
          for (int j=0;j<4;j++){
            float mn0 = fmaxf(mr0[j], t0[j]);
            float co0 = exp2f(mr0[j] - mn0);
            mr0[j] = mn0; lp0[j] *= co0;
            float mn1 = fmaxf(mr1[j], t1[j]);
            float co1 = exp2f(mr1[j] - mn1);
            mr1[j] = mn1; lp1[j] *= co1;
            #pragma unroll
            for (int i=0;i<8;i++){ acc0[i][j] *= co0; acc1[i][j] *= co1; }
          }
        }
        #pragma unroll
        for (int j=0;j<4;j++){
          float p00 = exp2f(x00[j] - mr0[j]);
          float p01 = exp2f(x01[j] - mr0[j]);
          float p10 = exp2f(x10[j] - mr1[j]);
          float p11 = exp2f(x11[j] - mr1[j]);
          lp0[j] += p00 + p01;
          lp1[j] += p10 + p11;
          unsigned k0v, k1v;
          asm("v_cvt_pk_bf16_f32 %0, %1, %2" : "=v"(k0v) : "v"(p00), "v"(p01));
          asm("v_cvt_pk_bf16_f32 %0, %1, %2" : "=v"(k1v) : "v"(p10), "v"(p11));
          Ps[w][(kq*4+j)*VP + fr]           = (ushort_t)(k0v & 0xFFFFu);
          Ps[w][(kq*4+j)*VP + 16 + fr]      = (ushort_t)(k0v >> 16);
          Ps[w][(16 + kq*4+j)*VP + fr]      = (ushort_t)(k1v & 0xFFFFu);
          Ps[w][(16 + kq*4+j)*VP + 16 + fr] = (ushort_t)(k1v >> 16);
        }
        short8 ap0 = *(const short8*)&Ps[w][fr*VP + kq*8];
        short8 ap1 = *(const short8*)&Ps[w][(16+fr)*VP + kq*8];
        __builtin_amdgcn_s_setprio(1);
        #pragma unroll
        for (int v8=0; v8<8; v8++){
          short8 bv = *(const short8*)&Vs[(v8*16 + fr)*VP + kq*8];
          acc0[v8] = __builtin_amdgcn_mfma_f32_16x16x32_bf16(ap0, bv, acc0[v8], 0,0,0);
          acc1[v8] = __builtin_amdgcn_mfma_f32_16x16x32_bf16(ap1, bv, acc1[v8], 0,0,0);
        }
        __builtin_amdgcn_s_setprio(0);
      }
      __syncthreads();
    }

    #pragma unroll
    for (int m=1;m<16;m<<=1){
      #pragma unroll
      for (int j=0;j<4;j++){
        lp0[j] += __shfl_xor(lp0[j], m, 64);
        lp1[j] += __shfl_xor(lp1[j], m, 64);
      }
    }
    #pragma unroll
    for (int v8=0; v8<8; v8++){
      #pragma unroll
      for (int j=0;j<4;j++){
        int qg0 = wq0 + kq*4 + j;
        int qg1 = wq0 + 16 + kq*4 + j;
        out[(size_t)(batch*Sc + qg0)*(Hc*VDc) + h*VDc + v8*16 + fr] = f2bf(acc0[v8][j]/lp0[j]);
        out[(size_t)(batch*Sc + qg1)*(Hc*VDc) + h*VDc + v8*16 + fr] = f2bf(acc1[v8][j]/lp1[j]);
      }
    }
  }
}

// ---------------- launcher ----------------
extern "C" void kernel_launch(void* const* d_in, const int* in_sizes, int n_in,
                              void* d_out, int out_size, void* d_ws, size_t ws_size,
                              hipStream_t stream) {
  (void)in_sizes; (void)n_in; (void)out_size; (void)ws_size;
  const float* hidden  = (const float*)d_in[0];
  const float* q_a_w   = (const float*)d_in[3];
  const float* q_a_ln  = (const float*)d_in[4];
  const float* q_b_w   = (const float*)d_in[5];
  const float* kv_a_w  = (const float*)d_in[6];
  const float* kv_a_ln = (const float*)d_in[7];
  const float* kv_b_w  = (const float*)d_in[8];
  const float* o_w     = (const float*)d_in[9];
  float* outp = (float*)d_out;

  char* ws = (char*)d_ws;
  size_t off = 0;
  auto alloc = [&](size_t n)->char*{ char* p = ws + off; off += (n + 255) & ~(size_t)255; return p; };
  ushort_t* hbf  = (ushort_t*)alloc((size_t)Bc*Sc*HIDc*2);      // hidden bf16; later o_w bf16
  ushort_t* wqa  = (ushort_t*)alloc((size_t)QLRc*HIDc*2);       // later aliased as aout
  ushort_t* wqb  = (ushort_t*)alloc((size_t)Hc*QHDc*QLRc*2);
  ushort_t* wkva = (ushort_t*)alloc((size_t)640*HIDc*2);        // 640 rows (576 data + pad)
  ushort_t* wkvb = (ushort_t*)alloc((size_t)Hc*256*KVLRc*2);
  ushort_t* qa   = (ushort_t*)alloc((size_t)Bc*Sc*QLRc*2);
  ushort_t* qbf  = (ushort_t*)alloc((size_t)Bc*Sc*Hc*QHDc*2);
  ushort_t* ckv  = (ushort_t*)alloc((size_t)Bc*Sc*CKVS*2);      // stride 640
  ushort_t* kvbf = (ushort_t*)alloc((size_t)Bc*Sc*Hc*256*2);
  ushort_t* vtb  = (ushort_t*)alloc((size_t)Bc*Hc*VDc*Sc*2);    // V transposed [bh][vd][s]
  float*    ct   = (float*)alloc((size_t)Sc*32*4);
  float*    st   = (float*)alloc((size_t)Sc*32*4);
  ushort_t* aout = wqa;   // alias: wqa+wqb+wkva free before attn

  const int M = Bc*Sc; // 4096

  // one batched convert: hidden + q_a_w + q_b_w + kv_a_w + kv_b_w
  conv_all<<<2048,256,0,stream>>>(hidden, q_a_w, q_b_w, kv_a_w, kv_b_w,
                                  hbf, wqa, wqb, wkva, wkvb);
  // q_a = hidden @ q_a_w^T   [4096,1536,4096]
  gemm256x128<true><<<(M/256)*(QLRc/128),512,0,stream>>>(hbf, wqa, qa, M, QLRc, HIDc, HIDc);
  // ckv = hidden @ kv_a_w^T  (N padded to 640; cols 576..639 are garbage, never read)
  gemm256x128<true><<<(M/256)*(640/128),512,0,stream>>>(hbf, wkva, ckv, M, CKVS, HIDc, HIDc);
  // merged RMSNorm (qa + ckv)
  rmsnorm2<<<2*M,256,0,stream>>>(qa, q_a_ln, ckv, kv_a_ln);
  // hbf free now -> convert o_w into it
  f32_to_bf16<<<2048,256,0,stream>>>(o_w, hbf, (long long)HIDc*HIDc);
  // q = q_a @ q_b_w^T  [4096,6144,1536]
  gemm256x128<true><<<(M/256)*(Hc*QHDc/128),512,0,stream>>>(qa, wqb, qbf, M, Hc*QHDc, QLRc, QLRc);
  // kv = ckv_norm @ kv_b_w^T  [4096,8192,512], lda=640
  gemm256<true><<<(M/256)*(Hc*256/256),512,0,stream>>>(ckv, wkvb, kvbf, M, Hc*256, KVLRc, CKVS);
  // RoPE
  rope_tab<<<CDIV(Sc*32,256),256,0,stream>>>(ct, st);
  rope_qk<<<CDIV(Bc*Sc*Hc*32 + Bc*Sc*32,256),256,0,stream>>>(qbf, ckv, ct, st);
  // V transpose + attention (1024 uniform blocks, diagonal-paired, 128 threads)
  vtrans<<<dim3(Sc/64, Bc*Hc),256,0,stream>>>(kvbf, vtb);
  attn_fwd<<<dim3(Bc*Hc, 16),128,0,stream>>>(qbf, kvbf, ckv, vtb, aout);
  // out = attn @ o_w^T  [4096,4096,4096], f32 store
  gemm256<false><<<(M/256)*(HIDc/256),512,0,stream>>>(aout, hbf, outp, M, HIDc, HIDc, HIDc);
}

// Round 11
// 695.470 us; speedup vs baseline: 1.0419x; 1.0419x over previous
//
#include <hip/hip_runtime.h>
#include <hip/hip_bf16.h>

typedef __attribute__((ext_vector_type(8))) short short8;
typedef __attribute__((ext_vector_type(4))) float f32x4;
typedef unsigned short ushort_t;

static constexpr int Bc = 2, Sc = 2048, HIDc = 4096, Hc = 32;
static constexpr int NOPEc = 128, ROPEc = 64, VDc = 128, QHDc = 192;
static constexpr int QLRc = 1536, KVLRc = 512;
static constexpr int CKVS = 640;   // padded ckv row stride (576 -> 640)

#define CDIV(a,b) (((a)+(b)-1)/(b))

__device__ __forceinline__ float bf2f(ushort_t u){
  union { unsigned u32; float f; } x; x.u32 = ((unsigned)u) << 16; return x.f;
}
__device__ __forceinline__ ushort_t f2bf(float f){
  union { float f; unsigned u32; } x; x.f = f;
  unsigned r = x.u32 + 0x7FFFu + ((x.u32 >> 16) & 1u);
  return (ushort_t)(r >> 16);
}
__device__ __forceinline__ void gload16(const void* g, void* l){
  __builtin_amdgcn_global_load_lds((const __attribute__((address_space(1))) void*)g,
                                   (__attribute__((address_space(3))) void*)l, 16, 0, 0);
}

// ---------------- f32 -> bf16 convert (vectorized, grid-stride) ----------------
__global__ __launch_bounds__(256)
void f32_to_bf16(const float* __restrict__ in, ushort_t* __restrict__ out, long long n){
  long long stride = (long long)gridDim.x * 256 * 4;
  for (long long i = ((long long)blockIdx.x*256 + threadIdx.x)*4; i < n; i += stride){
    float4 v = *(const float4*)(in + i);
    unsigned long long pk = (unsigned long long)f2bf(v.x)
                          | ((unsigned long long)f2bf(v.y) << 16)
                          | ((unsigned long long)f2bf(v.z) << 32)
                          | ((unsigned long long)f2bf(v.w) << 48);
    *(unsigned long long*)(out + i) = pk;
  }
}

// ---------------- batched 5-segment f32->bf16 (hidden + 4 weights) ----------------
__global__ __launch_bounds__(256)
void conv_all(const float* __restrict__ s0, const float* __restrict__ s1,
              const float* __restrict__ s2, const float* __restrict__ s3,
              const float* __restrict__ s4,
              ushort_t* __restrict__ d0, ushort_t* __restrict__ d1,
              ushort_t* __restrict__ d2, ushort_t* __restrict__ d3,
              ushort_t* __restrict__ d4){
  constexpr long long C0 = 16777216, C1 = 23068672, C2 = 32505856, C3 = 34865152, C4 = 39059456;
  long long stride = (long long)gridDim.x * 256 * 4;
  for (long long e = ((long long)blockIdx.x*256 + threadIdx.x)*4; e < C4; e += stride){
    const float* sp; ushort_t* dp; long long o;
    if      (e < C0){ sp = s0; dp = d0; o = e; }
    else if (e < C1){ sp = s1; dp = d1; o = e - C0; }
    else if (e < C2){ sp = s2; dp = d2; o = e - C1; }
    else if (e < C3){ sp = s3; dp = d3; o = e - C2; }
    else            { sp = s4; dp = d4; o = e - C3; }
    float4 v = *(const float4*)(sp + o);
    unsigned long long pk = (unsigned long long)f2bf(v.x)
                          | ((unsigned long long)f2bf(v.y) << 16)
                          | ((unsigned long long)f2bf(v.z) << 32)
                          | ((unsigned long long)f2bf(v.w) << 48);
    *(unsigned long long*)(dp + o) = pk;
  }
}

// ======== GEMM 256x256 tile, BK=64, 8 waves, dbuf LDS, swizzled, counted vmcnt ======
template<bool OUTBF>
__global__ __launch_bounds__(512, 2)
void gemm256(const ushort_t* __restrict__ A, const ushort_t* __restrict__ Bw,
             void* __restrict__ Cp, int M, int N, int K, int lda)
{
  __shared__ __attribute__((aligned(16))) ushort_t sm[65536];
  const int tid = threadIdx.x, lane = tid & 63, w = tid >> 6;
  const int wr = w >> 2, wc = w & 3;
  const int fr = lane & 15, kq = lane >> 4;

  const int nwg = gridDim.x, nx = N >> 8;
  const int bid = blockIdx.x;
  const int swz = (bid & 7) * (nwg >> 3) + (bid >> 3);
  const int m0 = (swz / nx) << 8, n0 = (swz % nx) << 8;

  f32x4 acc[8][4];
  #pragma unroll
  for (int m=0;m<8;m++)
    #pragma unroll
    for (int n=0;n<4;n++) acc[m][n] = (f32x4){0.f,0.f,0.f,0.f};

  const int srow = tid >> 3;
  const int gch  = (tid & 7) ^ (srow & 7);

  auto stage = [&](int c, int kt){
    const int k0 = kt << 6;
    ushort_t* Al = sm + c*16384;
    ushort_t* Bl = sm + 32768 + c*16384;
    const ushort_t* Ag = A  + (size_t)(m0 + srow)*lda + k0 + gch*8;
    const ushort_t* Bg = Bw + (size_t)(n0 + srow)*K   + k0 + gch*8;
    #pragma unroll
    for (int i=0;i<4;i++) gload16(Ag + (size_t)(i*64)*lda, Al + i*4096 + tid*8);
    #pragma unroll
    for (int i=0;i<4;i++) gload16(Bg + (size_t)(i*64)*K,   Bl + i*4096 + tid*8);
  };

  auto compute = [&](int c){
    const ushort_t* Al = sm + c*16384;
    const ushort_t* Bl = sm + 32768 + c*16384;
    const int s = fr & 7;
    short8 bfr[4][2];
    #pragma unroll
    for (int n=0;n<4;n++){
      const int row = wc*64 + n*16 + fr;
      bfr[n][0] = *(const short8*)(Bl + row*64 + ((kq    ) ^ s)*8);
      bfr[n][1] = *(const short8*)(Bl + row*64 + ((kq + 4) ^ s)*8);
    }
    #pragma unroll
    for (int m=0;m<8;m++){
      const int row = wr*128 + m*16 + fr;
      short8 a0 = *(const short8*)(Al + row*64 + ((kq    ) ^ s)*8);
      short8 a1 = *(const short8*)(Al + row*64 + ((kq + 4) ^ s)*8);
      #pragma unroll
      for (int n=0;n<4;n++){
        acc[m][n] = __builtin_amdgcn_mfma_f32_16x16x32_bf16(a0, bfr[n][0], acc[m][n], 0,0,0);
        acc[m][n] = __builtin_amdgcn_mfma_f32_16x16x32_bf16(a1, bfr[n][1], acc[m][n], 0,0,0);
      }
    }
  };

  const int nkt = K >> 6;
  stage(0, 0);
  stage(1, 1);
  asm volatile("s_waitcnt vmcnt(8)" ::: "memory");
  __builtin_amdgcn_s_barrier();
  __builtin_amdgcn_sched_barrier(0);

  int cur = 0;
  for (int kt = 0; kt < nkt; ++kt){
    compute(cur);
    __builtin_amdgcn_s_barrier();
    __builtin_amdgcn_sched_barrier(0);
    if (kt + 2 < nkt){
      stage(cur, kt + 2);
      asm volatile("s_waitcnt vmcnt(8)" ::: "memory");
    } else {
      asm volatile("s_waitcnt vmcnt(0)" ::: "memory");
    }
    __builtin_amdgcn_s_barrier();
    __builtin_amdgcn_sched_barrier(0);
    cur ^= 1;
  }

  const int rb = m0 + wr*128 + kq*4;
  const int cb = n0 + wc*64 + fr;
  #pragma unroll
  for (int m=0;m<8;m++)
    #pragma unroll
    for (int n=0;n<4;n++){
      const int col = cb + n*16;
      #pragma unroll
      for (int j=0;j<4;j++){
        const int row = rb + m*16 + j;
        float v = acc[m][n][j];
        if (OUTBF) ((ushort_t*)Cp)[(size_t)row*N + col] = f2bf(v);
        else       ((float*)  Cp)[(size_t)row*N + col] = v;
      }
    }
}

// ======== GEMM 256x128 tile, BK=64, 8 waves (4Mx2N), dbuf, counted vmcnt ======
template<bool OUTBF>
__global__ __launch_bounds__(512, 2)
void gemm256x128(const ushort_t* __restrict__ A, const ushort_t* __restrict__ Bw,
                 void* __restrict__ Cp, int M, int N, int K, int lda)
{
  __shared__ __attribute__((aligned(16))) ushort_t sm[49152];
  const int tid = threadIdx.x, lane = tid & 63, w = tid >> 6;
  const int wr = w >> 1, wc = w & 1;
  const int fr = lane & 15, kq = lane >> 4;

  const int nwg = gridDim.x, nx = N >> 7;
  const int bid = blockIdx.x;
  const int swz = (bid & 7) * (nwg >> 3) + (bid >> 3);
  const int m0 = (swz / nx) << 8, n0 = (swz % nx) << 7;

  f32x4 acc[4][4];
  #pragma unroll
  for (int m=0;m<4;m++)
    #pragma unroll
    for (int n=0;n<4;n++) acc[m][n] = (f32x4){0.f,0.f,0.f,0.f};

  const int srow = tid >> 3;
  const int gch  = (tid & 7) ^ (srow & 7);

  auto stage = [&](int c, int kt){
    const int k0 = kt << 6;
    ushort_t* Al = sm + c*16384;
    ushort_t* Bl = sm + 32768 + c*8192;
    const ushort_t* Ag = A  + (size_t)(m0 + srow)*lda + k0 + gch*8;
    const ushort_t* Bg = Bw + (size_t)(n0 + srow)*K   + k0 + gch*8;
    #pragma unroll
    for (int i=0;i<4;i++) gload16(Ag + (size_t)(i*64)*lda, Al + i*4096 + tid*8);
    #pragma unroll
    for (int i=0;i<2;i++) gload16(Bg + (size_t)(i*64)*K,   Bl + i*4096 + tid*8);
  };

  auto compute = [&](int c){
    const ushort_t* Al = sm + c*16384;
    const ushort_t* Bl = sm + 32768 + c*8192;
    const int s = fr & 7;
    short8 bfr[4][2];
    #pragma unroll
    for (int n=0;n<4;n++){
      const int row = wc*64 + n*16 + fr;
      bfr[n][0] = *(const short8*)(Bl + row*64 + ((kq    ) ^ s)*8);
      bfr[n][1] = *(const short8*)(Bl + row*64 + ((kq + 4) ^ s)*8);
    }
    #pragma unroll
    for (int m=0;m<4;m++){
      const int row = wr*64 + m*16 + fr;
      short8 a0 = *(const short8*)(Al + row*64 + ((kq    ) ^ s)*8);
      short8 a1 = *(const short8*)(Al + row*64 + ((kq + 4) ^ s)*8);
      #pragma unroll
      for (int n=0;n<4;n++){
        acc[m][n] = __builtin_amdgcn_mfma_f32_16x16x32_bf16(a0, bfr[n][0], acc[m][n], 0,0,0);
        acc[m][n] = __builtin_amdgcn_mfma_f32_16x16x32_bf16(a1, bfr[n][1], acc[m][n], 0,0,0);
      }
    }
  };

  const int nkt = K >> 6;
  stage(0, 0);
  stage(1, 1);
  asm volatile("s_waitcnt vmcnt(6)" ::: "memory");
  __builtin_amdgcn_s_barrier();
  __builtin_amdgcn_sched_barrier(0);

  int cur = 0;
  for (int kt = 0; kt < nkt; ++kt){
    compute(cur);
    __builtin_amdgcn_s_barrier();
    __builtin_amdgcn_sched_barrier(0);
    if (kt + 2 < nkt){
      stage(cur, kt + 2);
      asm volatile("s_waitcnt vmcnt(6)" ::: "memory");
    } else {
      asm volatile("s_waitcnt vmcnt(0)" ::: "memory");
    }
    __builtin_amdgcn_s_barrier();
    __builtin_amdgcn_sched_barrier(0);
    cur ^= 1;
  }

  const int rb = m0 + wr*64 + kq*4;
  const int cb = n0 + wc*64 + fr;
  #pragma unroll
  for (int m=0;m<4;m++)
    #pragma unroll
    for (int n=0;n<4;n++){
      const int col = cb + n*16;
      #pragma unroll
      for (int j=0;j<4;j++){
        const int row = rb + m*16 + j;
        float v = acc[m][n][j];
        if (OUTBF) ((ushort_t*)Cp)[(size_t)row*N + col] = f2bf(v);
        else       ((float*)  Cp)[(size_t)row*N + col] = v;
      }
    }
}

// ---------------- merged RMSNorm (qa rows then ckv rows) ----------------
__global__ __launch_bounds__(256)
void rmsnorm2(ushort_t* __restrict__ xa, const float* __restrict__ wa,
              ushort_t* __restrict__ xb, const float* __restrict__ wb){
  const int row = blockIdx.x;
  ushort_t* p; const float* w; int D;
  if (row < Bc*Sc){ p = xa + (size_t)row*QLRc; w = wa; D = QLRc; }
  else            { p = xb + (size_t)(row - Bc*Sc)*CKVS; w = wb; D = KVLRc; }
  float ss = 0.f;
  for (int c = threadIdx.x*8; c < D; c += 2048) {
    short8 v = *(const short8*)(p + c);
    #pragma unroll
    for (int j=0;j<8;j++){ float f = bf2f((ushort_t)v[j]); ss += f*f; }
  }
  #pragma unroll
  for (int m=1;m<64;m<<=1) ss += __shfl_xor(ss, m, 64);
  __shared__ float red[4];
  if ((threadIdx.x & 63)==0) red[threadIdx.x>>6] = ss;
  __syncthreads();
  float tot = red[0]+red[1]+red[2]+red[3];
  float inv = rsqrtf(tot/(float)D + 1e-6f);
  for (int c = threadIdx.x*8; c < D; c += 2048) {
    short8 v = *(const short8*)(p + c);
    short8 o;
    #pragma unroll
    for (int j=0;j<8;j++) o[j] = (short)f2bf(bf2f((ushort_t)v[j]) * inv * w[c+j]);
    *(short8*)(p + c) = o;
  }
}

// ---------------- RoPE tables ----------------
__global__ void rope_tab(float* __restrict__ ct, float* __restrict__ st){
  int i = blockIdx.x*256 + threadIdx.x;
  if (i >= Sc*32) return;
  int t = i >> 5, p = i & 31;
  float invf = exp2f(-(float)p * (13.287712379549449f / 32.f));
  float ang = (float)t * invf;
  ct[i] = cosf(ang);
  st[i] = sinf(ang);
}

// ---------------- merged RoPE for q and k ----------------
__global__ void rope_qk(ushort_t* __restrict__ q, ushort_t* __restrict__ ckv,
                        const float* __restrict__ ct, const float* __restrict__ st){
  const int NQ = Bc*Sc*Hc*32;
  int i = blockIdx.x*256 + threadIdx.x;
  if (i < NQ) {
    int p = i & 31, h = (i >> 5) & (Hc-1);
    int bs = i >> 10;
    int t = bs & (Sc-1);
    ushort_t* base = q + (size_t)bs*Hc*QHDc + h*QHDc + NOPEc + 2*p;
    unsigned u = *(const unsigned*)base;
    float a = bf2f((ushort_t)(u & 0xFFFFu)), bb = bf2f((ushort_t)(u >> 16));
    float c = ct[t*32+p], s = st[t*32+p];
    unsigned o = (unsigned)f2bf(a*c - bb*s) | ((unsigned)f2bf(bb*c + a*s) << 16);
    *(unsigned*)base = o;
  } else {
    int k = i - NQ;
    if (k >= Bc*Sc*32) return;
    int p = k & 31;
    int bs = k >> 5;
    int t = bs & (Sc-1);
    ushort_t* base = ckv + (size_t)bs*CKVS + 512 + 2*p;
    unsigned u = *(const unsigned*)base;
    float a = bf2f((ushort_t)(u & 0xFFFFu)), bb = bf2f((ushort_t)(u >> 16));
    float c = ct[t*32+p], s = st[t*32+p];
    unsigned o = (unsigned)f2bf(a*c - bb*s) | ((unsigned)f2bf(bb*c + a*s) << 16);
    *(unsigned*)base = o;
  }
}

// ---------------- V transpose: kv[bs][h][256](+128) -> vt[bh][vd][s] ----------------
__global__ __launch_bounds__(256)
void vtrans(const ushort_t* __restrict__ kv, ushort_t* __restrict__ vt){
  const int s0 = blockIdx.x * 64;
  const int bh = blockIdx.y;
  const int batch = bh >> 5, h = bh & 31;
  __shared__ __attribute__((aligned(16))) ushort_t L[64][136];
  #pragma unroll
  for (int i = 0; i < 4; i++) {
    int chunk = i*256 + threadIdx.x;
    int r = chunk >> 4;
    int c = (chunk & 15) * 8;
    short8 v = *(const short8*)(kv + ((size_t)(batch*Sc + s0 + r)*Hc + h)*256 + 128 + c);
    *(short8*)&L[r][c] = v;
  }
  __syncthreads();
  #pragma unroll
  for (int i = 0; i < 4; i++) {
    int chunk = i*256 + threadIdx.x;
    int vd = chunk >> 3;
    int sc2 = (chunk & 7) * 8;
    short8 o;
    #pragma unroll
    for (int j=0;j<8;j++) o[j] = (short)L[sc2+j][vd];
    *(short8*)(vt + ((size_t)bh*VDc + vd)*Sc + s0 + sc2) = o;
  }
}

// ---------------- Flash attention (causal), 4 waves — PROVEN 211us version ----------
// Diagonal pairing: block (bh, y) processes q-tiles {31-y, y} sequentially ->
// every block does exactly 66 KV-tile iterations (perfect balance); same-bh blocks
// stream K/V in lockstep -> near-perfect L2 reuse (FETCH ~111MB). 1-deep reg-staged
// prefetch; attn is TLP-bound (R9: depth-2 null; R10: fewer-reads/fewer-waves hurt).
__global__ __launch_bounds__(256)
void attn_fwd(const ushort_t* __restrict__ qb, const ushort_t* __restrict__ kvb,
              const ushort_t* __restrict__ ckv, const ushort_t* __restrict__ vt,
              ushort_t* __restrict__ out)
{
  constexpr int KP = 200, VP = 40;   // padded strides: 2-way-bank-conflict only
  __shared__ __attribute__((aligned(16))) ushort_t Ks[32*KP];
  __shared__ __attribute__((aligned(16))) ushort_t Vs[128*VP];
  __shared__ __attribute__((aligned(16))) ushort_t Ps[4][16*VP];
  const int tid = threadIdx.x, lane = tid & 63, w = tid >> 6;
  const int fr = lane & 15, kq = lane >> 4;
  const int y = (int)blockIdx.y;                      // 0..15
  const int bh = blockIdx.x, batch = bh >> 5, h = bh & 31;

  const float scl = 0.07216878364870323f * 1.4426950408889634f; // 192^-0.5 * log2(e)
  const float THR = 8.0f;

  const int ksr = tid >> 3, ksub = tid & 7;   // K staging: 32 rows x 24 chunks
  const int vvd = tid >> 1, vsub = tid & 1;   // V staging: 128 rows x 4 chunks

  const ushort_t* kbase  = kvb + ((size_t)batch*Sc + ksr)*((size_t)Hc*256) + (size_t)h*256;
  const ushort_t* pebase = ckv + (size_t)(batch*Sc + ksr)*CKVS + 512;
  const ushort_t* vbase  = vt + ((size_t)bh*VDc + vvd)*Sc;

  for (int seg = 0; seg < 2; ++seg) {
    const int qt = seg == 0 ? (31 - y) : y;           // heavy tile first
    const int q0 = qt * 64;

    const int qrow = q0 + w*16 + fr;
    const ushort_t* qptr = qb + ((size_t)(batch*Sc + qrow)*Hc + h)*QHDc;
    short8 qf[6];
    #pragma unroll
    for (int kk=0;kk<6;kk++) qf[kk] = *(const short8*)(qptr + kk*32 + kq*8);

    f32x4 acc_o[8];
    #pragma unroll
    for (int i=0;i<8;i++) acc_o[i] = (f32x4){0.f,0.f,0.f,0.f};
    float mrow[4]  = {-3e38f,-3e38f,-3e38f,-3e38f};
    float lpart[4] = {0.f,0.f,0.f,0.f};

    const int ktiles = q0/32 + 2;

    short8 kreg[3], vreg[2];
    {
      #pragma unroll
      for (int i=0;i<3;i++){
        int c = (ksub*3 + i)*8;
        kreg[i] = (c < 128) ? *(const short8*)(kbase + c)
                            : *(const short8*)(pebase + (c - 128));
      }
      #pragma unroll
      for (int i=0;i<2;i++) vreg[i] = *(const short8*)(vbase + (vsub*2+i)*8);
    }

    for (int kt = 0; kt < ktiles; kt++) {
      const int j0 = kt*32;
      #pragma unroll
      for (int i=0;i<3;i++) *(short8*)&Ks[ksr*KP + (ksub*3 + i)*8] = kreg[i];
      #pragma unroll
      for (int i=0;i<2;i++) *(short8*)&Vs[vvd*VP + (vsub*2 + i)*8] = vreg[i];
      __syncthreads();

      if (kt + 1 < ktiles) {
        const size_t roff = (size_t)(j0 + 32);
        #pragma unroll
        for (int i=0;i<3;i++){
          int c = (ksub*3 + i)*8;
          kreg[i] = (c < 128) ? *(const short8*)(kbase + roff*((size_t)Hc*256) + c)
                              : *(const short8*)(pebase + roff*CKVS + (c - 128));
        }
        #pragma unroll
        for (int i=0;i<2;i++) vreg[i] = *(const short8*)(vbase + roff + (vsub*2+i)*8);
      }

      f32x4 s0 = (f32x4){0.f,0.f,0.f,0.f}, s1 = (f32x4){0.f,0.f,0.f,0.f};
      __builtin_amdgcn_s_setprio(1);
      #pragma unroll
      for (int kk=0;kk<6;kk++){
        short8 b0 = *(const short8*)&Ks[fr*KP + kk*32 + kq*8];
        short8 b1 = *(const short8*)&Ks[(16+fr)*KP + kk*32 + kq*8];
        s0 = __builtin_amdgcn_mfma_f32_16x16x32_bf16(qf[kk], b0, s0, 0,0,0);
        s1 = __builtin_amdgcn_mfma_f32_16x16x32_bf16(qf[kk], b1, s1, 0,0,0);
      }
      __builtin_amdgcn_s_setprio(0);

      const bool full = (j0 + 31 <= q0 + w*16);
      float x0[4], x1[4];
      int okl = 1;
      #pragma unroll
      for (int j=0;j<4;j++){
        float a  = s0[j]*scl, c2 = s1[j]*scl;
        if (!full) {
          int qp = q0 + w*16 + kq*4 + j;
          if (j0 + fr      > qp) a  = -3e38f;
          if (j0 + 16 + fr > qp) c2 = -3e38f;
        }
        x0[j] = a; x1[j] = c2;
        okl &= (fmaxf(a, c2) <= mrow[j] + THR) ? 1 : 0;
      }
      if (!__all(okl)) {
        float tmax[4];
        #pragma unroll
        for (int j=0;j<4;j++) tmax[j] = fmaxf(x0[j], x1[j]);
        #pragma unroll
        for (int m=1;m<16;m<<=1){
          #pragma unroll
          for (int j=0;j<4;j++) tmax[j] = fmaxf(tmax[j], __shfl_xor(tmax[j], m, 64));
        }
        #pragma unroll
        for (int j=0;j<4;j++){
          float mn = fmaxf(mrow[j], tmax[j]);
          float corr = exp2f(mrow[j] - mn);
          mrow[j] = mn;
          lpart[j] *= corr;
          #pragma unroll
          for (int i=0;i<8;i++) acc_o[i][j] *= corr;
        }
      }
      float p0[4], p1[4];
      #pragma unroll
      for (int j=0;j<4;j++){
        p0[j] = exp2f(x0[j] - mrow[j]);
        p1[j] = exp2f(x1[j] - mrow[j]);
        lpart[j] += p0[j] + p1[j];
      }
      #pragma unroll
      for (int j=0;j<4;j++){
        unsigned pk;
        asm("v_cvt_pk_bf16_f32 %0, %1, %2" : "=v"(pk) : "v"(p0[j]), "v"(p1[j]));
        Ps[w][(kq*4+j)*VP + fr]      = (ushort_t)(pk & 0xFFFFu);
        Ps[w][(kq*4+j)*VP + 16 + fr] = (ushort_t)(pk >> 16);
      }
      short8 ap = *(const short8*)&Ps[w][fr*VP + kq*8];
      __builtin_amdgcn_s_setprio(1);
      #pragma unroll
      for (int v8=0; v8<8; v8++){
        short8 bv = *(const short8*)&Vs[(v8*16 + fr)*VP + kq*8];
        acc_o[v8] = __builtin_amdgcn_mfma_f32_16x16x32_bf16(ap, bv, acc_o[v8], 0,0,0);
      }
      __builtin_amdgcn_s_setprio(0);
      __syncthreads();
    }

    #pragma unroll
    for (int m=1;m<16;m<<=1){
      #pragma unroll
      for (int j=0;j<4;j++) lpart[j] += __shfl_xor(lpart[j], m, 64);
    }
    #pragma unroll
    for (int v8=0; v8<8; v8++){
      #pragma unroll
      for (int j=0;j<4;j++){
        int qg = q0 + w*16 + kq*4 + j;
        float o = acc_o[v8][j] / lpart[j];
        out[(size_t)(batch*Sc + qg)*(Hc*VDc) + h*VDc + v8*16 + fr] = f2bf(o);
      }
    }
  }
}

// ---------------- launcher ----------------
extern "C" void kernel_launch(void* const* d_in, const int* in_sizes, int n_in,
                              void* d_out, int out_size, void* d_ws, size_t ws_size,
                              hipStream_t stream) {
  (void)in_sizes; (void)n_in; (void)out_size; (void)ws_size;
  const float* hidden  = (const float*)d_in[0];
  const float* q_a_w   = (const float*)d_in[3];
  const float* q_a_ln  = (const float*)d_in[4];
  const float* q_b_w   = (const float*)d_in[5];
  const float* kv_a_w  = (const float*)d_in[6];
  const float* kv_a_ln = (const float*)d_in[7];
  const float* kv_b_w  = (const float*)d_in[8];
  const float* o_w     = (const float*)d_in[9];
  float* outp = (float*)d_out;

  char* ws = (char*)d_ws;
  size_t off = 0;
  auto alloc = [&](size_t n)->char*{ char* p = ws + off; off += (n + 255) & ~(size_t)255; return p; };
  ushort_t* hbf  = (ushort_t*)alloc((size_t)Bc*Sc*HIDc*2);      // hidden bf16; later o_w bf16
  ushort_t* wqa  = (ushort_t*)alloc((size_t)QLRc*HIDc*2);       // later aliased as aout
  ushort_t* wqb  = (ushort_t*)alloc((size_t)Hc*QHDc*QLRc*2);
  ushort_t* wkva = (ushort_t*)alloc((size_t)640*HIDc*2);        // 640 rows (576 data + pad)
  ushort_t* wkvb = (ushort_t*)alloc((size_t)Hc*256*KVLRc*2);
  ushort_t* qa   = (ushort_t*)alloc((size_t)Bc*Sc*QLRc*2);
  ushort_t* qbf  = (ushort_t*)alloc((size_t)Bc*Sc*Hc*QHDc*2);
  ushort_t* ckv  = (ushort_t*)alloc((size_t)Bc*Sc*CKVS*2);      // stride 640
  ushort_t* kvbf = (ushort_t*)alloc((size_t)Bc*Sc*Hc*256*2);
  ushort_t* vtb  = (ushort_t*)alloc((size_t)Bc*Hc*VDc*Sc*2);    // V transposed [bh][vd][s]
  float*    ct   = (float*)alloc((size_t)Sc*32*4);
  float*    st   = (float*)alloc((size_t)Sc*32*4);
  ushort_t* aout = wqa;   // alias: wqa+wqb+wkva free before attn

  const int M = Bc*Sc; // 4096

  // one batched convert: hidden + q_a_w + q_b_w + kv_a_w + kv_b_w
  conv_all<<<2048,256,0,stream>>>(hidden, q_a_w, q_b_w, kv_a_w, kv_b_w,
                                  hbf, wqa, wqb, wkva, wkvb);
  // q_a = hidden @ q_a_w^T   [4096,1536,4096]
  gemm256x128<true><<<(M/256)*(QLRc/128),512,0,stream>>>(hbf, wqa, qa, M, QLRc, HIDc, HIDc);
  // ckv = hidden @ kv_a_w^T  (N padded to 640; cols 576..639 are garbage, never read)
  gemm256x128<true><<<(M/256)*(640/128),512,0,stream>>>(hbf, wkva, ckv, M, CKVS, HIDc, HIDc);
  // merged RMSNorm (qa + ckv)
  rmsnorm2<<<2*M,256,0,stream>>>(qa, q_a_ln, ckv, kv_a_ln);
  // hbf free now -> convert o_w into it
  f32_to_bf16<<<2048,256,0,stream>>>(o_w, hbf, (long long)HIDc*HIDc);
  // q = q_a @ q_b_w^T  [4096,6144,1536]
  gemm256x128<true><<<(M/256)*(Hc*QHDc/128),512,0,stream>>>(qa, wqb, qbf, M, Hc*QHDc, QLRc, QLRc);
  // kv = ckv_norm @ kv_b_w^T  [4096,8192,512], lda=640 (512 blocks = 2/CU)
  gemm256<true><<<(M/256)*(Hc*256/256),512,0,stream>>>(ckv, wkvb, kvbf, M, Hc*256, KVLRc, CKVS);
  // RoPE
  rope_tab<<<CDIV(Sc*32,256),256,0,stream>>>(ct, st);
  rope_qk<<<CDIV(Bc*Sc*Hc*32 + Bc*Sc*32,256),256,0,stream>>>(qbf, ckv, ct, st);
  // V transpose + attention (1024 uniform blocks, diagonal-paired)
  vtrans<<<dim3(Sc/64, Bc*Hc),256,0,stream>>>(kvbf, vtb);
  attn_fwd<<<dim3(Bc*Hc, 16),256,0,stream>>>(qbf, kvbf, ckv, vtb, aout);
  // out = attn @ o_w^T  [4096,4096,4096], f32 store — 256x128 tiles: 512 blocks = 2/CU
  gemm256x128<false><<<(M/256)*(HIDc/128),512,0,stream>>>(aout, hbf, outp, M, HIDc, HIDc, HIDc);
}

// Round 12
// 670.558 us; speedup vs baseline: 1.0806x; 1.0372x over previous
//
#include <hip/hip_runtime.h>
#include <hip/hip_bf16.h>

typedef __attribute__((ext_vector_type(8))) short short8;
typedef __attribute__((ext_vector_type(4))) float f32x4;
typedef unsigned short ushort_t;

static constexpr int Bc = 2, Sc = 2048, HIDc = 4096, Hc = 32;
static constexpr int NOPEc = 128, ROPEc = 64, VDc = 128, QHDc = 192;
static constexpr int QLRc = 1536, KVLRc = 512;
static constexpr int CKVS = 640;   // padded ckv row stride (576 -> 640)

#define CDIV(a,b) (((a)+(b)-1)/(b))

__device__ __forceinline__ float bf2f(ushort_t u){
  union { unsigned u32; float f; } x; x.u32 = ((unsigned)u) << 16; return x.f;
}
__device__ __forceinline__ ushort_t f2bf(float f){
  union { float f; unsigned u32; } x; x.f = f;
  unsigned r = x.u32 + 0x7FFFu + ((x.u32 >> 16) & 1u);
  return (ushort_t)(r >> 16);
}
__device__ __forceinline__ void gload16(const void* g, void* l){
  __builtin_amdgcn_global_load_lds((const __attribute__((address_space(1))) void*)g,
                                   (__attribute__((address_space(3))) void*)l, 16, 0, 0);
}

// ---------------- f32 -> bf16 convert (vectorized, grid-stride) ----------------
__global__ __launch_bounds__(256)
void f32_to_bf16(const float* __restrict__ in, ushort_t* __restrict__ out, long long n){
  long long stride = (long long)gridDim.x * 256 * 4;
  for (long long i = ((long long)blockIdx.x*256 + threadIdx.x)*4; i < n; i += stride){
    float4 v = *(const float4*)(in + i);
    unsigned long long pk = (unsigned long long)f2bf(v.x)
                          | ((unsigned long long)f2bf(v.y) << 16)
                          | ((unsigned long long)f2bf(v.z) << 32)
                          | ((unsigned long long)f2bf(v.w) << 48);
    *(unsigned long long*)(out + i) = pk;
  }
}

// ---------------- batched 5-segment f32->bf16 (hidden + 4 weights) ----------------
__global__ __launch_bounds__(256)
void conv_all(const float* __restrict__ s0, const float* __restrict__ s1,
              const float* __restrict__ s2, const float* __restrict__ s3,
              const float* __restrict__ s4,
              ushort_t* __restrict__ d0, ushort_t* __restrict__ d1,
              ushort_t* __restrict__ d2, ushort_t* __restrict__ d3,
              ushort_t* __restrict__ d4){
  constexpr long long C0 = 16777216, C1 = 23068672, C2 = 32505856, C3 = 34865152, C4 = 39059456;
  long long stride = (long long)gridDim.x * 256 * 4;
  for (long long e = ((long long)blockIdx.x*256 + threadIdx.x)*4; e < C4; e += stride){
    const float* sp; ushort_t* dp; long long o;
    if      (e < C0){ sp = s0; dp = d0; o = e; }
    else if (e < C1){ sp = s1; dp = d1; o = e - C0; }
    else if (e < C2){ sp = s2; dp = d2; o = e - C1; }
    else if (e < C3){ sp = s3; dp = d3; o = e - C2; }
    else            { sp = s4; dp = d4; o = e - C3; }
    float4 v = *(const float4*)(sp + o);
    unsigned long long pk = (unsigned long long)f2bf(v.x)
                          | ((unsigned long long)f2bf(v.y) << 16)
                          | ((unsigned long long)f2bf(v.z) << 32)
                          | ((unsigned long long)f2bf(v.w) << 48);
    *(unsigned long long*)(dp + o) = pk;
  }
}

// ======== GEMM 256x256 tile, BK=64, 8 waves, dbuf LDS, swizzled, counted vmcnt ======
template<bool OUTBF>
__global__ __launch_bounds__(512, 2)
void gemm256(const ushort_t* __restrict__ A, const ushort_t* __restrict__ Bw,
             void* __restrict__ Cp, int M, int N, int K, int lda)
{
  __shared__ __attribute__((aligned(16))) ushort_t sm[65536];
  const int tid = threadIdx.x, lane = tid & 63, w = tid >> 6;
  const int wr = w >> 2, wc = w & 3;
  const int fr = lane & 15, kq = lane >> 4;

  const int nwg = gridDim.x, nx = N >> 8;
  const int bid = blockIdx.x;
  const int swz = (bid & 7) * (nwg >> 3) + (bid >> 3);
  const int m0 = (swz / nx) << 8, n0 = (swz % nx) << 8;

  f32x4 acc[8][4];
  #pragma unroll
  for (int m=0;m<8;m++)
    #pragma unroll
    for (int n=0;n<4;n++) acc[m][n] = (f32x4){0.f,0.f,0.f,0.f};

  const int srow = tid >> 3;
  const int gch  = (tid & 7) ^ (srow & 7);

  auto stage = [&](int c, int kt){
    const int k0 = kt << 6;
    ushort_t* Al = sm + c*16384;
    ushort_t* Bl = sm + 32768 + c*16384;
    const ushort_t* Ag = A  + (size_t)(m0 + srow)*lda + k0 + gch*8;
    const ushort_t* Bg = Bw + (size_t)(n0 + srow)*K   + k0 + gch*8;
    #pragma unroll
    for (int i=0;i<4;i++) gload16(Ag + (size_t)(i*64)*lda, Al + i*4096 + tid*8);
    #pragma unroll
    for (int i=0;i<4;i++) gload16(Bg + (size_t)(i*64)*K,   Bl + i*4096 + tid*8);
  };

  auto compute = [&](int c){
    const ushort_t* Al = sm + c*16384;
    const ushort_t* Bl = sm + 32768 + c*16384;
    const int s = fr & 7;
    short8 bfr[4][2];
    #pragma unroll
    for (int n=0;n<4;n++){
      const int row = wc*64 + n*16 + fr;
      bfr[n][0] = *(const short8*)(Bl + row*64 + ((kq    ) ^ s)*8);
      bfr[n][1] = *(const short8*)(Bl + row*64 + ((kq + 4) ^ s)*8);
    }
    #pragma unroll
    for (int m=0;m<8;m++){
      const int row = wr*128 + m*16 + fr;
      short8 a0 = *(const short8*)(Al + row*64 + ((kq    ) ^ s)*8);
      short8 a1 = *(const short8*)(Al + row*64 + ((kq + 4) ^ s)*8);
      #pragma unroll
      for (int n=0;n<4;n++){
        acc[m][n] = __builtin_amdgcn_mfma_f32_16x16x32_bf16(a0, bfr[n][0], acc[m][n], 0,0,0);
        acc[m][n] = __builtin_amdgcn_mfma_f32_16x16x32_bf16(a1, bfr[n][1], acc[m][n], 0,0,0);
      }
    }
  };

  const int nkt = K >> 6;
  stage(0, 0);
  stage(1, 1);
  asm volatile("s_waitcnt vmcnt(8)" ::: "memory");
  __builtin_amdgcn_s_barrier();
  __builtin_amdgcn_sched_barrier(0);

  int cur = 0;
  for (int kt = 0; kt < nkt; ++kt){
    compute(cur);
    __builtin_amdgcn_s_barrier();
    __builtin_amdgcn_sched_barrier(0);
    if (kt + 2 < nkt){
      stage(cur, kt + 2);
      asm volatile("s_waitcnt vmcnt(8)" ::: "memory");
    } else {
      asm volatile("s_waitcnt vmcnt(0)" ::: "memory");
    }
    __builtin_amdgcn_s_barrier();
    __builtin_amdgcn_sched_barrier(0);
    cur ^= 1;
  }

  const int rb = m0 + wr*128 + kq*4;
  const int cb = n0 + wc*64 + fr;
  #pragma unroll
  for (int m=0;m<8;m++)
    #pragma unroll
    for (int n=0;n<4;n++){
      const int col = cb + n*16;
      #pragma unroll
      for (int j=0;j<4;j++){
        const int row = rb + m*16 + j;
        float v = acc[m][n][j];
        if (OUTBF) ((ushort_t*)Cp)[(size_t)row*N + col] = f2bf(v);
        else       ((float*)  Cp)[(size_t)row*N + col] = v;
      }
    }
}

// ======== GEMM 256x128 tile, BK=64, 8 waves (4Mx2N), dbuf, counted vmcnt ======
template<bool OUTBF>
__global__ __launch_bounds__(512, 2)
void gemm256x128(const ushort_t* __restrict__ A, const ushort_t* __restrict__ Bw,
                 void* __restrict__ Cp, int M, int N, int K, int lda)
{
  __shared__ __attribute__((aligned(16))) ushort_t sm[49152];
  const int tid = threadIdx.x, lane = tid & 63, w = tid >> 6;
  const int wr = w >> 1, wc = w & 1;
  const int fr = lane & 15, kq = lane >> 4;

  const int nwg = gridDim.x, nx = N >> 7;
  const int bid = blockIdx.x;
  const int swz = (bid & 7) * (nwg >> 3) + (bid >> 3);
  const int m0 = (swz / nx) << 8, n0 = (swz % nx) << 7;

  f32x4 acc[4][4];
  #pragma unroll
  for (int m=0;m<4;m++)
    #pragma unroll
    for (int n=0;n<4;n++) acc[m][n] = (f32x4){0.f,0.f,0.f,0.f};

  const int srow = tid >> 3;
  const int gch  = (tid & 7) ^ (srow & 7);

  auto stage = [&](int c, int kt){
    const int k0 = kt << 6;
    ushort_t* Al = sm + c*16384;
    ushort_t* Bl = sm + 32768 + c*8192;
    const ushort_t* Ag = A  + (size_t)(m0 + srow)*lda + k0 + gch*8;
    const ushort_t* Bg = Bw + (size_t)(n0 + srow)*K   + k0 + gch*8;
    #pragma unroll
    for (int i=0;i<4;i++) gload16(Ag + (size_t)(i*64)*lda, Al + i*4096 + tid*8);
    #pragma unroll
    for (int i=0;i<2;i++) gload16(Bg + (size_t)(i*64)*K,   Bl + i*4096 + tid*8);
  };

  auto compute = [&](int c){
    const ushort_t* Al = sm + c*16384;
    const ushort_t* Bl = sm + 32768 + c*8192;
    const int s = fr & 7;
    short8 bfr[4][2];
    #pragma unroll
    for (int n=0;n<4;n++){
      const int row = wc*64 + n*16 + fr;
      bfr[n][0] = *(const short8*)(Bl + row*64 + ((kq    ) ^ s)*8);
      bfr[n][1] = *(const short8*)(Bl + row*64 + ((kq + 4) ^ s)*8);
    }
    #pragma unroll
    for (int m=0;m<4;m++){
      const int row = wr*64 + m*16 + fr;
      short8 a0 = *(const short8*)(Al + row*64 + ((kq    ) ^ s)*8);
      short8 a1 = *(const short8*)(Al + row*64 + ((kq + 4) ^ s)*8);
      #pragma unroll
      for (int n=0;n<4;n++){
        acc[m][n] = __builtin_amdgcn_mfma_f32_16x16x32_bf16(a0, bfr[n][0], acc[m][n], 0,0,0);
        acc[m][n] = __builtin_amdgcn_mfma_f32_16x16x32_bf16(a1, bfr[n][1], acc[m][n], 0,0,0);
      }
    }
  };

  const int nkt = K >> 6;
  stage(0, 0);
  stage(1, 1);
  asm volatile("s_waitcnt vmcnt(6)" ::: "memory");
  __builtin_amdgcn_s_barrier();
  __builtin_amdgcn_sched_barrier(0);

  int cur = 0;
  for (int kt = 0; kt < nkt; ++kt){
    compute(cur);
    __builtin_amdgcn_s_barrier();
    __builtin_amdgcn_sched_barrier(0);
    if (kt + 2 < nkt){
      stage(cur, kt + 2);
      asm volatile("s_waitcnt vmcnt(6)" ::: "memory");
    } else {
      asm volatile("s_waitcnt vmcnt(0)" ::: "memory");
    }
    __builtin_amdgcn_s_barrier();
    __builtin_amdgcn_sched_barrier(0);
    cur ^= 1;
  }

  const int rb = m0 + wr*64 + kq*4;
  const int cb = n0 + wc*64 + fr;
  #pragma unroll
  for (int m=0;m<4;m++)
    #pragma unroll
    for (int n=0;n<4;n++){
      const int col = cb + n*16;
      #pragma unroll
      for (int j=0;j<4;j++){
        const int row = rb + m*16 + j;
        float v = acc[m][n][j];
        if (OUTBF) ((ushort_t*)Cp)[(size_t)row*N + col] = f2bf(v);
        else       ((float*)  Cp)[(size_t)row*N + col] = v;
      }
    }
}

// ---------------- merged RMSNorm (qa rows then ckv rows) ----------------
__global__ __launch_bounds__(256)
void rmsnorm2(ushort_t* __restrict__ xa, const float* __restrict__ wa,
              ushort_t* __restrict__ xb, const float* __restrict__ wb){
  const int row = blockIdx.x;
  ushort_t* p; const float* w; int D;
  if (row < Bc*Sc){ p = xa + (size_t)row*QLRc; w = wa; D = QLRc; }
  else            { p = xb + (size_t)(row - Bc*Sc)*CKVS; w = wb; D = KVLRc; }
  float ss = 0.f;
  for (int c = threadIdx.x*8; c < D; c += 2048) {
    short8 v = *(const short8*)(p + c);
    #pragma unroll
    for (int j=0;j<8;j++){ float f = bf2f((ushort_t)v[j]); ss += f*f; }
  }
  #pragma unroll
  for (int m=1;m<64;m<<=1) ss += __shfl_xor(ss, m, 64);
  __shared__ float red[4];
  if ((threadIdx.x & 63)==0) red[threadIdx.x>>6] = ss;
  __syncthreads();
  float tot = red[0]+red[1]+red[2]+red[3];
  float inv = rsqrtf(tot/(float)D + 1e-6f);
  for (int c = threadIdx.x*8; c < D; c += 2048) {
    short8 v = *(const short8*)(p + c);
    short8 o;
    #pragma unroll
    for (int j=0;j<8;j++) o[j] = (short)f2bf(bf2f((ushort_t)v[j]) * inv * w[c+j]);
    *(short8*)(p + c) = o;
  }
}

// ------- fused RoPE (inline sincos) + V transpose, one launch -------
// Blocks [0, RB): rope on q_pe (NQ elems) then k_pe (NK elems), cos/sin computed
// per-thread (no table dependency). Blocks [RB, RB+2048): vtrans tiles.
__global__ __launch_bounds__(256)
void rope_vt(ushort_t* __restrict__ q, ushort_t* __restrict__ ckv,
             const ushort_t* __restrict__ kv, ushort_t* __restrict__ vt){
  constexpr int NQ = Bc*Sc*Hc*32;
  constexpr int NK = Bc*Sc*32;
  constexpr int RB = (NQ + NK + 255) / 256;   // 16640 rope blocks
  __shared__ __attribute__((aligned(16))) ushort_t L[64][136];

  if ((int)blockIdx.x < RB) {
    int i = blockIdx.x*256 + threadIdx.x;
    int p, t; ushort_t* base;
    if (i < NQ) {
      p = i & 31;
      int h = (i >> 5) & (Hc-1);
      int bs = i >> 10;
      t = bs & (Sc-1);
      base = q + (size_t)bs*Hc*QHDc + h*QHDc + NOPEc + 2*p;
    } else {
      int k = i - NQ;
      if (k >= NK) return;
      p = k & 31;
      int bs = k >> 5;
      t = bs & (Sc-1);
      base = ckv + (size_t)bs*CKVS + 512 + 2*p;
    }
    float invf = exp2f(-(float)p * (13.287712379549449f / 32.f)); // 10000^(-p/32)
    float ang = (float)t * invf;
    float s, c;
    sincosf(ang, &s, &c);
    unsigned u = *(const unsigned*)base;
    float a = bf2f((ushort_t)(u & 0xFFFFu)), bb = bf2f((ushort_t)(u >> 16));
    unsigned o = (unsigned)f2bf(a*c - bb*s) | ((unsigned)f2bf(bb*c + a*s) << 16);
    *(unsigned*)base = o;
    return;
  }

  // ---- vtrans part: kv[bs][h][256](+128) -> vt[bh][vd][s] ----
  const int vb = (int)blockIdx.x - RB;       // 0..2047
  const int s0 = (vb & 31) * 64;
  const int bh = vb >> 5;
  const int batch = bh >> 5, h = bh & 31;
  #pragma unroll
  for (int i = 0; i < 4; i++) {
    int chunk = i*256 + threadIdx.x;
    int r = chunk >> 4;
    int c = (chunk & 15) * 8;
    short8 v = *(const short8*)(kv + ((size_t)(batch*Sc + s0 + r)*Hc + h)*256 + 128 + c);
    *(short8*)&L[r][c] = v;
  }
  __syncthreads();
  #pragma unroll
  for (int i = 0; i < 4; i++) {
    int chunk = i*256 + threadIdx.x;
    int vd = chunk >> 3;
    int sc2 = (chunk & 7) * 8;
    short8 o;
    #pragma unroll
    for (int j=0;j<8;j++) o[j] = (short)L[sc2+j][vd];
    *(short8*)(vt + ((size_t)bh*VDc + vd)*Sc + s0 + sc2) = o;
  }
}

// ---------------- Flash attention (causal), 4 waves — PROVEN 211us version ----------
// Diagonal pairing: block (bh, y) processes q-tiles {31-y, y} sequentially ->
// every block does exactly 66 KV-tile iterations (perfect balance); same-bh blocks
// stream K/V in lockstep -> near-perfect L2 reuse (FETCH ~111MB). 1-deep reg-staged
// prefetch; attn is TLP-bound (R9: depth-2 null; R10: fewer-reads/fewer-waves hurt).
__global__ __launch_bounds__(256)
void attn_fwd(const ushort_t* __restrict__ qb, const ushort_t* __restrict__ kvb,
              const ushort_t* __restrict__ ckv, const ushort_t* __restrict__ vt,
              ushort_t* __restrict__ out)
{
  constexpr int KP = 200, VP = 40;   // padded strides: 2-way-bank-conflict only
  __shared__ __attribute__((aligned(16))) ushort_t Ks[32*KP];
  __shared__ __attribute__((aligned(16))) ushort_t Vs[128*VP];
  __shared__ __attribute__((aligned(16))) ushort_t Ps[4][16*VP];
  const int tid = threadIdx.x, lane = tid & 63, w = tid >> 6;
  const int fr = lane & 15, kq = lane >> 4;
  const int y = (int)blockIdx.y;                      // 0..15
  const int bh = blockIdx.x, batch = bh >> 5, h = bh & 31;

  const float scl = 0.07216878364870323f * 1.4426950408889634f; // 192^-0.5 * log2(e)
  const float THR = 8.0f;

  const int ksr = tid >> 3, ksub = tid & 7;   // K staging: 32 rows x 24 chunks
  const int vvd = tid >> 1, vsub = tid & 1;   // V staging: 128 rows x 4 chunks

  const ushort_t* kbase  = kvb + ((size_t)batch*Sc + ksr)*((size_t)Hc*256) + (size_t)h*256;
  const ushort_t* pebase = ckv + (size_t)(batch*Sc + ksr)*CKVS + 512;
  const ushort_t* vbase  = vt + ((size_t)bh*VDc + vvd)*Sc;

  for (int seg = 0; seg < 2; ++seg) {
    const int qt = seg == 0 ? (31 - y) : y;           // heavy tile first
    const int q0 = qt * 64;

    const int qrow = q0 + w*16 + fr;
    const ushort_t* qptr = qb + ((size_t)(batch*Sc + qrow)*Hc + h)*QHDc;
    short8 qf[6];
    #pragma unroll
    for (int kk=0;kk<6;kk++) qf[kk] = *(const short8*)(qptr + kk*32 + kq*8);

    f32x4 acc_o[8];
    #pragma unroll
    for (int i=0;i<8;i++) acc_o[i] = (f32x4){0.f,0.f,0.f,0.f};
    float mrow[4]  = {-3e38f,-3e38f,-3e38f,-3e38f};
    float lpart[4] = {0.f,0.f,0.f,0.f};

    const int ktiles = q0/32 + 2;

    short8 kreg[3], vreg[2];
    {
      #pragma unroll
      for (int i=0;i<3;i++){
        int c = (ksub*3 + i)*8;
        kreg[i] = (c < 128) ? *(const short8*)(kbase + c)
                            : *(const short8*)(pebase + (c - 128));
      }
      #pragma unroll
      for (int i=0;i<2;i++) vreg[i] = *(const short8*)(vbase + (vsub*2+i)*8);
    }

    for (int kt = 0; kt < ktiles; kt++) {
      const int j0 = kt*32;
      #pragma unroll
      for (int i=0;i<3;i++) *(short8*)&Ks[ksr*KP + (ksub*3 + i)*8] = kreg[i];
      #pragma unroll
      for (int i=0;i<2;i++) *(short8*)&Vs[vvd*VP + (vsub*2 + i)*8] = vreg[i];
      __syncthreads();

      if (kt + 1 < ktiles) {
        const size_t roff = (size_t)(j0 + 32);
        #pragma unroll
        for (int i=0;i<3;i++){
          int c = (ksub*3 + i)*8;
          kreg[i] = (c < 128) ? *(const short8*)(kbase + roff*((size_t)Hc*256) + c)
                              : *(const short8*)(pebase + roff*CKVS + (c - 128));
        }
        #pragma unroll
        for (int i=0;i<2;i++) vreg[i] = *(const short8*)(vbase + roff + (vsub*2+i)*8);
      }

      f32x4 s0 = (f32x4){0.f,0.f,0.f,0.f}, s1 = (f32x4){0.f,0.f,0.f,0.f};
      __builtin_amdgcn_s_setprio(1);
      #pragma unroll
      for (int kk=0;kk<6;kk++){
        short8 b0 = *(const short8*)&Ks[fr*KP + kk*32 + kq*8];
        short8 b1 = *(const short8*)&Ks[(16+fr)*KP + kk*32 + kq*8];
        s0 = __builtin_amdgcn_mfma_f32_16x16x32_bf16(qf[kk], b0, s0, 0,0,0);
        s1 = __builtin_amdgcn_mfma_f32_16x16x32_bf16(qf[kk], b1, s1, 0,0,0);
      }
      __builtin_amdgcn_s_setprio(0);

      const bool full = (j0 + 31 <= q0 + w*16);
      float x0[4], x1[4];
      int okl = 1;
      #pragma unroll
      for (int j=0;j<4;j++){
        float a  = s0[j]*scl, c2 = s1[j]*scl;
        if (!full) {
          int qp = q0 + w*16 + kq*4 + j;
          if (j0 + fr      > qp) a  = -3e38f;
          if (j0 + 16 + fr > qp) c2 = -3e38f;
        }
        x0[j] = a; x1[j] = c2;
        okl &= (fmaxf(a, c2) <= mrow[j] + THR) ? 1 : 0;
      }
      if (!__all(okl)) {
        float tmax[4];
        #pragma unroll
        for (int j=0;j<4;j++) tmax[j] = fmaxf(x0[j], x1[j]);
        #pragma unroll
        for (int m=1;m<16;m<<=1){
          #pragma unroll
          for (int j=0;j<4;j++) tmax[j] = fmaxf(tmax[j], __shfl_xor(tmax[j], m, 64));
        }
        #pragma unroll
        for (int j=0;j<4;j++){
          float mn = fmaxf(mrow[j], tmax[j]);
          float corr = exp2f(mrow[j] - mn);
          mrow[j] = mn;
          lpart[j] *= corr;
          #pragma unroll
          for (int i=0;i<8;i++) acc_o[i][j] *= corr;
        }
      }
      float p0[4], p1[4];
      #pragma unroll
      for (int j=0;j<4;j++){
        p0[j] = exp2f(x0[j] - mrow[j]);
        p1[j] = exp2f(x1[j] - mrow[j]);
        lpart[j] += p0[j] + p1[j];
      }
      #pragma unroll
      for (int j=0;j<4;j++){
        unsigned pk;
        asm("v_cvt_pk_bf16_f32 %0, %1, %2" : "=v"(pk) : "v"(p0[j]), "v"(p1[j]));
        Ps[w][(kq*4+j)*VP + fr]      = (ushort_t)(pk & 0xFFFFu);
        Ps[w][(kq*4+j)*VP + 16 + fr] = (ushort_t)(pk >> 16);
      }
      short8 ap = *(const short8*)&Ps[w][fr*VP + kq*8];
      __builtin_amdgcn_s_setprio(1);
      #pragma unroll
      for (int v8=0; v8<8; v8++){
        short8 bv = *(const short8*)&Vs[(v8*16 + fr)*VP + kq*8];
        acc_o[v8] = __builtin_amdgcn_mfma_f32_16x16x32_bf16(ap, bv, acc_o[v8], 0,0,0);
      }
      __builtin_amdgcn_s_setprio(0);
      __syncthreads();
    }

    #pragma unroll
    for (int m=1;m<16;m<<=1){
      #pragma unroll
      for (int j=0;j<4;j++) lpart[j] += __shfl_xor(lpart[j], m, 64);
    }
    #pragma unroll
    for (int v8=0; v8<8; v8++){
      #pragma unroll
      for (int j=0;j<4;j++){
        int qg = q0 + w*16 + kq*4 + j;
        float o = acc_o[v8][j] / lpart[j];
        out[(size_t)(batch*Sc + qg)*(Hc*VDc) + h*VDc + v8*16 + fr] = f2bf(o);
      }
    }
  }
}

// ---------------- launcher ----------------
extern "C" void kernel_launch(void* const* d_in, const int* in_sizes, int n_in,
                              void* d_out, int out_size, void* d_ws, size_t ws_size,
                              hipStream_t stream) {
  (void)in_sizes; (void)n_in; (void)out_size; (void)ws_size;
  const float* hidden  = (const float*)d_in[0];
  const float* q_a_w   = (const float*)d_in[3];
  const float* q_a_ln  = (const float*)d_in[4];
  const float* q_b_w   = (const float*)d_in[5];
  const float* kv_a_w  = (const float*)d_in[6];
  const float* kv_a_ln = (const float*)d_in[7];
  const float* kv_b_w  = (const float*)d_in[8];
  const float* o_w     = (const float*)d_in[9];
  float* outp = (float*)d_out;

  char* ws = (char*)d_ws;
  size_t off = 0;
  auto alloc = [&](size_t n)->char*{ char* p = ws + off; off += (n + 255) & ~(size_t)255; return p; };
  ushort_t* hbf  = (ushort_t*)alloc((size_t)Bc*Sc*HIDc*2);      // hidden bf16; later o_w bf16
  ushort_t* wqa  = (ushort_t*)alloc((size_t)QLRc*HIDc*2);       // later aliased as aout
  ushort_t* wqb  = (ushort_t*)alloc((size_t)Hc*QHDc*QLRc*2);
  ushort_t* wkva = (ushort_t*)alloc((size_t)640*HIDc*2);        // 640 rows (576 data + pad)
  ushort_t* wkvb = (ushort_t*)alloc((size_t)Hc*256*KVLRc*2);
  ushort_t* qa   = (ushort_t*)alloc((size_t)Bc*Sc*QLRc*2);
  ushort_t* qbf  = (ushort_t*)alloc((size_t)Bc*Sc*Hc*QHDc*2);
  ushort_t* ckv  = (ushort_t*)alloc((size_t)Bc*Sc*CKVS*2);      // stride 640
  ushort_t* kvbf = (ushort_t*)alloc((size_t)Bc*Sc*Hc*256*2);
  ushort_t* vtb  = (ushort_t*)alloc((size_t)Bc*Hc*VDc*Sc*2);    // V transposed [bh][vd][s]
  ushort_t* aout = wqa;   // alias: wqa+wqb+wkva free before attn

  const int M = Bc*Sc; // 4096

  // one batched convert: hidden + q_a_w + q_b_w + kv_a_w + kv_b_w
  conv_all<<<2048,256,0,stream>>>(hidden, q_a_w, q_b_w, kv_a_w, kv_b_w,
                                  hbf, wqa, wqb, wkva, wkvb);
  // q_a = hidden @ q_a_w^T   [4096,1536,4096]
  gemm256x128<true><<<(M/256)*(QLRc/128),512,0,stream>>>(hbf, wqa, qa, M, QLRc, HIDc, HIDc);
  // ckv = hidden @ kv_a_w^T  (N padded to 640; cols 576..639 are garbage, never read)
  gemm256x128<true><<<(M/256)*(640/128),512,0,stream>>>(hbf, wkva, ckv, M, CKVS, HIDc, HIDc);
  // merged RMSNorm (qa + ckv)
  rmsnorm2<<<2*M,256,0,stream>>>(qa, q_a_ln, ckv, kv_a_ln);
  // hbf free now -> convert o_w into it
  f32_to_bf16<<<2048,256,0,stream>>>(o_w, hbf, (long long)HIDc*HIDc);
  // q = q_a @ q_b_w^T  [4096,6144,1536]
  gemm256x128<true><<<(M/256)*(Hc*QHDc/128),512,0,stream>>>(qa, wqb, qbf, M, Hc*QHDc, QLRc, QLRc);
  // kv = ckv_norm @ kv_b_w^T  [4096,8192,512], lda=640 (512 blocks = 2/CU)
  gemm256<true><<<(M/256)*(Hc*256/256),512,0,stream>>>(ckv, wkvb, kvbf, M, Hc*256, KVLRc, CKVS);
  // fused RoPE (inline sincos) + V transpose: one launch
  {
    constexpr int NQ = Bc*Sc*Hc*32, NK = Bc*Sc*32;
    constexpr int RB = (NQ + NK + 255) / 256;
    rope_vt<<<RB + (Sc/64)*(Bc*Hc),256,0,stream>>>(qbf, ckv, kvbf, vtb);
  }
  // attention (1024 uniform blocks, diagonal-paired)
  attn_fwd<<<dim3(Bc*Hc, 16),256,0,stream>>>(qbf, kvbf, ckv, vtb, aout);
  // out = attn @ o_w^T  [4096,4096,4096], f32 store — 256^2 tiles (R11 showed 256x128 hurts here)
  gemm256<false><<<(M/256)*(HIDc/256),512,0,stream>>>(aout, hbf, outp, M, HIDc, HIDc, HIDc);
}

// Round 13
// 667.967 us; speedup vs baseline: 1.0848x; 1.0039x over previous
//
#include <hip/hip_runtime.h>
#include <hip/hip_bf16.h>

typedef __attribute__((ext_vector_type(8))) short short8;
typedef __attribute__((ext_vector_type(4))) float f32x4;
typedef unsigned short ushort_t;

static constexpr int Bc = 2, Sc = 2048, HIDc = 4096, Hc = 32;
static constexpr int NOPEc = 128, ROPEc = 64, VDc = 128, QHDc = 192;
static constexpr int QLRc = 1536, KVLRc = 512;
static constexpr int CKVS = 640;   // padded ckv row stride (576 -> 640)

#define CDIV(a,b) (((a)+(b)-1)/(b))

__device__ __forceinline__ float bf2f(ushort_t u){
  union { unsigned u32; float f; } x; x.u32 = ((unsigned)u) << 16; return x.f;
}
__device__ __forceinline__ ushort_t f2bf(float f){
  union { float f; unsigned u32; } x; x.f = f;
  unsigned r = x.u32 + 0x7FFFu + ((x.u32 >> 16) & 1u);
  return (ushort_t)(r >> 16);
}
__device__ __forceinline__ void gload16(const void* g, void* l){
  __builtin_amdgcn_global_load_lds((const __attribute__((address_space(1))) void*)g,
                                   (__attribute__((address_space(3))) void*)l, 16, 0, 0);
}

// ---------------- f32 -> bf16 convert (vectorized, grid-stride) ----------------
__global__ __launch_bounds__(256)
void f32_to_bf16(const float* __restrict__ in, ushort_t* __restrict__ out, long long n){
  long long stride = (long long)gridDim.x * 256 * 4;
  for (long long i = ((long long)blockIdx.x*256 + threadIdx.x)*4; i < n; i += stride){
    float4 v = *(const float4*)(in + i);
    unsigned long long pk = (unsigned long long)f2bf(v.x)
                          | ((unsigned long long)f2bf(v.y) << 16)
                          | ((unsigned long long)f2bf(v.z) << 32)
                          | ((unsigned long long)f2bf(v.w) << 48);
    *(unsigned long long*)(out + i) = pk;
  }
}

// ---------------- batched 5-segment f32->bf16 (hidden + 4 weights) ----------------
__global__ __launch_bounds__(256)
void conv_all(const float* __restrict__ s0, const float* __restrict__ s1,
              const float* __restrict__ s2, const float* __restrict__ s3,
              const float* __restrict__ s4,
              ushort_t* __restrict__ d0, ushort_t* __restrict__ d1,
              ushort_t* __restrict__ d2, ushort_t* __restrict__ d3,
              ushort_t* __restrict__ d4){
  constexpr long long C0 = 16777216, C1 = 23068672, C2 = 32505856, C3 = 34865152, C4 = 39059456;
  long long stride = (long long)gridDim.x * 256 * 4;
  for (long long e = ((long long)blockIdx.x*256 + threadIdx.x)*4; e < C4; e += stride){
    const float* sp; ushort_t* dp; long long o;
    if      (e < C0){ sp = s0; dp = d0; o = e; }
    else if (e < C1){ sp = s1; dp = d1; o = e - C0; }
    else if (e < C2){ sp = s2; dp = d2; o = e - C1; }
    else if (e < C3){ sp = s3; dp = d3; o = e - C2; }
    else            { sp = s4; dp = d4; o = e - C3; }
    float4 v = *(const float4*)(sp + o);
    unsigned long long pk = (unsigned long long)f2bf(v.x)
                          | ((unsigned long long)f2bf(v.y) << 16)
                          | ((unsigned long long)f2bf(v.z) << 32)
                          | ((unsigned long long)f2bf(v.w) << 48);
    *(unsigned long long*)(dp + o) = pk;
  }
}

// ======== GEMM 256x256 tile, BK=64, 8 waves, dbuf LDS, swizzled, counted vmcnt ======
template<bool OUTBF>
__global__ __launch_bounds__(512, 2)
void gemm256(const ushort_t* __restrict__ A, const ushort_t* __restrict__ Bw,
             void* __restrict__ Cp, int M, int N, int K, int lda)
{
  __shared__ __attribute__((aligned(16))) ushort_t sm[65536];
  const int tid = threadIdx.x, lane = tid & 63, w = tid >> 6;
  const int wr = w >> 2, wc = w & 3;
  const int fr = lane & 15, kq = lane >> 4;

  const int nwg = gridDim.x, nx = N >> 8;
  const int bid = blockIdx.x;
  const int swz = (bid & 7) * (nwg >> 3) + (bid >> 3);
  const int m0 = (swz / nx) << 8, n0 = (swz % nx) << 8;

  f32x4 acc[8][4];
  #pragma unroll
  for (int m=0;m<8;m++)
    #pragma unroll
    for (int n=0;n<4;n++) acc[m][n] = (f32x4){0.f,0.f,0.f,0.f};

  const int srow = tid >> 3;
  const int gch  = (tid & 7) ^ (srow & 7);

  auto stage = [&](int c, int kt){
    const int k0 = kt << 6;
    ushort_t* Al = sm + c*16384;
    ushort_t* Bl = sm + 32768 + c*16384;
    const ushort_t* Ag = A  + (size_t)(m0 + srow)*lda + k0 + gch*8;
    const ushort_t* Bg = Bw + (size_t)(n0 + srow)*K   + k0 + gch*8;
    #pragma unroll
    for (int i=0;i<4;i++) gload16(Ag + (size_t)(i*64)*lda, Al + i*4096 + tid*8);
    #pragma unroll
    for (int i=0;i<4;i++) gload16(Bg + (size_t)(i*64)*K,   Bl + i*4096 + tid*8);
  };

  auto compute = [&](int c){
    const ushort_t* Al = sm + c*16384;
    const ushort_t* Bl = sm + 32768 + c*16384;
    const int s = fr & 7;
    short8 bfr[4][2];
    #pragma unroll
    for (int n=0;n<4;n++){
      const int row = wc*64 + n*16 + fr;
      bfr[n][0] = *(const short8*)(Bl + row*64 + ((kq    ) ^ s)*8);
      bfr[n][1] = *(const short8*)(Bl + row*64 + ((kq + 4) ^ s)*8);
    }
    #pragma unroll
    for (int m=0;m<8;m++){
      const int row = wr*128 + m*16 + fr;
      short8 a0 = *(const short8*)(Al + row*64 + ((kq    ) ^ s)*8);
      short8 a1 = *(const short8*)(Al + row*64 + ((kq + 4) ^ s)*8);
      #pragma unroll
      for (int n=0;n<4;n++){
        acc[m][n] = __builtin_amdgcn_mfma_f32_16x16x32_bf16(a0, bfr[n][0], acc[m][n], 0,0,0);
        acc[m][n] = __builtin_amdgcn_mfma_f32_16x16x32_bf16(a1, bfr[n][1], acc[m][n], 0,0,0);
      }
    }
  };

  const int nkt = K >> 6;
  stage(0, 0);
  stage(1, 1);
  asm volatile("s_waitcnt vmcnt(8)" ::: "memory");
  __builtin_amdgcn_s_barrier();
  __builtin_amdgcn_sched_barrier(0);

  int cur = 0;
  for (int kt = 0; kt < nkt; ++kt){
    compute(cur);
    __builtin_amdgcn_s_barrier();
    __builtin_amdgcn_sched_barrier(0);
    if (kt + 2 < nkt){
      stage(cur, kt + 2);
      asm volatile("s_waitcnt vmcnt(8)" ::: "memory");
    } else {
      asm volatile("s_waitcnt vmcnt(0)" ::: "memory");
    }
    __builtin_amdgcn_s_barrier();
    __builtin_amdgcn_sched_barrier(0);
    cur ^= 1;
  }

  const int rb = m0 + wr*128 + kq*4;
  const int cb = n0 + wc*64 + fr;
  #pragma unroll
  for (int m=0;m<8;m++)
    #pragma unroll
    for (int n=0;n<4;n++){
      const int col = cb + n*16;
      #pragma unroll
      for (int j=0;j<4;j++){
        const int row = rb + m*16 + j;
        float v = acc[m][n][j];
        if (OUTBF) ((ushort_t*)Cp)[(size_t)row*N + col] = f2bf(v);
        else       ((float*)  Cp)[(size_t)row*N + col] = v;
      }
    }
}

// ======== GEMM 256x256, BK=64, 4-phase interleaved pipeline (8-phase-style) ========
// Phase p of tile kt: 16 MFMA (m{2p,2p+1} x 4n x 2kk), B-frags front-loaded at p0;
// after each phase's barrier, stage the just-freed quarter regions of tile kt+2
// into the SAME buffer (2 gloads/thread/phase). One counted vmcnt(6) per tile:
// in-order retirement => tile kt+1 fully resident; never drain-0 mid-loop.
template<bool OUTBF>
__global__ __launch_bounds__(512, 2)
void gemm256p(const ushort_t* __restrict__ A, const ushort_t* __restrict__ Bw,
              void* __restrict__ Cp, int M, int N, int K, int lda)
{
  __shared__ __attribute__((aligned(16))) ushort_t sm[65536];
  const int tid = threadIdx.x, lane = tid & 63, w = tid >> 6;
  const int wr = w >> 2, wc = w & 3;
  const int fr = lane & 15, kq = lane >> 4;
  const int s = fr & 7;

  const int nwg = gridDim.x, nx = N >> 8;
  const int bid = blockIdx.x;
  const int swz = (bid & 7) * (nwg >> 3) + (bid >> 3);
  const int m0 = (swz / nx) << 8, n0 = (swz % nx) << 8;

  f32x4 acc[8][4];
  #pragma unroll
  for (int m=0;m<8;m++)
    #pragma unroll
    for (int n=0;n<4;n++) acc[m][n] = (f32x4){0.f,0.f,0.f,0.f};

  const int ridx = tid >> 3;
  const int gch8 = ((tid & 7) ^ (ridx & 7)) * 8;
  const int thr8 = (tid & 7) * 8;

  auto stagePro = [&](int c, int kt){   // full-tile prologue stage (proven layout)
    const int k0 = kt << 6;
    ushort_t* Al = sm + c*16384;
    ushort_t* Bl = sm + 32768 + c*16384;
    const ushort_t* Ag = A  + (size_t)(m0 + ridx)*lda + k0 + gch8;
    const ushort_t* Bg = Bw + (size_t)(n0 + ridx)*K   + k0 + gch8;
    #pragma unroll
    for (int i=0;i<4;i++) gload16(Ag + (size_t)(i*64)*lda, Al + i*4096 + tid*8);
    #pragma unroll
    for (int i=0;i<4;i++) gload16(Bg + (size_t)(i*64)*K,   Bl + i*4096 + tid*8);
  };

  const int nkt = K >> 6;
  stagePro(0, 0);
  stagePro(1, 1);
  asm volatile("s_waitcnt vmcnt(8)" ::: "memory");
  __builtin_amdgcn_s_barrier();
  __builtin_amdgcn_sched_barrier(0);

  for (int kt = 0; kt < nkt; ++kt){
    const int c = kt & 1;
    const ushort_t* Al = sm + c*16384;
    const ushort_t* Bl = sm + 32768 + c*16384;
    ushort_t* AlW = sm + c*16384;                 // stage target: tile kt+2, same buf
    ushort_t* BlW = sm + 32768 + c*16384;
    const bool st = (kt + 2 < nkt);
    const int k2 = (kt + 2) << 6;
    short8 bfr[4][2];

    #pragma unroll
    for (int p = 0; p < 4; ++p){
      if (p == 0){
        #pragma unroll
        for (int n=0;n<4;n++){
          const int row = wc*64 + n*16 + fr;
          bfr[n][0] = *(const short8*)(Bl + row*64 + ((kq    ) ^ s)*8);
          bfr[n][1] = *(const short8*)(Bl + row*64 + ((kq + 4) ^ s)*8);
        }
      }
      const int r0 = wr*128 + (2*p  )*16 + fr;
      const int r1 = wr*128 + (2*p+1)*16 + fr;
      short8 a0k0 = *(const short8*)(Al + r0*64 + ((kq    ) ^ s)*8);
      short8 a0k1 = *(const short8*)(Al + r0*64 + ((kq + 4) ^ s)*8);
      short8 a1k0 = *(const short8*)(Al + r1*64 + ((kq    ) ^ s)*8);
      short8 a1k1 = *(const short8*)(Al + r1*64 + ((kq + 4) ^ s)*8);

      __builtin_amdgcn_s_setprio(1);
      #pragma unroll
      for (int n=0;n<4;n++){
        acc[2*p  ][n] = __builtin_amdgcn_mfma_f32_16x16x32_bf16(a0k0, bfr[n][0], acc[2*p  ][n], 0,0,0);
        acc[2*p  ][n] = __builtin_amdgcn_mfma_f32_16x16x32_bf16(a0k1, bfr[n][1], acc[2*p  ][n], 0,0,0);
        acc[2*p+1][n] = __builtin_amdgcn_mfma_f32_16x16x32_bf16(a1k0, bfr[n][0], acc[2*p+1][n], 0,0,0);
        acc[2*p+1][n] = __builtin_amdgcn_mfma_f32_16x16x32_bf16(a1k1, bfr[n][1], acc[2*p+1][n], 0,0,0);
      }
      __builtin_amdgcn_s_setprio(0);

      if (p == 3){
        if (st) asm volatile("s_waitcnt vmcnt(6)" ::: "memory");  // tile kt+1 resident
        else    asm volatile("s_waitcnt vmcnt(0)" ::: "memory");  // tail drain
      }
      __builtin_amdgcn_s_barrier();
      __builtin_amdgcn_sched_barrier(0);

      if (st){
        // stage quarter regions of tile kt+2 freed by this phase's reads
        const int rA = (ridx < 32) ? (32*p + ridx) : (96 + 32*p + ridx);  // {32p..}+{128+32p..}
        gload16(A  + (size_t)(m0 + rA)*lda + k2 + gch8, AlW + rA*64 + thr8);
        const int rB = 64*p + ridx;                                        // B free after p0
        gload16(Bw + (size_t)(n0 + rB)*K   + k2 + gch8, BlW + rB*64 + thr8);
      }
    }
  }

  const int rb = m0 + wr*128 + kq*4;
  const int cb = n0 + wc*64 + fr;
  #pragma unroll
  for (int m=0;m<8;m++)
    #pragma unroll
    for (int n=0;n<4;n++){
      const int col = cb + n*16;
      #pragma unroll
      for (int j=0;j<4;j++){
        const int row = rb + m*16 + j;
        float v = acc[m][n][j];
        if (OUTBF) ((ushort_t*)Cp)[(size_t)row*N + col] = f2bf(v);
        else       ((float*)  Cp)[(size_t)row*N + col] = v;
      }
    }
}

// ======== GEMM 256x128 tile, BK=64, 8 waves (4Mx2N), dbuf, counted vmcnt ======
template<bool OUTBF>
__global__ __launch_bounds__(512, 2)
void gemm256x128(const ushort_t* __restrict__ A, const ushort_t* __restrict__ Bw,
                 void* __restrict__ Cp, int M, int N, int K, int lda)
{
  __shared__ __attribute__((aligned(16))) ushort_t sm[49152];
  const int tid = threadIdx.x, lane = tid & 63, w = tid >> 6;
  const int wr = w >> 1, wc = w & 1;
  const int fr = lane & 15, kq = lane >> 4;

  const int nwg = gridDim.x, nx = N >> 7;
  const int bid = blockIdx.x;
  const int swz = (bid & 7) * (nwg >> 3) + (bid >> 3);
  const int m0 = (swz / nx) << 8, n0 = (swz % nx) << 7;

  f32x4 acc[4][4];
  #pragma unroll
  for (int m=0;m<4;m++)
    #pragma unroll
    for (int n=0;n<4;n++) acc[m][n] = (f32x4){0.f,0.f,0.f,0.f};

  const int srow = tid >> 3;
  const int gch  = (tid & 7) ^ (srow & 7);

  auto stage = [&](int c, int kt){
    const int k0 = kt << 6;
    ushort_t* Al = sm + c*16384;
    ushort_t* Bl = sm + 32768 + c*8192;
    const ushort_t* Ag = A  + (size_t)(m0 + srow)*lda + k0 + gch*8;
    const ushort_t* Bg = Bw + (size_t)(n0 + srow)*K   + k0 + gch*8;
    #pragma unroll
    for (int i=0;i<4;i++) gload16(Ag + (size_t)(i*64)*lda, Al + i*4096 + tid*8);
    #pragma unroll
    for (int i=0;i<2;i++) gload16(Bg + (size_t)(i*64)*K,   Bl + i*4096 + tid*8);
  };

  auto compute = [&](int c){
    const ushort_t* Al = sm + c*16384;
    const ushort_t* Bl = sm + 32768 + c*8192;
    const int s = fr & 7;
    short8 bfr[4][2];
    #pragma unroll
    for (int n=0;n<4;n++){
      const int row = wc*64 + n*16 + fr;
      bfr[n][0] = *(const short8*)(Bl + row*64 + ((kq    ) ^ s)*8);
      bfr[n][1] = *(const short8*)(Bl + row*64 + ((kq + 4) ^ s)*8);
    }
    #pragma unroll
    for (int m=0;m<4;m++){
      const int row = wr*64 + m*16 + fr;
      short8 a0 = *(const short8*)(Al + row*64 + ((kq    ) ^ s)*8);
      short8 a1 = *(const short8*)(Al + row*64 + ((kq + 4) ^ s)*8);
      #pragma unroll
      for (int n=0;n<4;n++){
        acc[m][n] = __builtin_amdgcn_mfma_f32_16x16x32_bf16(a0, bfr[n][0], acc[m][n], 0,0,0);
        acc[m][n] = __builtin_amdgcn_mfma_f32_16x16x32_bf16(a1, bfr[n][1], acc[m][n], 0,0,0);
      }
    }
  };

  const int nkt = K >> 6;
  stage(0, 0);
  stage(1, 1);
  asm volatile("s_waitcnt vmcnt(6)" ::: "memory");
  __builtin_amdgcn_s_barrier();
  __builtin_amdgcn_sched_barrier(0);

  int cur = 0;
  for (int kt = 0; kt < nkt; ++kt){
    compute(cur);
    __builtin_amdgcn_s_barrier();
    __builtin_amdgcn_sched_barrier(0);
    if (kt + 2 < nkt){
      stage(cur, kt + 2);
      asm volatile("s_waitcnt vmcnt(6)" ::: "memory");
    } else {
      asm volatile("s_waitcnt vmcnt(0)" ::: "memory");
    }
    __builtin_amdgcn_s_barrier();
    __builtin_amdgcn_sched_barrier(0);
    cur ^= 1;
  }

  const int rb = m0 + wr*64 + kq*4;
  const int cb = n0 + wc*64 + fr;
  #pragma unroll
  for (int m=0;m<4;m++)
    #pragma unroll
    for (int n=0;n<4;n++){
      const int col = cb + n*16;
      #pragma unroll
      for (int j=0;j<4;j++){
        const int row = rb + m*16 + j;
        float v = acc[m][n][j];
        if (OUTBF) ((ushort_t*)Cp)[(size_t)row*N + col] = f2bf(v);
        else       ((float*)  Cp)[(size_t)row*N + col] = v;
      }
    }
}

// ---------------- merged RMSNorm (qa rows then ckv rows) ----------------
__global__ __launch_bounds__(256)
void rmsnorm2(ushort_t* __restrict__ xa, const float* __restrict__ wa,
              ushort_t* __restrict__ xb, const float* __restrict__ wb){
  const int row = blockIdx.x;
  ushort_t* p; const float* w; int D;
  if (row < Bc*Sc){ p = xa + (size_t)row*QLRc; w = wa; D = QLRc; }
  else            { p = xb + (size_t)(row - Bc*Sc)*CKVS; w = wb; D = KVLRc; }
  float ss = 0.f;
  for (int c = threadIdx.x*8; c < D; c += 2048) {
    short8 v = *(const short8*)(p + c);
    #pragma unroll
    for (int j=0;j<8;j++){ float f = bf2f((ushort_t)v[j]); ss += f*f; }
  }
  #pragma unroll
  for (int m=1;m<64;m<<=1) ss += __shfl_xor(ss, m, 64);
  __shared__ float red[4];
  if ((threadIdx.x & 63)==0) red[threadIdx.x>>6] = ss;
  __syncthreads();
  float tot = red[0]+red[1]+red[2]+red[3];
  float inv = rsqrtf(tot/(float)D + 1e-6f);
  for (int c = threadIdx.x*8; c < D; c += 2048) {
    short8 v = *(const short8*)(p + c);
    short8 o;
    #pragma unroll
    for (int j=0;j<8;j++) o[j] = (short)f2bf(bf2f((ushort_t)v[j]) * inv * w[c+j]);
    *(short8*)(p + c) = o;
  }
}

// ------- fused RoPE (inline sincos) + V transpose, one launch -------
__global__ __launch_bounds__(256)
void rope_vt(ushort_t* __restrict__ q, ushort_t* __restrict__ ckv,
             const ushort_t* __restrict__ kv, ushort_t* __restrict__ vt){
  constexpr int NQ = Bc*Sc*Hc*32;
  constexpr int NK = Bc*Sc*32;
  constexpr int RB = (NQ + NK + 255) / 256;   // rope blocks
  __shared__ __attribute__((aligned(16))) ushort_t L[64][136];

  if ((int)blockIdx.x < RB) {
    int i = blockIdx.x*256 + threadIdx.x;
    int p, t; ushort_t* base;
    if (i < NQ) {
      p = i & 31;
      int h = (i >> 5) & (Hc-1);
      int bs = i >> 10;
      t = bs & (Sc-1);
      base = q + (size_t)bs*Hc*QHDc + h*QHDc + NOPEc + 2*p;
    } else {
      int k = i - NQ;
      if (k >= NK) return;
      p = k & 31;
      int bs = k >> 5;
      t = bs & (Sc-1);
      base = ckv + (size_t)bs*CKVS + 512 + 2*p;
    }
    float invf = exp2f(-(float)p * (13.287712379549449f / 32.f)); // 10000^(-p/32)
    float ang = (float)t * invf;
    float s, c;
    sincosf(ang, &s, &c);
    unsigned u = *(const unsigned*)base;
    float a = bf2f((ushort_t)(u & 0xFFFFu)), bb = bf2f((ushort_t)(u >> 16));
    unsigned o = (unsigned)f2bf(a*c - bb*s) | ((unsigned)f2bf(bb*c + a*s) << 16);
    *(unsigned*)base = o;
    return;
  }

  const int vb = (int)blockIdx.x - RB;
  const int s0 = (vb & 31) * 64;
  const int bh = vb >> 5;
  const int batch = bh >> 5, h = bh & 31;
  #pragma unroll
  for (int i = 0; i < 4; i++) {
    int chunk = i*256 + threadIdx.x;
    int r = chunk >> 4;
    int c = (chunk & 15) * 8;
    short8 v = *(const short8*)(kv + ((size_t)(batch*Sc + s0 + r)*Hc + h)*256 + 128 + c);
    *(short8*)&L[r][c] = v;
  }
  __syncthreads();
  #pragma unroll
  for (int i = 0; i < 4; i++) {
    int chunk = i*256 + threadIdx.x;
    int vd = chunk >> 3;
    int sc2 = (chunk & 7) * 8;
    short8 o;
    #pragma unroll
    for (int j=0;j<8;j++) o[j] = (short)L[sc2+j][vd];
    *(short8*)(vt + ((size_t)bh*VDc + vd)*Sc + s0 + sc2) = o;
  }
}

// ---------------- Flash attention (causal), 4 waves — PROVEN 211us version ----------
__global__ __launch_bounds__(256)
void attn_fwd(const ushort_t* __restrict__ qb, const ushort_t* __restrict__ kvb,
              const ushort_t* __restrict__ ckv, const ushort_t* __restrict__ vt,
              ushort_t* __restrict__ out)
{
  constexpr int KP = 200, VP = 40;
  __shared__ __attribute__((aligned(16))) ushort_t Ks[32*KP];
  __shared__ __attribute__((aligned(16))) ushort_t Vs[128*VP];
  __shared__ __attribute__((aligned(16))) ushort_t Ps[4][16*VP];
  const int tid = threadIdx.x, lane = tid & 63, w = tid >> 6;
  const int fr = lane & 15, kq = lane >> 4;
  const int y = (int)blockIdx.y;
  const int bh = blockIdx.x, batch = bh >> 5, h = bh & 31;

  const float scl = 0.07216878364870323f * 1.4426950408889634f;
  const float THR = 8.0f;

  const int ksr = tid >> 3, ksub = tid & 7;
  const int vvd = tid >> 1, vsub = tid & 1;

  const ushort_t* kbase  = kvb + ((size_t)batch*Sc + ksr)*((size_t)Hc*256) + (size_t)h*256;
  const ushort_t* pebase = ckv + (size_t)(batch*Sc + ksr)*CKVS + 512;
  const ushort_t* vbase  = vt + ((size_t)bh*VDc + vvd)*Sc;

  for (int seg = 0; seg < 2; ++seg) {
    const int qt = seg == 0 ? (31 - y) : y;
    const int q0 = qt * 64;

    const int qrow = q0 + w*16 + fr;
    const ushort_t* qptr = qb + ((size_t)(batch*Sc + qrow)*Hc + h)*QHDc;
    short8 qf[6];
    #pragma unroll
    for (int kk=0;kk<6;kk++) qf[kk] = *(const short8*)(qptr + kk*32 + kq*8);

    f32x4 acc_o[8];
    #pragma unroll
    for (int i=0;i<8;i++) acc_o[i] = (f32x4){0.f,0.f,0.f,0.f};
    float mrow[4]  = {-3e38f,-3e38f,-3e38f,-3e38f};
    float lpart[4] = {0.f,0.f,0.f,0.f};

    const int ktiles = q0/32 + 2;

    short8 kreg[3], vreg[2];
    {
      #pragma unroll
      for (int i=0;i<3;i++){
        int c = (ksub*3 + i)*8;
        kreg[i] = (c < 128) ? *(const short8*)(kbase + c)
                            : *(const short8*)(pebase + (c - 128));
      }
      #pragma unroll
      for (int i=0;i<2;i++) vreg[i] = *(const short8*)(vbase + (vsub*2+i)*8);
    }

    for (int kt = 0; kt < ktiles; kt++) {
      const int j0 = kt*32;
      #pragma unroll
      for (int i=0;i<3;i++) *(short8*)&Ks[ksr*KP + (ksub*3 + i)*8] = kreg[i];
      #pragma unroll
      for (int i=0;i<2;i++) *(short8*)&Vs[vvd*VP + (vsub*2 + i)*8] = vreg[i];
      __syncthreads();

      if (kt + 1 < ktiles) {
        const size_t roff = (size_t)(j0 + 32);
        #pragma unroll
        for (int i=0;i<3;i++){
          int c = (ksub*3 + i)*8;
          kreg[i] = (c < 128) ? *(const short8*)(kbase + roff*((size_t)Hc*256) + c)
                              : *(const short8*)(pebase + roff*CKVS + (c - 128));
        }
        #pragma unroll
        for (int i=0;i<2;i++) vreg[i] = *(const short8*)(vbase + roff + (vsub*2+i)*8);
      }

      f32x4 s0 = (f32x4){0.f,0.f,0.f,0.f}, s1 = (f32x4){0.f,0.f,0.f,0.f};
      __builtin_amdgcn_s_setprio(1);
      #pragma unroll
      for (int kk=0;kk<6;kk++){
        short8 b0 = *(const short8*)&Ks[fr*KP + kk*32 + kq*8];
        short8 b1 = *(const short8*)&Ks[(16+fr)*KP + kk*32 + kq*8];
        s0 = __builtin_amdgcn_mfma_f32_16x16x32_bf16(qf[kk], b0, s0, 0,0,0);
        s1 = __builtin_amdgcn_mfma_f32_16x16x32_bf16(qf[kk], b1, s1, 0,0,0);
      }
      __builtin_amdgcn_s_setprio(0);

      const bool full = (j0 + 31 <= q0 + w*16);
      float x0[4], x1[4];
      int okl = 1;
      #pragma unroll
      for (int j=0;j<4;j++){
        float a  = s0[j]*scl, c2 = s1[j]*scl;
        if (!full) {
          int qp = q0 + w*16 + kq*4 + j;
          if (j0 + fr      > qp) a  = -3e38f;
          if (j0 + 16 + fr > qp) c2 = -3e38f;
        }
        x0[j] = a; x1[j] = c2;
        okl &= (fmaxf(a, c2) <= mrow[j] + THR) ? 1 : 0;
      }
      if (!__all(okl)) {
        float tmax[4];
        #pragma unroll
        for (int j=0;j<4;j++) tmax[j] = fmaxf(x0[j], x1[j]);
        #pragma unroll
        for (int m=1;m<16;m<<=1){
          #pragma unroll
          for (int j=0;j<4;j++) tmax[j] = fmaxf(tmax[j], __shfl_xor(tmax[j], m, 64));
        }
        #pragma unroll
        for (int j=0;j<4;j++){
          float mn = fmaxf(mrow[j], tmax[j]);
          float corr = exp2f(mrow[j] - mn);
          mrow[j] = mn;
          lpart[j] *= corr;
          #pragma unroll
          for (int i=0;i<8;i++) acc_o[i][j] *= corr;
        }
      }
      float p0[4], p1[4];
      #pragma unroll
      for (int j=0;j<4;j++){
        p0[j] = exp2f(x0[j] - mrow[j]);
        p1[j] = exp2f(x1[j] - mrow[j]);
        lpart[j] += p0[j] + p1[j];
      }
      #pragma unroll
      for (int j=0;j<4;j++){
        unsigned pk;
        asm("v_cvt_pk_bf16_f32 %0, %1, %2" : "=v"(pk) : "v"(p0[j]), "v"(p1[j]));
        Ps[w][(kq*4+j)*VP + fr]      = (ushort_t)(pk & 0xFFFFu);
        Ps[w][(kq*4+j)*VP + 16 + fr] = (ushort_t)(pk >> 16);
      }
      short8 ap = *(const short8*)&Ps[w][fr*VP + kq*8];
      __builtin_amdgcn_s_setprio(1);
      #pragma unroll
      for (int v8=0; v8<8; v8++){
        short8 bv = *(const short8*)&Vs[(v8*16 + fr)*VP + kq*8];
        acc_o[v8] = __builtin_amdgcn_mfma_f32_16x16x32_bf16(ap, bv, acc_o[v8], 0,0,0);
      }
      __builtin_amdgcn_s_setprio(0);
      __syncthreads();
    }

    #pragma unroll
    for (int m=1;m<16;m<<=1){
      #pragma unroll
      for (int j=0;j<4;j++) lpart[j] += __shfl_xor(lpart[j], m, 64);
    }
    #pragma unroll
    for (int v8=0; v8<8; v8++){
      #pragma unroll
      for (int j=0;j<4;j++){
        int qg = q0 + w*16 + kq*4 + j;
        float o = acc_o[v8][j] / lpart[j];
        out[(size_t)(batch*Sc + qg)*(Hc*VDc) + h*VDc + v8*16 + fr] = f2bf(o);
      }
    }
  }
}

// ---------------- launcher ----------------
extern "C" void kernel_launch(void* const* d_in, const int* in_sizes, int n_in,
                              void* d_out, int out_size, void* d_ws, size_t ws_size,
                              hipStream_t stream) {
  (void)in_sizes; (void)n_in; (void)out_size; (void)ws_size;
  const float* hidden  = (const float*)d_in[0];
  const float* q_a_w   = (const float*)d_in[3];
  const float* q_a_ln  = (const float*)d_in[4];
  const float* q_b_w   = (const float*)d_in[5];
  const float* kv_a_w  = (const float*)d_in[6];
  const float* kv_a_ln = (const float*)d_in[7];
  const float* kv_b_w  = (const float*)d_in[8];
  const float* o_w     = (const float*)d_in[9];
  float* outp = (float*)d_out;

  char* ws = (char*)d_ws;
  size_t off = 0;
  auto alloc = [&](size_t n)->char*{ char* p = ws + off; off += (n + 255) & ~(size_t)255; return p; };
  ushort_t* hbf  = (ushort_t*)alloc((size_t)Bc*Sc*HIDc*2);      // hidden bf16; later o_w bf16
  ushort_t* wqa  = (ushort_t*)alloc((size_t)QLRc*HIDc*2);       // later aliased as aout
  ushort_t* wqb  = (ushort_t*)alloc((size_t)Hc*QHDc*QLRc*2);
  ushort_t* wkva = (ushort_t*)alloc((size_t)640*HIDc*2);        // 640 rows (576 data + pad)
  ushort_t* wkvb = (ushort_t*)alloc((size_t)Hc*256*KVLRc*2);
  ushort_t* qa   = (ushort_t*)alloc((size_t)Bc*Sc*QLRc*2);
  ushort_t* qbf  = (ushort_t*)alloc((size_t)Bc*Sc*Hc*QHDc*2);
  ushort_t* ckv  = (ushort_t*)alloc((size_t)Bc*Sc*CKVS*2);      // stride 640
  ushort_t* kvbf = (ushort_t*)alloc((size_t)Bc*Sc*Hc*256*2);
  ushort_t* vtb  = (ushort_t*)alloc((size_t)Bc*Hc*VDc*Sc*2);    // V transposed [bh][vd][s]
  ushort_t* aout = wqa;   // alias: wqa+wqb+wkva free before attn

  const int M = Bc*Sc; // 4096

  // one batched convert: hidden + q_a_w + q_b_w + kv_a_w + kv_b_w
  conv_all<<<2048,256,0,stream>>>(hidden, q_a_w, q_b_w, kv_a_w, kv_b_w,
                                  hbf, wqa, wqb, wkva, wkvb);
  // q_a = hidden @ q_a_w^T   [4096,1536,4096]
  gemm256x128<true><<<(M/256)*(QLRc/128),512,0,stream>>>(hbf, wqa, qa, M, QLRc, HIDc, HIDc);
  // ckv = hidden @ kv_a_w^T  (N padded to 640; cols 576..639 are garbage, never read)
  gemm256x128<true><<<(M/256)*(640/128),512,0,stream>>>(hbf, wkva, ckv, M, CKVS, HIDc, HIDc);
  // merged RMSNorm (qa + ckv)
  rmsnorm2<<<2*M,256,0,stream>>>(qa, q_a_ln, ckv, kv_a_ln);
  // hbf free now -> convert o_w into it
  f32_to_bf16<<<2048,256,0,stream>>>(o_w, hbf, (long long)HIDc*HIDc);
  // q = q_a @ q_b_w^T  [4096,6144,1536]
  gemm256x128<true><<<(M/256)*(Hc*QHDc/128),512,0,stream>>>(qa, wqb, qbf, M, Hc*QHDc, QLRc, QLRc);
  // kv = ckv_norm @ kv_b_w^T  [4096,8192,512], lda=640
  gemm256<true><<<(M/256)*(Hc*256/256),512,0,stream>>>(ckv, wkvb, kvbf, M, Hc*256, KVLRc, CKVS);
  // fused RoPE (inline sincos) + V transpose: one launch
  {
    constexpr int NQ = Bc*Sc*Hc*32, NK = Bc*Sc*32;
    constexpr int RB = (NQ + NK + 255) / 256;
    rope_vt<<<RB + (Sc/64)*(Bc*Hc),256,0,stream>>>(qbf, ckv, kvbf, vtb);
  }
  // attention (1024 uniform blocks, diagonal-paired)
  attn_fwd<<<dim3(Bc*Hc, 16),256,0,stream>>>(qbf, kvbf, ckv, vtb, aout);
  // out = attn @ o_w^T  [4096,4096,4096], f32 store — 4-phase interleaved pipeline
  gemm256p<false><<<(M/256)*(HIDc/256),512,0,stream>>>(aout, hbf, outp, M, HIDc, HIDc, HIDc);
}

// Round 14
// 667.892 us; speedup vs baseline: 1.0849x; 1.0001x over previous
//
#include <hip/hip_runtime.h>
#include <hip/hip_bf16.h>

typedef __attribute__((ext_vector_type(8))) short short8;
typedef __attribute__((ext_vector_type(4))) float f32x4;
typedef unsigned short ushort_t;

static constexpr int Bc = 2, Sc = 2048, HIDc = 4096, Hc = 32;
static constexpr int NOPEc = 128, ROPEc = 64, VDc = 128, QHDc = 192;
static constexpr int QLRc = 1536, KVLRc = 512;
static constexpr int CKVS = 640;   // padded ckv row stride (576 -> 640)

#define CDIV(a,b) (((a)+(b)-1)/(b))

__device__ __forceinline__ float bf2f(ushort_t u){
  union { unsigned u32; float f; } x; x.u32 = ((unsigned)u) << 16; return x.f;
}
__device__ __forceinline__ ushort_t f2bf(float f){
  union { float f; unsigned u32; } x; x.f = f;
  unsigned r = x.u32 + 0x7FFFu + ((x.u32 >> 16) & 1u);
  return (ushort_t)(r >> 16);
}
__device__ __forceinline__ void gload16(const void* g, void* l){
  __builtin_amdgcn_global_load_lds((const __attribute__((address_space(1))) void*)g,
                                   (__attribute__((address_space(3))) void*)l, 16, 0, 0);
}

// ---------------- f32 -> bf16 convert (vectorized, grid-stride) ----------------
__global__ __launch_bounds__(256)
void f32_to_bf16(const float* __restrict__ in, ushort_t* __restrict__ out, long long n){
  long long stride = (long long)gridDim.x * 256 * 4;
  for (long long i = ((long long)blockIdx.x*256 + threadIdx.x)*4; i < n; i += stride){
    float4 v = *(const float4*)(in + i);
    unsigned long long pk = (unsigned long long)f2bf(v.x)
                          | ((unsigned long long)f2bf(v.y) << 16)
                          | ((unsigned long long)f2bf(v.z) << 32)
                          | ((unsigned long long)f2bf(v.w) << 48);
    *(unsigned long long*)(out + i) = pk;
  }
}

// ---------------- batched 5-segment f32->bf16 (hidden + 4 weights) ----------------
__global__ __launch_bounds__(256)
void conv_all(const float* __restrict__ s0, const float* __restrict__ s1,
              const float* __restrict__ s2, const float* __restrict__ s3,
              const float* __restrict__ s4,
              ushort_t* __restrict__ d0, ushort_t* __restrict__ d1,
              ushort_t* __restrict__ d2, ushort_t* __restrict__ d3,
              ushort_t* __restrict__ d4){
  constexpr long long C0 = 16777216, C1 = 23068672, C2 = 32505856, C3 = 34865152, C4 = 39059456;
  long long stride = (long long)gridDim.x * 256 * 4;
  for (long long e = ((long long)blockIdx.x*256 + threadIdx.x)*4; e < C4; e += stride){
    const float* sp; ushort_t* dp; long long o;
    if      (e < C0){ sp = s0; dp = d0; o = e; }
    else if (e < C1){ sp = s1; dp = d1; o = e - C0; }
    else if (e < C2){ sp = s2; dp = d2; o = e - C1; }
    else if (e < C3){ sp = s3; dp = d3; o = e - C2; }
    else            { sp = s4; dp = d4; o = e - C3; }
    float4 v = *(const float4*)(sp + o);
    unsigned long long pk = (unsigned long long)f2bf(v.x)
                          | ((unsigned long long)f2bf(v.y) << 16)
                          | ((unsigned long long)f2bf(v.z) << 32)
                          | ((unsigned long long)f2bf(v.w) << 48);
    *(unsigned long long*)(dp + o) = pk;
  }
}

// ======== GEMM 256x256 tile, BK=64, 8 waves, dbuf LDS, swizzled, counted vmcnt ======
template<bool OUTBF>
__global__ __launch_bounds__(512, 2)
void gemm256(const ushort_t* __restrict__ A, const ushort_t* __restrict__ Bw,
             void* __restrict__ Cp, int M, int N, int K, int lda)
{
  __shared__ __attribute__((aligned(16))) ushort_t sm[65536];
  const int tid = threadIdx.x, lane = tid & 63, w = tid >> 6;
  const int wr = w >> 2, wc = w & 3;
  const int fr = lane & 15, kq = lane >> 4;

  const int nwg = gridDim.x, nx = N >> 8;
  const int bid = blockIdx.x;
  const int swz = (bid & 7) * (nwg >> 3) + (bid >> 3);
  const int m0 = (swz / nx) << 8, n0 = (swz % nx) << 8;

  f32x4 acc[8][4];
  #pragma unroll
  for (int m=0;m<8;m++)
    #pragma unroll
    for (int n=0;n<4;n++) acc[m][n] = (f32x4){0.f,0.f,0.f,0.f};

  const int srow = tid >> 3;
  const int gch  = (tid & 7) ^ (srow & 7);

  auto stage = [&](int c, int kt){
    const int k0 = kt << 6;
    ushort_t* Al = sm + c*16384;
    ushort_t* Bl = sm + 32768 + c*16384;
    const ushort_t* Ag = A  + (size_t)(m0 + srow)*lda + k0 + gch*8;
    const ushort_t* Bg = Bw + (size_t)(n0 + srow)*K   + k0 + gch*8;
    #pragma unroll
    for (int i=0;i<4;i++) gload16(Ag + (size_t)(i*64)*lda, Al + i*4096 + tid*8);
    #pragma unroll
    for (int i=0;i<4;i++) gload16(Bg + (size_t)(i*64)*K,   Bl + i*4096 + tid*8);
  };

  auto compute = [&](int c){
    const ushort_t* Al = sm + c*16384;
    const ushort_t* Bl = sm + 32768 + c*16384;
    const int s = fr & 7;
    short8 bfr[4][2];
    #pragma unroll
    for (int n=0;n<4;n++){
      const int row = wc*64 + n*16 + fr;
      bfr[n][0] = *(const short8*)(Bl + row*64 + ((kq    ) ^ s)*8);
      bfr[n][1] = *(const short8*)(Bl + row*64 + ((kq + 4) ^ s)*8);
    }
    #pragma unroll
    for (int m=0;m<8;m++){
      const int row = wr*128 + m*16 + fr;
      short8 a0 = *(const short8*)(Al + row*64 + ((kq    ) ^ s)*8);
      short8 a1 = *(const short8*)(Al + row*64 + ((kq + 4) ^ s)*8);
      #pragma unroll
      for (int n=0;n<4;n++){
        acc[m][n] = __builtin_amdgcn_mfma_f32_16x16x32_bf16(a0, bfr[n][0], acc[m][n], 0,0,0);
        acc[m][n] = __builtin_amdgcn_mfma_f32_16x16x32_bf16(a1, bfr[n][1], acc[m][n], 0,0,0);
      }
    }
  };

  const int nkt = K >> 6;
  stage(0, 0);
  stage(1, 1);
  asm volatile("s_waitcnt vmcnt(8)" ::: "memory");
  __builtin_amdgcn_s_barrier();
  __builtin_amdgcn_sched_barrier(0);

  int cur = 0;
  for (int kt = 0; kt < nkt; ++kt){
    compute(cur);
    __builtin_amdgcn_s_barrier();
    __builtin_amdgcn_sched_barrier(0);
    if (kt + 2 < nkt){
      stage(cur, kt + 2);
      asm volatile("s_waitcnt vmcnt(8)" ::: "memory");
    } else {
      asm volatile("s_waitcnt vmcnt(0)" ::: "memory");
    }
    __builtin_amdgcn_s_barrier();
    __builtin_amdgcn_sched_barrier(0);
    cur ^= 1;
  }

  const int rb = m0 + wr*128 + kq*4;
  const int cb = n0 + wc*64 + fr;
  #pragma unroll
  for (int m=0;m<8;m++)
    #pragma unroll
    for (int n=0;n<4;n++){
      const int col = cb + n*16;
      #pragma unroll
      for (int j=0;j<4;j++){
        const int row = rb + m*16 + j;
        float v = acc[m][n][j];
        if (OUTBF) ((ushort_t*)Cp)[(size_t)row*N + col] = f2bf(v);
        else       ((float*)  Cp)[(size_t)row*N + col] = v;
      }
    }
}

// ======== Fused q_a+ckv GEMM: C[4096,2176] = hidden @ [wqa;wkva]^T (contiguous B) ====
// 256x128 body; C-write routes col<1536 -> qa (stride 1536), else -> ckv (stride 640).
__global__ __launch_bounds__(512, 2)
void gemm_qackv(const ushort_t* __restrict__ A, const ushort_t* __restrict__ Bw,
                ushort_t* __restrict__ qa, ushort_t* __restrict__ ckv)
{
  constexpr int N = QLRc + CKVS;   // 2176
  constexpr int K = HIDc, lda = HIDc;
  __shared__ __attribute__((aligned(16))) ushort_t sm[49152];
  const int tid = threadIdx.x, lane = tid & 63, w = tid >> 6;
  const int wr = w >> 1, wc = w & 1;
  const int fr = lane & 15, kq = lane >> 4;

  const int nwg = gridDim.x, nx = N >> 7;   // 17
  const int bid = blockIdx.x;
  const int swz = (bid & 7) * (nwg >> 3) + (bid >> 3);
  const int m0 = (swz / nx) << 8, n0 = (swz % nx) << 7;

  f32x4 acc[4][4];
  #pragma unroll
  for (int m=0;m<4;m++)
    #pragma unroll
    for (int n=0;n<4;n++) acc[m][n] = (f32x4){0.f,0.f,0.f,0.f};

  const int srow = tid >> 3;
  const int gch  = (tid & 7) ^ (srow & 7);

  auto stage = [&](int c, int kt){
    const int k0 = kt << 6;
    ushort_t* Al = sm + c*16384;
    ushort_t* Bl = sm + 32768 + c*8192;
    const ushort_t* Ag = A  + (size_t)(m0 + srow)*lda + k0 + gch*8;
    const ushort_t* Bg = Bw + (size_t)(n0 + srow)*K   + k0 + gch*8;
    #pragma unroll
    for (int i=0;i<4;i++) gload16(Ag + (size_t)(i*64)*lda, Al + i*4096 + tid*8);
    #pragma unroll
    for (int i=0;i<2;i++) gload16(Bg + (size_t)(i*64)*K,   Bl + i*4096 + tid*8);
  };

  auto compute = [&](int c){
    const ushort_t* Al = sm + c*16384;
    const ushort_t* Bl = sm + 32768 + c*8192;
    const int s = fr & 7;
    short8 bfr[4][2];
    #pragma unroll
    for (int n=0;n<4;n++){
      const int row = wc*64 + n*16 + fr;
      bfr[n][0] = *(const short8*)(Bl + row*64 + ((kq    ) ^ s)*8);
      bfr[n][1] = *(const short8*)(Bl + row*64 + ((kq + 4) ^ s)*8);
    }
    #pragma unroll
    for (int m=0;m<4;m++){
      const int row = wr*64 + m*16 + fr;
      short8 a0 = *(const short8*)(Al + row*64 + ((kq    ) ^ s)*8);
      short8 a1 = *(const short8*)(Al + row*64 + ((kq + 4) ^ s)*8);
      #pragma unroll
      for (int n=0;n<4;n++){
        acc[m][n] = __builtin_amdgcn_mfma_f32_16x16x32_bf16(a0, bfr[n][0], acc[m][n], 0,0,0);
        acc[m][n] = __builtin_amdgcn_mfma_f32_16x16x32_bf16(a1, bfr[n][1], acc[m][n], 0,0,0);
      }
    }
  };

  const int nkt = K >> 6;
  stage(0, 0);
  stage(1, 1);
  asm volatile("s_waitcnt vmcnt(6)" ::: "memory");
  __builtin_amdgcn_s_barrier();
  __builtin_amdgcn_sched_barrier(0);

  int cur = 0;
  for (int kt = 0; kt < nkt; ++kt){
    compute(cur);
    __builtin_amdgcn_s_barrier();
    __builtin_amdgcn_sched_barrier(0);
    if (kt + 2 < nkt){
      stage(cur, kt + 2);
      asm volatile("s_waitcnt vmcnt(6)" ::: "memory");
    } else {
      asm volatile("s_waitcnt vmcnt(0)" ::: "memory");
    }
    __builtin_amdgcn_s_barrier();
    __builtin_amdgcn_sched_barrier(0);
    cur ^= 1;
  }

  const int rb = m0 + wr*64 + kq*4;
  const int cb = n0 + wc*64 + fr;
  #pragma unroll
  for (int m=0;m<4;m++)
    #pragma unroll
    for (int n=0;n<4;n++){
      const int col = cb + n*16;
      #pragma unroll
      for (int j=0;j<4;j++){
        const int row = rb + m*16 + j;
        const ushort_t v = f2bf(acc[m][n][j]);
        if (col < QLRc) qa [(size_t)row*QLRc + col]          = v;
        else            ckv[(size_t)row*CKVS + (col - QLRc)] = v;
      }
    }
}

// ======== Fused q_b + kv_b launch: blocks [0,768) q_b (256x128), [768,1280) kv_b (256x256)
__global__ __launch_bounds__(512, 2)
void gemm_qbkvb(const ushort_t* __restrict__ qa,  const ushort_t* __restrict__ wqb,
                ushort_t* __restrict__ qbf,
                const ushort_t* __restrict__ ckv, const ushort_t* __restrict__ wkvb,
                ushort_t* __restrict__ kvbf)
{
  __shared__ __attribute__((aligned(16))) ushort_t sm[65536];
  const int tid = threadIdx.x, lane = tid & 63, w = tid >> 6;
  const int fr = lane & 15, kq = lane >> 4;
  const int s = fr & 7;

  if ((int)blockIdx.x < 768) {
    // ---- q_b: C[4096,6144] = qa @ wqb^T, K=1536, 256x128 tile ----
    constexpr int N = Hc*QHDc, K = QLRc, lda = QLRc;
    const int wr = w >> 1, wc = w & 1;
    const int nwg = 768, nx = N >> 7;      // 48
    const int bid = blockIdx.x;
    const int swz = (bid & 7) * (nwg >> 3) + (bid >> 3);
    const int m0 = (swz / nx) << 8, n0 = (swz % nx) << 7;

    f32x4 acc[4][4];
    #pragma unroll
    for (int m=0;m<4;m++)
      #pragma unroll
      for (int n=0;n<4;n++) acc[m][n] = (f32x4){0.f,0.f,0.f,0.f};

    const int srow = tid >> 3;
    const int gch  = (tid & 7) ^ (srow & 7);

    auto stage = [&](int c, int kt){
      const int k0 = kt << 6;
      ushort_t* Al = sm + c*16384;
      ushort_t* Bl = sm + 32768 + c*8192;
      const ushort_t* Ag = qa  + (size_t)(m0 + srow)*lda + k0 + gch*8;
      const ushort_t* Bg = wqb + (size_t)(n0 + srow)*K   + k0 + gch*8;
      #pragma unroll
      for (int i=0;i<4;i++) gload16(Ag + (size_t)(i*64)*lda, Al + i*4096 + tid*8);
      #pragma unroll
      for (int i=0;i<2;i++) gload16(Bg + (size_t)(i*64)*K,   Bl + i*4096 + tid*8);
    };
    auto compute = [&](int c){
      const ushort_t* Al = sm + c*16384;
      const ushort_t* Bl = sm + 32768 + c*8192;
      short8 bfr[4][2];
      #pragma unroll
      for (int n=0;n<4;n++){
        const int row = wc*64 + n*16 + fr;
        bfr[n][0] = *(const short8*)(Bl + row*64 + ((kq    ) ^ s)*8);
        bfr[n][1] = *(const short8*)(Bl + row*64 + ((kq + 4) ^ s)*8);
      }
      #pragma unroll
      for (int m=0;m<4;m++){
        const int row = wr*64 + m*16 + fr;
        short8 a0 = *(const short8*)(Al + row*64 + ((kq    ) ^ s)*8);
        short8 a1 = *(const short8*)(Al + row*64 + ((kq + 4) ^ s)*8);
        #pragma unroll
        for (int n=0;n<4;n++){
          acc[m][n] = __builtin_amdgcn_mfma_f32_16x16x32_bf16(a0, bfr[n][0], acc[m][n], 0,0,0);
          acc[m][n] = __builtin_amdgcn_mfma_f32_16x16x32_bf16(a1, bfr[n][1], acc[m][n], 0,0,0);
        }
      }
    };

    const int nkt = K >> 6;
    stage(0, 0);
    stage(1, 1);
    asm volatile("s_waitcnt vmcnt(6)" ::: "memory");
    __builtin_amdgcn_s_barrier();
    __builtin_amdgcn_sched_barrier(0);

    int cur = 0;
    for (int kt = 0; kt < nkt; ++kt){
      compute(cur);
      __builtin_amdgcn_s_barrier();
      __builtin_amdgcn_sched_barrier(0);
      if (kt + 2 < nkt){
        stage(cur, kt + 2);
        asm volatile("s_waitcnt vmcnt(6)" ::: "memory");
      } else {
        asm volatile("s_waitcnt vmcnt(0)" ::: "memory");
      }
      __builtin_amdgcn_s_barrier();
      __builtin_amdgcn_sched_barrier(0);
      cur ^= 1;
    }

    const int rb = m0 + wr*64 + kq*4;
    const int cb = n0 + wc*64 + fr;
    #pragma unroll
    for (int m=0;m<4;m++)
      #pragma unroll
      for (int n=0;n<4;n++){
        const int col = cb + n*16;
        #pragma unroll
        for (int j=0;j<4;j++){
          const int row = rb + m*16 + j;
          qbf[(size_t)row*N + col] = f2bf(acc[m][n][j]);
        }
      }
  } else {
    // ---- kv_b: C[4096,8192] = ckv @ wkvb^T, K=512, lda=640, 256x256 tile ----
    constexpr int N = Hc*256, K = KVLRc, lda = CKVS;
    const int wr = w >> 2, wc = w & 3;
    const int nwg = 512, nx = N >> 8;      // 32
    const int bid = (int)blockIdx.x - 768;
    const int swz = (bid & 7) * (nwg >> 3) + (bid >> 3);
    const int m0 = (swz / nx) << 8, n0 = (swz % nx) << 8;

    f32x4 acc[8][4];
    #pragma unroll
    for (int m=0;m<8;m++)
      #pragma unroll
      for (int n=0;n<4;n++) acc[m][n] = (f32x4){0.f,0.f,0.f,0.f};

    const int srow = tid >> 3;
    const int gch  = (tid & 7) ^ (srow & 7);

    auto stage = [&](int c, int kt){
      const int k0 = kt << 6;
      ushort_t* Al = sm + c*16384;
      ushort_t* Bl = sm + 32768 + c*16384;
      const ushort_t* Ag = ckv  + (size_t)(m0 + srow)*lda + k0 + gch*8;
      const ushort_t* Bg = wkvb + (size_t)(n0 + srow)*K   + k0 + gch*8;
      #pragma unroll
      for (int i=0;i<4;i++) gload16(Ag + (size_t)(i*64)*lda, Al + i*4096 + tid*8);
      #pragma unroll
      for (int i=0;i<4;i++) gload16(Bg + (size_t)(i*64)*K,   Bl + i*4096 + tid*8);
    };
    auto compute = [&](int c){
      const ushort_t* Al = sm + c*16384;
      const ushort_t* Bl = sm + 32768 + c*16384;
      short8 bfr[4][2];
      #pragma unroll
      for (int n=0;n<4;n++){
        const int row = wc*64 + n*16 + fr;
        bfr[n][0] = *(const short8*)(Bl + row*64 + ((kq    ) ^ s)*8);
        bfr[n][1] = *(const short8*)(Bl + row*64 + ((kq + 4) ^ s)*8);
      }
      #pragma unroll
      for (int m=0;m<8;m++){
        const int row = wr*128 + m*16 + fr;
        short8 a0 = *(const short8*)(Al + row*64 + ((kq    ) ^ s)*8);
        short8 a1 = *(const short8*)(Al + row*64 + ((kq + 4) ^ s)*8);
        #pragma unroll
        for (int n=0;n<4;n++){
          acc[m][n] = __builtin_amdgcn_mfma_f32_16x16x32_bf16(a0, bfr[n][0], acc[m][n], 0,0,0);
          acc[m][n] = __builtin_amdgcn_mfma_f32_16x16x32_bf16(a1, bfr[n][1], acc[m][n], 0,0,0);
        }
      }
    };

    const int nkt = K >> 6;
    stage(0, 0);
    stage(1, 1);
    asm volatile("s_waitcnt vmcnt(8)" ::: "memory");
    __builtin_amdgcn_s_barrier();
    __builtin_amdgcn_sched_barrier(0);

    int cur = 0;
    for (int kt = 0; kt < nkt; ++kt){
      compute(cur);
      __builtin_amdgcn_s_barrier();
      __builtin_amdgcn_sched_barrier(0);
      if (kt + 2 < nkt){
        stage(cur, kt + 2);
        asm volatile("s_waitcnt vmcnt(8)" ::: "memory");
      } else {
        asm volatile("s_waitcnt vmcnt(0)" ::: "memory");
      }
      __builtin_amdgcn_s_barrier();
      __builtin_amdgcn_sched_barrier(0);
      cur ^= 1;
    }

    const int rb = m0 + wr*128 + kq*4;
    const int cb = n0 + wc*64 + fr;
    #pragma unroll
    for (int m=0;m<8;m++)
      #pragma unroll
      for (int n=0;n<4;n++){
        const int col = cb + n*16;
        #pragma unroll
        for (int j=0;j<4;j++){
          const int row = rb + m*16 + j;
          kvbf[(size_t)row*N + col] = f2bf(acc[m][n][j]);
        }
      }
  }
}

// ---------------- merged RMSNorm (qa rows then ckv rows) ----------------
__global__ __launch_bounds__(256)
void rmsnorm2(ushort_t* __restrict__ xa, const float* __restrict__ wa,
              ushort_t* __restrict__ xb, const float* __restrict__ wb){
  const int row = blockIdx.x;
  ushort_t* p; const float* w; int D;
  if (row < Bc*Sc){ p = xa + (size_t)row*QLRc; w = wa; D = QLRc; }
  else            { p = xb + (size_t)(row - Bc*Sc)*CKVS; w = wb; D = KVLRc; }
  float ss = 0.f;
  for (int c = threadIdx.x*8; c < D; c += 2048) {
    short8 v = *(const short8*)(p + c);
    #pragma unroll
    for (int j=0;j<8;j++){ float f = bf2f((ushort_t)v[j]); ss += f*f; }
  }
  #pragma unroll
  for (int m=1;m<64;m<<=1) ss += __shfl_xor(ss, m, 64);
  __shared__ float red[4];
  if ((threadIdx.x & 63)==0) red[threadIdx.x>>6] = ss;
  __syncthreads();
  float tot = red[0]+red[1]+red[2]+red[3];
  float inv = rsqrtf(tot/(float)D + 1e-6f);
  for (int c = threadIdx.x*8; c < D; c += 2048) {
    short8 v = *(const short8*)(p + c);
    short8 o;
    #pragma unroll
    for (int j=0;j<8;j++) o[j] = (short)f2bf(bf2f((ushort_t)v[j]) * inv * w[c+j]);
    *(short8*)(p + c) = o;
  }
}

// ------- fused RoPE (inline sincos) + V transpose, one launch -------
__global__ __launch_bounds__(256)
void rope_vt(ushort_t* __restrict__ q, ushort_t* __restrict__ ckv,
             const ushort_t* __restrict__ kv, ushort_t* __restrict__ vt){
  constexpr int NQ = Bc*Sc*Hc*32;
  constexpr int NK = Bc*Sc*32;
  constexpr int RB = (NQ + NK + 255) / 256;   // rope blocks
  __shared__ __attribute__((aligned(16))) ushort_t L[64][136];

  if ((int)blockIdx.x < RB) {
    int i = blockIdx.x*256 + threadIdx.x;
    int p, t; ushort_t* base;
    if (i < NQ) {
      p = i & 31;
      int h = (i >> 5) & (Hc-1);
      int bs = i >> 10;
      t = bs & (Sc-1);
      base = q + (size_t)bs*Hc*QHDc + h*QHDc + NOPEc + 2*p;
    } else {
      int k = i - NQ;
      if (k >= NK) return;
      p = k & 31;
      int bs = k >> 5;
      t = bs & (Sc-1);
      base = ckv + (size_t)bs*CKVS + 512 + 2*p;
    }
    float invf = exp2f(-(float)p * (13.287712379549449f / 32.f)); // 10000^(-p/32)
    float ang = (float)t * invf;
    float s, c;
    sincosf(ang, &s, &c);
    unsigned u = *(const unsigned*)base;
    float a = bf2f((ushort_t)(u & 0xFFFFu)), bb = bf2f((ushort_t)(u >> 16));
    unsigned o = (unsigned)f2bf(a*c - bb*s) | ((unsigned)f2bf(bb*c + a*s) << 16);
    *(unsigned*)base = o;
    return;
  }

  const int vb = (int)blockIdx.x - RB;
  const int s0 = (vb & 31) * 64;
  const int bh = vb >> 5;
  const int batch = bh >> 5, h = bh & 31;
  #pragma unroll
  for (int i = 0; i < 4; i++) {
    int chunk = i*256 + threadIdx.x;
    int r = chunk >> 4;
    int c = (chunk & 15) * 8;
    short8 v = *(const short8*)(kv + ((size_t)(batch*Sc + s0 + r)*Hc + h)*256 + 128 + c);
    *(short8*)&L[r][c] = v;
  }
  __syncthreads();
  #pragma unroll
  for (int i = 0; i < 4; i++) {
    int chunk = i*256 + threadIdx.x;
    int vd = chunk >> 3;
    int sc2 = (chunk & 7) * 8;
    short8 o;
    #pragma unroll
    for (int j=0;j<8;j++) o[j] = (short)L[sc2+j][vd];
    *(short8*)(vt + ((size_t)bh*VDc + vd)*Sc + s0 + sc2) = o;
  }
}

// ---------------- Flash attention (causal), 4 waves — PROVEN 211us version ----------
__global__ __launch_bounds__(256)
void attn_fwd(const ushort_t* __restrict__ qb, const ushort_t* __restrict__ kvb,
              const ushort_t* __restrict__ ckv, const ushort_t* __restrict__ vt,
              ushort_t* __restrict__ out)
{
  constexpr int KP = 200, VP = 40;
  __shared__ __attribute__((aligned(16))) ushort_t Ks[32*KP];
  __shared__ __attribute__((aligned(16))) ushort_t Vs[128*VP];
  __shared__ __attribute__((aligned(16))) ushort_t Ps[4][16*VP];
  const int tid = threadIdx.x, lane = tid & 63, w = tid >> 6;
  const int fr = lane & 15, kq = lane >> 4;
  const int y = (int)blockIdx.y;
  const int bh = blockIdx.x, batch = bh >> 5, h = bh & 31;

  const float scl = 0.07216878364870323f * 1.4426950408889634f;
  const float THR = 8.0f;

  const int ksr = tid >> 3, ksub = tid & 7;
  const int vvd = tid >> 1, vsub = tid & 1;

  const ushort_t* kbase  = kvb + ((size_t)batch*Sc + ksr)*((size_t)Hc*256) + (size_t)h*256;
  const ushort_t* pebase = ckv + (size_t)(batch*Sc + ksr)*CKVS + 512;
  const ushort_t* vbase  = vt + ((size_t)bh*VDc + vvd)*Sc;

  for (int seg = 0; seg < 2; ++seg) {
    const int qt = seg == 0 ? (31 - y) : y;
    const int q0 = qt * 64;

    const int qrow = q0 + w*16 + fr;
    const ushort_t* qptr = qb + ((size_t)(batch*Sc + qrow)*Hc + h)*QHDc;
    short8 qf[6];
    #pragma unroll
    for (int kk=0;kk<6;kk++) qf[kk] = *(const short8*)(qptr + kk*32 + kq*8);

    f32x4 acc_o[8];
    #pragma unroll
    for (int i=0;i<8;i++) acc_o[i] = (f32x4){0.f,0.f,0.f,0.f};
    float mrow[4]  = {-3e38f,-3e38f,-3e38f,-3e38f};
    float lpart[4] = {0.f,0.f,0.f,0.f};

    const int ktiles = q0/32 + 2;

    short8 kreg[3], vreg[2];
    {
      #pragma unroll
      for (int i=0;i<3;i++){
        int c = (ksub*3 + i)*8;
        kreg[i] = (c < 128) ? *(const short8*)(kbase + c)
                            : *(const short8*)(pebase + (c - 128));
      }
      #pragma unroll
      for (int i=0;i<2;i++) vreg[i] = *(const short8*)(vbase + (vsub*2+i)*8);
    }

    for (int kt = 0; kt < ktiles; kt++) {
      const int j0 = kt*32;
      #pragma unroll
      for (int i=0;i<3;i++) *(short8*)&Ks[ksr*KP + (ksub*3 + i)*8] = kreg[i];
      #pragma unroll
      for (int i=0;i<2;i++) *(short8*)&Vs[vvd*VP + (vsub*2 + i)*8] = vreg[i];
      __syncthreads();

      if (kt + 1 < ktiles) {
        const size_t roff = (size_t)(j0 + 32);
        #pragma unroll
        for (int i=0;i<3;i++){
          int c = (ksub*3 + i)*8;
          kreg[i] = (c < 128) ? *(const short8*)(kbase + roff*((size_t)Hc*256) + c)
                              : *(const short8*)(pebase + roff*CKVS + (c - 128));
        }
        #pragma unroll
        for (int i=0;i<2;i++) vreg[i] = *(const short8*)(vbase + roff + (vsub*2+i)*8);
      }

      f32x4 s0 = (f32x4){0.f,0.f,0.f,0.f}, s1 = (f32x4){0.f,0.f,0.f,0.f};
      __builtin_amdgcn_s_setprio(1);
      #pragma unroll
      for (int kk=0;kk<6;kk++){
        short8 b0 = *(const short8*)&Ks[fr*KP + kk*32 + kq*8];
        short8 b1 = *(const short8*)&Ks[(16+fr)*KP + kk*32 + kq*8];
        s0 = __builtin_amdgcn_mfma_f32_16x16x32_bf16(qf[kk], b0, s0, 0,0,0);
        s1 = __builtin_amdgcn_mfma_f32_16x16x32_bf16(qf[kk], b1, s1, 0,0,0);
      }
      __builtin_amdgcn_s_setprio(0);

      const bool full = (j0 + 31 <= q0 + w*16);
      float x0[4], x1[4];
      int okl = 1;
      #pragma unroll
      for (int j=0;j<4;j++){
        float a  = s0[j]*scl, c2 = s1[j]*scl;
        if (!full) {
          int qp = q0 + w*16 + kq*4 + j;
          if (j0 + fr      > qp) a  = -3e38f;
          if (j0 + 16 + fr > qp) c2 = -3e38f;
        }
        x0[j] = a; x1[j] = c2;
        okl &= (fmaxf(a, c2) <= mrow[j] + THR) ? 1 : 0;
      }
      if (!__all(okl)) {
        float tmax[4];
        #pragma unroll
        for (int j=0;j<4;j++) tmax[j] = fmaxf(x0[j], x1[j]);
        #pragma unroll
        for (int m=1;m<16;m<<=1){
          #pragma unroll
          for (int j=0;j<4;j++) tmax[j] = fmaxf(tmax[j], __shfl_xor(tmax[j], m, 64));
        }
        #pragma unroll
        for (int j=0;j<4;j++){
          float mn = fmaxf(mrow[j], tmax[j]);
          float corr = exp2f(mrow[j] - mn);
          mrow[j] = mn;
          lpart[j] *= corr;
          #pragma unroll
          for (int i=0;i<8;i++) acc_o[i][j] *= corr;
        }
      }
      float p0[4], p1[4];
      #pragma unroll
      for (int j=0;j<4;j++){
        p0[j] = exp2f(x0[j] - mrow[j]);
        p1[j] = exp2f(x1[j] - mrow[j]);
        lpart[j] += p0[j] + p1[j];
      }
      #pragma unroll
      for (int j=0;j<4;j++){
        unsigned pk;
        asm("v_cvt_pk_bf16_f32 %0, %1, %2" : "=v"(pk) : "v"(p0[j]), "v"(p1[j]));
        Ps[w][(kq*4+j)*VP + fr]      = (ushort_t)(pk & 0xFFFFu);
        Ps[w][(kq*4+j)*VP + 16 + fr] = (ushort_t)(pk >> 16);
      }
      short8 ap = *(const short8*)&Ps[w][fr*VP + kq*8];
      __builtin_amdgcn_s_setprio(1);
      #pragma unroll
      for (int v8=0; v8<8; v8++){
        short8 bv = *(const short8*)&Vs[(v8*16 + fr)*VP + kq*8];
        acc_o[v8] = __builtin_amdgcn_mfma_f32_16x16x32_bf16(ap, bv, acc_o[v8], 0,0,0);
      }
      __builtin_amdgcn_s_setprio(0);
      __syncthreads();
    }

    #pragma unroll
    for (int m=1;m<16;m<<=1){
      #pragma unroll
      for (int j=0;j<4;j++) lpart[j] += __shfl_xor(lpart[j], m, 64);
    }
    #pragma unroll
    for (int v8=0; v8<8; v8++){
      #pragma unroll
      for (int j=0;j<4;j++){
        int qg = q0 + w*16 + kq*4 + j;
        float o = acc_o[v8][j] / lpart[j];
        out[(size_t)(batch*Sc + qg)*(Hc*VDc) + h*VDc + v8*16 + fr] = f2bf(o);
      }
    }
  }
}

// ---------------- launcher ----------------
extern "C" void kernel_launch(void* const* d_in, const int* in_sizes, int n_in,
                              void* d_out, int out_size, void* d_ws, size_t ws_size,
                              hipStream_t stream) {
  (void)in_sizes; (void)n_in; (void)out_size; (void)ws_size;
  const float* hidden  = (const float*)d_in[0];
  const float* q_a_w   = (const float*)d_in[3];
  const float* q_a_ln  = (const float*)d_in[4];
  const float* q_b_w   = (const float*)d_in[5];
  const float* kv_a_w  = (const float*)d_in[6];
  const float* kv_a_ln = (const float*)d_in[7];
  const float* kv_b_w  = (const float*)d_in[8];
  const float* o_w     = (const float*)d_in[9];
  float* outp = (float*)d_out;

  char* ws = (char*)d_ws;
  size_t off = 0;
  auto alloc = [&](size_t n)->char*{ char* p = ws + off; off += (n + 255) & ~(size_t)255; return p; };
  ushort_t* hbf  = (ushort_t*)alloc((size_t)Bc*Sc*HIDc*2);      // hidden bf16; later o_w bf16
  // NOTE: wqa and wkva MUST be contiguous (fused q_a+ckv GEMM reads [wqa;wkva] as one B).
  ushort_t* wqa  = (ushort_t*)alloc((size_t)QLRc*HIDc*2);       // 12.58 MB (256-aligned size)
  ushort_t* wkva = (ushort_t*)alloc((size_t)640*HIDc*2);        // directly follows wqa
  ushort_t* wqb  = (ushort_t*)alloc((size_t)Hc*QHDc*QLRc*2);
  ushort_t* wkvb = (ushort_t*)alloc((size_t)Hc*256*KVLRc*2);
  ushort_t* qa   = (ushort_t*)alloc((size_t)Bc*Sc*QLRc*2);
  ushort_t* qbf  = (ushort_t*)alloc((size_t)Bc*Sc*Hc*QHDc*2);
  ushort_t* ckv  = (ushort_t*)alloc((size_t)Bc*Sc*CKVS*2);      // stride 640
  ushort_t* kvbf = (ushort_t*)alloc((size_t)Bc*Sc*Hc*256*2);
  ushort_t* vtb  = (ushort_t*)alloc((size_t)Bc*Hc*VDc*Sc*2);    // V transposed [bh][vd][s]
  ushort_t* aout = wqa;   // alias: wqa+wkva+wqb (36.7 MB) free before attn

  const int M = Bc*Sc; // 4096

  // one batched convert: hidden + q_a_w + q_b_w + kv_a_w + kv_b_w
  conv_all<<<2048,256,0,stream>>>(hidden, q_a_w, q_b_w, kv_a_w, kv_b_w,
                                  hbf, wqa, wqb, wkva, wkvb);
  // fused q_a + ckv GEMM: [4096, 2176, 4096], B = [wqa;wkva] contiguous, 272 blocks
  gemm_qackv<<<(M/256)*((QLRc+CKVS)/128),512,0,stream>>>(hbf, wqa, qa, ckv);
  // merged RMSNorm (qa + ckv)
  rmsnorm2<<<2*M,256,0,stream>>>(qa, q_a_ln, ckv, kv_a_ln);
  // hbf free now -> convert o_w into it
  f32_to_bf16<<<2048,256,0,stream>>>(o_w, hbf, (long long)HIDc*HIDc);
  // fused q_b + kv_b launch: 768 + 512 = 1280 blocks
  gemm_qbkvb<<<1280,512,0,stream>>>(qa, wqb, qbf, ckv, wkvb, kvbf);
  // fused RoPE (inline sincos) + V transpose: one launch
  {
    constexpr int NQ = Bc*Sc*Hc*32, NK = Bc*Sc*32;
    constexpr int RB = (NQ + NK + 255) / 256;
    rope_vt<<<RB + (Sc/64)*(Bc*Hc),256,0,stream>>>(qbf, ckv, kvbf, vtb);
  }
  // attention (1024 uniform blocks, diagonal-paired)
  attn_fwd<<<dim3(Bc*Hc, 16),256,0,stream>>>(qbf, kvbf, ckv, vtb, aout);
  // out = attn @ o_w^T  [4096,4096,4096], f32 store — 256^2 tiles
  gemm256<false><<<(M/256)*(HIDc/256),512,0,stream>>>(aout, hbf, outp, M, HIDc, HIDc, HIDc);
}

// Round 15
// 646.964 us; speedup vs baseline: 1.1200x; 1.0323x over previous
//
#include <hip/hip_runtime.h>
#include <hip/hip_bf16.h>

typedef __attribute__((ext_vector_type(8))) short short8;
typedef __attribute__((ext_vector_type(4))) float f32x4;
typedef unsigned short ushort_t;

static constexpr int Bc = 2, Sc = 2048, HIDc = 4096, Hc = 32;
static constexpr int NOPEc = 128, ROPEc = 64, VDc = 128, QHDc = 192;
static constexpr int QLRc = 1536, KVLRc = 512;
static constexpr int CKVS = 640;   // padded ckv row stride (576 -> 640)

#define CDIV(a,b) (((a)+(b)-1)/(b))

__device__ __forceinline__ float bf2f(ushort_t u){
  union { unsigned u32; float f; } x; x.u32 = ((unsigned)u) << 16; return x.f;
}
__device__ __forceinline__ ushort_t f2bf(float f){
  union { float f; unsigned u32; } x; x.f = f;
  unsigned r = x.u32 + 0x7FFFu + ((x.u32 >> 16) & 1u);
  return (ushort_t)(r >> 16);
}
__device__ __forceinline__ void gload16(const void* g, void* l){
  __builtin_amdgcn_global_load_lds((const __attribute__((address_space(1))) void*)g,
                                   (__attribute__((address_space(3))) void*)l, 16, 0, 0);
}

// ---------------- f32 -> bf16 convert (vectorized, grid-stride) ----------------
__global__ __launch_bounds__(256)
void f32_to_bf16(const float* __restrict__ in, ushort_t* __restrict__ out, long long n){
  long long stride = (long long)gridDim.x * 256 * 4;
  for (long long i = ((long long)blockIdx.x*256 + threadIdx.x)*4; i < n; i += stride){
    float4 v = *(const float4*)(in + i);
    unsigned long long pk = (unsigned long long)f2bf(v.x)
                          | ((unsigned long long)f2bf(v.y) << 16)
                          | ((unsigned long long)f2bf(v.z) << 32)
                          | ((unsigned long long)f2bf(v.w) << 48);
    *(unsigned long long*)(out + i) = pk;
  }
}

// ---------------- batched 5-segment f32->bf16 (hidden + 4 weights) ----------------
__global__ __launch_bounds__(256)
void conv_all(const float* __restrict__ s0, const float* __restrict__ s1,
              const float* __restrict__ s2, const float* __restrict__ s3,
              const float* __restrict__ s4,
              ushort_t* __restrict__ d0, ushort_t* __restrict__ d1,
              ushort_t* __restrict__ d2, ushort_t* __restrict__ d3,
              ushort_t* __restrict__ d4){
  constexpr long long C0 = 16777216, C1 = 23068672, C2 = 32505856, C3 = 34865152, C4 = 39059456;
  long long stride = (long long)gridDim.x * 256 * 4;
  for (long long e = ((long long)blockIdx.x*256 + threadIdx.x)*4; e < C4; e += stride){
    const float* sp; ushort_t* dp; long long o;
    if      (e < C0){ sp = s0; dp = d0; o = e; }
    else if (e < C1){ sp = s1; dp = d1; o = e - C0; }
    else if (e < C2){ sp = s2; dp = d2; o = e - C1; }
    else if (e < C3){ sp = s3; dp = d3; o = e - C2; }
    else            { sp = s4; dp = d4; o = e - C3; }
    float4 v = *(const float4*)(sp + o);
    unsigned long long pk = (unsigned long long)f2bf(v.x)
                          | ((unsigned long long)f2bf(v.y) << 16)
                          | ((unsigned long long)f2bf(v.z) << 32)
                          | ((unsigned long long)f2bf(v.w) << 48);
    *(unsigned long long*)(dp + o) = pk;
  }
}

// ======== GEMM 256x256 tile, BK=64, 8 waves, dbuf LDS, SINGLE-barrier K-loop ======
// Loop: compute(cur); vmcnt(0) [loads issued 1 full tile ago]; barrier [certifies
// both: all waves' next-tile loads landed AND all waves done reading cur];
// stage(cur, kt+2). One s_barrier per K-tile instead of two.
template<bool OUTBF>
__global__ __launch_bounds__(512, 2)
void gemm256(const ushort_t* __restrict__ A, const ushort_t* __restrict__ Bw,
             void* __restrict__ Cp, int M, int N, int K, int lda)
{
  __shared__ __attribute__((aligned(16))) ushort_t sm[65536];
  const int tid = threadIdx.x, lane = tid & 63, w = tid >> 6;
  const int wr = w >> 2, wc = w & 3;
  const int fr = lane & 15, kq = lane >> 4;

  const int nwg = gridDim.x, nx = N >> 8;
  const int bid = blockIdx.x;
  const int swz = (bid & 7) * (nwg >> 3) + (bid >> 3);
  const int m0 = (swz / nx) << 8, n0 = (swz % nx) << 8;

  f32x4 acc[8][4];
  #pragma unroll
  for (int m=0;m<8;m++)
    #pragma unroll
    for (int n=0;n<4;n++) acc[m][n] = (f32x4){0.f,0.f,0.f,0.f};

  const int srow = tid >> 3;
  const int gch  = (tid & 7) ^ (srow & 7);

  auto stage = [&](int c, int kt){
    const int k0 = kt << 6;
    ushort_t* Al = sm + c*16384;
    ushort_t* Bl = sm + 32768 + c*16384;
    const ushort_t* Ag = A  + (size_t)(m0 + srow)*lda + k0 + gch*8;
    const ushort_t* Bg = Bw + (size_t)(n0 + srow)*K   + k0 + gch*8;
    #pragma unroll
    for (int i=0;i<4;i++) gload16(Ag + (size_t)(i*64)*lda, Al + i*4096 + tid*8);
    #pragma unroll
    for (int i=0;i<4;i++) gload16(Bg + (size_t)(i*64)*K,   Bl + i*4096 + tid*8);
  };

  auto compute = [&](int c){
    const ushort_t* Al = sm + c*16384;
    const ushort_t* Bl = sm + 32768 + c*16384;
    const int s = fr & 7;
    short8 bfr[4][2];
    #pragma unroll
    for (int n=0;n<4;n++){
      const int row = wc*64 + n*16 + fr;
      bfr[n][0] = *(const short8*)(Bl + row*64 + ((kq    ) ^ s)*8);
      bfr[n][1] = *(const short8*)(Bl + row*64 + ((kq + 4) ^ s)*8);
    }
    #pragma unroll
    for (int m=0;m<8;m++){
      const int row = wr*128 + m*16 + fr;
      short8 a0 = *(const short8*)(Al + row*64 + ((kq    ) ^ s)*8);
      short8 a1 = *(const short8*)(Al + row*64 + ((kq + 4) ^ s)*8);
      #pragma unroll
      for (int n=0;n<4;n++){
        acc[m][n] = __builtin_amdgcn_mfma_f32_16x16x32_bf16(a0, bfr[n][0], acc[m][n], 0,0,0);
        acc[m][n] = __builtin_amdgcn_mfma_f32_16x16x32_bf16(a1, bfr[n][1], acc[m][n], 0,0,0);
      }
    }
  };

  const int nkt = K >> 6;
  stage(0, 0);
  stage(1, 1);
  asm volatile("s_waitcnt vmcnt(8)" ::: "memory");   // tile 0 resident, tile 1 in flight
  __builtin_amdgcn_s_barrier();
  __builtin_amdgcn_sched_barrier(0);

  int cur = 0;
  for (int kt = 0; kt < nkt; ++kt){
    compute(cur);
    asm volatile("s_waitcnt vmcnt(0)" ::: "memory"); // next tile's loads (1 tile old)
    __builtin_amdgcn_s_barrier();                    // collective: resident + read-done
    __builtin_amdgcn_sched_barrier(0);
    if (kt + 2 < nkt) stage(cur, kt + 2);            // overwrite fully-consumed buffer
    cur ^= 1;
  }

  const int rb = m0 + wr*128 + kq*4;
  const int cb = n0 + wc*64 + fr;
  #pragma unroll
  for (int m=0;m<8;m++)
    #pragma unroll
    for (int n=0;n<4;n++){
      const int col = cb + n*16;
      #pragma unroll
      for (int j=0;j<4;j++){
        const int row = rb + m*16 + j;
        float v = acc[m][n][j];
        if (OUTBF) ((ushort_t*)Cp)[(size_t)row*N + col] = f2bf(v);
        else       ((float*)  Cp)[(size_t)row*N + col] = v;
      }
    }
}

// ======== Fused q_a+ckv GEMM: C[4096,2176] = hidden @ [wqa;wkva]^T, single-barrier ===
__global__ __launch_bounds__(512, 2)
void gemm_qackv(const ushort_t* __restrict__ A, const ushort_t* __restrict__ Bw,
                ushort_t* __restrict__ qa, ushort_t* __restrict__ ckv)
{
  constexpr int N = QLRc + CKVS;   // 2176
  constexpr int K = HIDc, lda = HIDc;
  __shared__ __attribute__((aligned(16))) ushort_t sm[49152];
  const int tid = threadIdx.x, lane = tid & 63, w = tid >> 6;
  const int wr = w >> 1, wc = w & 1;
  const int fr = lane & 15, kq = lane >> 4;

  const int nwg = gridDim.x, nx = N >> 7;   // 17
  const int bid = blockIdx.x;
  const int swz = (bid & 7) * (nwg >> 3) + (bid >> 3);
  const int m0 = (swz / nx) << 8, n0 = (swz % nx) << 7;

  f32x4 acc[4][4];
  #pragma unroll
  for (int m=0;m<4;m++)
    #pragma unroll
    for (int n=0;n<4;n++) acc[m][n] = (f32x4){0.f,0.f,0.f,0.f};

  const int srow = tid >> 3;
  const int gch  = (tid & 7) ^ (srow & 7);

  auto stage = [&](int c, int kt){
    const int k0 = kt << 6;
    ushort_t* Al = sm + c*16384;
    ushort_t* Bl = sm + 32768 + c*8192;
    const ushort_t* Ag = A  + (size_t)(m0 + srow)*lda + k0 + gch*8;
    const ushort_t* Bg = Bw + (size_t)(n0 + srow)*K   + k0 + gch*8;
    #pragma unroll
    for (int i=0;i<4;i++) gload16(Ag + (size_t)(i*64)*lda, Al + i*4096 + tid*8);
    #pragma unroll
    for (int i=0;i<2;i++) gload16(Bg + (size_t)(i*64)*K,   Bl + i*4096 + tid*8);
  };

  auto compute = [&](int c){
    const ushort_t* Al = sm + c*16384;
    const ushort_t* Bl = sm + 32768 + c*8192;
    const int s = fr & 7;
    short8 bfr[4][2];
    #pragma unroll
    for (int n=0;n<4;n++){
      const int row = wc*64 + n*16 + fr;
      bfr[n][0] = *(const short8*)(Bl + row*64 + ((kq    ) ^ s)*8);
      bfr[n][1] = *(const short8*)(Bl + row*64 + ((kq + 4) ^ s)*8);
    }
    #pragma unroll
    for (int m=0;m<4;m++){
      const int row = wr*64 + m*16 + fr;
      short8 a0 = *(const short8*)(Al + row*64 + ((kq    ) ^ s)*8);
      short8 a1 = *(const short8*)(Al + row*64 + ((kq + 4) ^ s)*8);
      #pragma unroll
      for (int n=0;n<4;n++){
        acc[m][n] = __builtin_amdgcn_mfma_f32_16x16x32_bf16(a0, bfr[n][0], acc[m][n], 0,0,0);
        acc[m][n] = __builtin_amdgcn_mfma_f32_16x16x32_bf16(a1, bfr[n][1], acc[m][n], 0,0,0);
      }
    }
  };

  const int nkt = K >> 6;
  stage(0, 0);
  stage(1, 1);
  asm volatile("s_waitcnt vmcnt(6)" ::: "memory");
  __builtin_amdgcn_s_barrier();
  __builtin_amdgcn_sched_barrier(0);

  int cur = 0;
  for (int kt = 0; kt < nkt; ++kt){
    compute(cur);
    asm volatile("s_waitcnt vmcnt(0)" ::: "memory");
    __builtin_amdgcn_s_barrier();
    __builtin_amdgcn_sched_barrier(0);
    if (kt + 2 < nkt) stage(cur, kt + 2);
    cur ^= 1;
  }

  const int rb = m0 + wr*64 + kq*4;
  const int cb = n0 + wc*64 + fr;
  #pragma unroll
  for (int m=0;m<4;m++)
    #pragma unroll
    for (int n=0;n<4;n++){
      const int col = cb + n*16;
      #pragma unroll
      for (int j=0;j<4;j++){
        const int row = rb + m*16 + j;
        const ushort_t v = f2bf(acc[m][n][j]);
        if (col < QLRc) qa [(size_t)row*QLRc + col]          = v;
        else            ckv[(size_t)row*CKVS + (col - QLRc)] = v;
      }
    }
}

// ======== Fused q_b + kv_b launch, single-barrier K-loops ========
__global__ __launch_bounds__(512, 2)
void gemm_qbkvb(const ushort_t* __restrict__ qa,  const ushort_t* __restrict__ wqb,
                ushort_t* __restrict__ qbf,
                const ushort_t* __restrict__ ckv, const ushort_t* __restrict__ wkvb,
                ushort_t* __restrict__ kvbf)
{
  __shared__ __attribute__((aligned(16))) ushort_t sm[65536];
  const int tid = threadIdx.x, lane = tid & 63, w = tid >> 6;
  const int fr = lane & 15, kq = lane >> 4;
  const int s = fr & 7;

  if ((int)blockIdx.x < 768) {
    // ---- q_b: C[4096,6144] = qa @ wqb^T, K=1536, 256x128 tile ----
    constexpr int N = Hc*QHDc, K = QLRc, lda = QLRc;
    const int wr = w >> 1, wc = w & 1;
    const int nwg = 768, nx = N >> 7;      // 48
    const int bid = blockIdx.x;
    const int swz = (bid & 7) * (nwg >> 3) + (bid >> 3);
    const int m0 = (swz / nx) << 8, n0 = (swz % nx) << 7;

    f32x4 acc[4][4];
    #pragma unroll
    for (int m=0;m<4;m++)
      #pragma unroll
      for (int n=0;n<4;n++) acc[m][n] = (f32x4){0.f,0.f,0.f,0.f};

    const int srow = tid >> 3;
    const int gch  = (tid & 7) ^ (srow & 7);

    auto stage = [&](int c, int kt){
      const int k0 = kt << 6;
      ushort_t* Al = sm + c*16384;
      ushort_t* Bl = sm + 32768 + c*8192;
      const ushort_t* Ag = qa  + (size_t)(m0 + srow)*lda + k0 + gch*8;
      const ushort_t* Bg = wqb + (size_t)(n0 + srow)*K   + k0 + gch*8;
      #pragma unroll
      for (int i=0;i<4;i++) gload16(Ag + (size_t)(i*64)*lda, Al + i*4096 + tid*8);
      #pragma unroll
      for (int i=0;i<2;i++) gload16(Bg + (size_t)(i*64)*K,   Bl + i*4096 + tid*8);
    };
    auto compute = [&](int c){
      const ushort_t* Al = sm + c*16384;
      const ushort_t* Bl = sm + 32768 + c*8192;
      short8 bfr[4][2];
      #pragma unroll
      for (int n=0;n<4;n++){
        const int row = wc*64 + n*16 + fr;
        bfr[n][0] = *(const short8*)(Bl + row*64 + ((kq    ) ^ s)*8);
        bfr[n][1] = *(const short8*)(Bl + row*64 + ((kq + 4) ^ s)*8);
      }
      #pragma unroll
      for (int m=0;m<4;m++){
        const int row = wr*64 + m*16 + fr;
        short8 a0 = *(const short8*)(Al + row*64 + ((kq    ) ^ s)*8);
        short8 a1 = *(const short8*)(Al + row*64 + ((kq + 4) ^ s)*8);
        #pragma unroll
        for (int n=0;n<4;n++){
          acc[m][n] = __builtin_amdgcn_mfma_f32_16x16x32_bf16(a0, bfr[n][0], acc[m][n], 0,0,0);
          acc[m][n] = __builtin_amdgcn_mfma_f32_16x16x32_bf16(a1, bfr[n][1], acc[m][n], 0,0,0);
        }
      }
    };

    const int nkt = K >> 6;
    stage(0, 0);
    stage(1, 1);
    asm volatile("s_waitcnt vmcnt(6)" ::: "memory");
    __builtin_amdgcn_s_barrier();
    __builtin_amdgcn_sched_barrier(0);

    int cur = 0;
    for (int kt = 0; kt < nkt; ++kt){
      compute(cur);
      asm volatile("s_waitcnt vmcnt(0)" ::: "memory");
      __builtin_amdgcn_s_barrier();
      __builtin_amdgcn_sched_barrier(0);
      if (kt + 2 < nkt) stage(cur, kt + 2);
      cur ^= 1;
    }

    const int rb = m0 + wr*64 + kq*4;
    const int cb = n0 + wc*64 + fr;
    #pragma unroll
    for (int m=0;m<4;m++)
      #pragma unroll
      for (int n=0;n<4;n++){
        const int col = cb + n*16;
        #pragma unroll
        for (int j=0;j<4;j++){
          const int row = rb + m*16 + j;
          qbf[(size_t)row*N + col] = f2bf(acc[m][n][j]);
        }
      }
  } else {
    // ---- kv_b: C[4096,8192] = ckv @ wkvb^T, K=512, lda=640, 256x256 tile ----
    constexpr int N = Hc*256, K = KVLRc, lda = CKVS;
    const int wr = w >> 2, wc = w & 3;
    const int nwg = 512, nx = N >> 8;      // 32
    const int bid = (int)blockIdx.x - 768;
    const int swz = (bid & 7) * (nwg >> 3) + (bid >> 3);
    const int m0 = (swz / nx) << 8, n0 = (swz % nx) << 8;

    f32x4 acc[8][4];
    #pragma unroll
    for (int m=0;m<8;m++)
      #pragma unroll
      for (int n=0;n<4;n++) acc[m][n] = (f32x4){0.f,0.f,0.f,0.f};

    const int srow = tid >> 3;
    const int gch  = (tid & 7) ^ (srow & 7);

    auto stage = [&](int c, int kt){
      const int k0 = kt << 6;
      ushort_t* Al = sm + c*16384;
      ushort_t* Bl = sm + 32768 + c*16384;
      const ushort_t* Ag = ckv  + (size_t)(m0 + srow)*lda + k0 + gch*8;
      const ushort_t* Bg = wkvb + (size_t)(n0 + srow)*K   + k0 + gch*8;
      #pragma unroll
      for (int i=0;i<4;i++) gload16(Ag + (size_t)(i*64)*lda, Al + i*4096 + tid*8);
      #pragma unroll
      for (int i=0;i<4;i++) gload16(Bg + (size_t)(i*64)*K,   Bl + i*4096 + tid*8);
    };
    auto compute = [&](int c){
      const ushort_t* Al = sm + c*16384;
      const ushort_t* Bl = sm + 32768 + c*16384;
      short8 bfr[4][2];
      #pragma unroll
      for (int n=0;n<4;n++){
        const int row = wc*64 + n*16 + fr;
        bfr[n][0] = *(const short8*)(Bl + row*64 + ((kq    ) ^ s)*8);
        bfr[n][1] = *(const short8*)(Bl + row*64 + ((kq + 4) ^ s)*8);
      }
      #pragma unroll
      for (int m=0;m<8;m++){
        const int row = wr*128 + m*16 + fr;
        short8 a0 = *(const short8*)(Al + row*64 + ((kq    ) ^ s)*8);
        short8 a1 = *(const short8*)(Al + row*64 + ((kq + 4) ^ s)*8);
        #pragma unroll
        for (int n=0;n<4;n++){
          acc[m][n] = __builtin_amdgcn_mfma_f32_16x16x32_bf16(a0, bfr[n][0], acc[m][n], 0,0,0);
          acc[m][n] = __builtin_amdgcn_mfma_f32_16x16x32_bf16(a1, bfr[n][1], acc[m][n], 0,0,0);
        }
      }
    };

    const int nkt = K >> 6;
    stage(0, 0);
    stage(1, 1);
    asm volatile("s_waitcnt vmcnt(8)" ::: "memory");
    __builtin_amdgcn_s_barrier();
    __builtin_amdgcn_sched_barrier(0);

    int cur = 0;
    for (int kt = 0; kt < nkt; ++kt){
      compute(cur);
      asm volatile("s_waitcnt vmcnt(0)" ::: "memory");
      __builtin_amdgcn_s_barrier();
      __builtin_amdgcn_sched_barrier(0);
      if (kt + 2 < nkt) stage(cur, kt + 2);
      cur ^= 1;
    }

    const int rb = m0 + wr*128 + kq*4;
    const int cb = n0 + wc*64 + fr;
    #pragma unroll
    for (int m=0;m<8;m++)
      #pragma unroll
      for (int n=0;n<4;n++){
        const int col = cb + n*16;
        #pragma unroll
        for (int j=0;j<4;j++){
          const int row = rb + m*16 + j;
          kvbf[(size_t)row*N + col] = f2bf(acc[m][n][j]);
        }
      }
  }
}

// ---------------- merged RMSNorm (qa rows then ckv rows) ----------------
__global__ __launch_bounds__(256)
void rmsnorm2(ushort_t* __restrict__ xa, const float* __restrict__ wa,
              ushort_t* __restrict__ xb, const float* __restrict__ wb){
  const int row = blockIdx.x;
  ushort_t* p; const float* w; int D;
  if (row < Bc*Sc){ p = xa + (size_t)row*QLRc; w = wa; D = QLRc; }
  else            { p = xb + (size_t)(row - Bc*Sc)*CKVS; w = wb; D = KVLRc; }
  float ss = 0.f;
  for (int c = threadIdx.x*8; c < D; c += 2048) {
    short8 v = *(const short8*)(p + c);
    #pragma unroll
    for (int j=0;j<8;j++){ float f = bf2f((ushort_t)v[j]); ss += f*f; }
  }
  #pragma unroll
  for (int m=1;m<64;m<<=1) ss += __shfl_xor(ss, m, 64);
  __shared__ float red[4];
  if ((threadIdx.x & 63)==0) red[threadIdx.x>>6] = ss;
  __syncthreads();
  float tot = red[0]+red[1]+red[2]+red[3];
  float inv = rsqrtf(tot/(float)D + 1e-6f);
  for (int c = threadIdx.x*8; c < D; c += 2048) {
    short8 v = *(const short8*)(p + c);
    short8 o;
    #pragma unroll
    for (int j=0;j<8;j++) o[j] = (short)f2bf(bf2f((ushort_t)v[j]) * inv * w[c+j]);
    *(short8*)(p + c) = o;
  }
}

// ------- fused RoPE (inline sincos) + V transpose, one launch -------
__global__ __launch_bounds__(256)
void rope_vt(ushort_t* __restrict__ q, ushort_t* __restrict__ ckv,
             const ushort_t* __restrict__ kv, ushort_t* __restrict__ vt){
  constexpr int NQ = Bc*Sc*Hc*32;
  constexpr int NK = Bc*Sc*32;
  constexpr int RB = (NQ + NK + 255) / 256;   // rope blocks
  __shared__ __attribute__((aligned(16))) ushort_t L[64][136];

  if ((int)blockIdx.x < RB) {
    int i = blockIdx.x*256 + threadIdx.x;
    int p, t; ushort_t* base;
    if (i < NQ) {
      p = i & 31;
      int h = (i >> 5) & (Hc-1);
      int bs = i >> 10;
      t = bs & (Sc-1);
      base = q + (size_t)bs*Hc*QHDc + h*QHDc + NOPEc + 2*p;
    } else {
      int k = i - NQ;
      if (k >= NK) return;
      p = k & 31;
      int bs = k >> 5;
      t = bs & (Sc-1);
      base = ckv + (size_t)bs*CKVS + 512 + 2*p;
    }
    float invf = exp2f(-(float)p * (13.287712379549449f / 32.f)); // 10000^(-p/32)
    float ang = (float)t * invf;
    float s, c;
    sincosf(ang, &s, &c);
    unsigned u = *(const unsigned*)base;
    float a = bf2f((ushort_t)(u & 0xFFFFu)), bb = bf2f((ushort_t)(u >> 16));
    unsigned o = (unsigned)f2bf(a*c - bb*s) | ((unsigned)f2bf(bb*c + a*s) << 16);
    *(unsigned*)base = o;
    return;
  }

  const int vb = (int)blockIdx.x - RB;
  const int s0 = (vb & 31) * 64;
  const int bh = vb >> 5;
  const int batch = bh >> 5, h = bh & 31;
  #pragma unroll
  for (int i = 0; i < 4; i++) {
    int chunk = i*256 + threadIdx.x;
    int r = chunk >> 4;
    int c = (chunk & 15) * 8;
    short8 v = *(const short8*)(kv + ((size_t)(batch*Sc + s0 + r)*Hc + h)*256 + 128 + c);
    *(short8*)&L[r][c] = v;
  }
  __syncthreads();
  #pragma unroll
  for (int i = 0; i < 4; i++) {
    int chunk = i*256 + threadIdx.x;
    int vd = chunk >> 3;
    int sc2 = (chunk & 7) * 8;
    short8 o;
    #pragma unroll
    for (int j=0;j<8;j++) o[j] = (short)L[sc2+j][vd];
    *(short8*)(vt + ((size_t)bh*VDc + vd)*Sc + s0 + sc2) = o;
  }
}

// ---------------- Flash attention (causal), 4 waves — PROVEN 211us version ----------
__global__ __launch_bounds__(256)
void attn_fwd(const ushort_t* __restrict__ qb, const ushort_t* __restrict__ kvb,
              const ushort_t* __restrict__ ckv, const ushort_t* __restrict__ vt,
              ushort_t* __restrict__ out)
{
  constexpr int KP = 200, VP = 40;
  __shared__ __attribute__((aligned(16))) ushort_t Ks[32*KP];
  __shared__ __attribute__((aligned(16))) ushort_t Vs[128*VP];
  __shared__ __attribute__((aligned(16))) ushort_t Ps[4][16*VP];
  const int tid = threadIdx.x, lane = tid & 63, w = tid >> 6;
  const int fr = lane & 15, kq = lane >> 4;
  const int y = (int)blockIdx.y;
  const int bh = blockIdx.x, batch = bh >> 5, h = bh & 31;

  const float scl = 0.07216878364870323f * 1.4426950408889634f;
  const float THR = 8.0f;

  const int ksr = tid >> 3, ksub = tid & 7;
  const int vvd = tid >> 1, vsub = tid & 1;

  const ushort_t* kbase  = kvb + ((size_t)batch*Sc + ksr)*((size_t)Hc*256) + (size_t)h*256;
  const ushort_t* pebase = ckv + (size_t)(batch*Sc + ksr)*CKVS + 512;
  const ushort_t* vbase  = vt + ((size_t)bh*VDc + vvd)*Sc;

  for (int seg = 0; seg < 2; ++seg) {
    const int qt = seg == 0 ? (31 - y) : y;
    const int q0 = qt * 64;

    const int qrow = q0 + w*16 + fr;
    const ushort_t* qptr = qb + ((size_t)(batch*Sc + qrow)*Hc + h)*QHDc;
    short8 qf[6];
    #pragma unroll
    for (int kk=0;kk<6;kk++) qf[kk] = *(const short8*)(qptr + kk*32 + kq*8);

    f32x4 acc_o[8];
    #pragma unroll
    for (int i=0;i<8;i++) acc_o[i] = (f32x4){0.f,0.f,0.f,0.f};
    float mrow[4]  = {-3e38f,-3e38f,-3e38f,-3e38f};
    float lpart[4] = {0.f,0.f,0.f,0.f};

    const int ktiles = q0/32 + 2;

    short8 kreg[3], vreg[2];
    {
      #pragma unroll
      for (int i=0;i<3;i++){
        int c = (ksub*3 + i)*8;
        kreg[i] = (c < 128) ? *(const short8*)(kbase + c)
                            : *(const short8*)(pebase + (c - 128));
      }
      #pragma unroll
      for (int i=0;i<2;i++) vreg[i] = *(const short8*)(vbase + (vsub*2+i)*8);
    }

    for (int kt = 0; kt < ktiles; kt++) {
      const int j0 = kt*32;
      #pragma unroll
      for (int i=0;i<3;i++) *(short8*)&Ks[ksr*KP + (ksub*3 + i)*8] = kreg[i];
      #pragma unroll
      for (int i=0;i<2;i++) *(short8*)&Vs[vvd*VP + (vsub*2 + i)*8] = vreg[i];
      __syncthreads();

      if (kt + 1 < ktiles) {
        const size_t roff = (size_t)(j0 + 32);
        #pragma unroll
        for (int i=0;i<3;i++){
          int c = (ksub*3 + i)*8;
          kreg[i] = (c < 128) ? *(const short8*)(kbase + roff*((size_t)Hc*256) + c)
                              : *(const short8*)(pebase + roff*CKVS + (c - 128));
        }
        #pragma unroll
        for (int i=0;i<2;i++) vreg[i] = *(const short8*)(vbase + roff + (vsub*2+i)*8);
      }

      f32x4 s0 = (f32x4){0.f,0.f,0.f,0.f}, s1 = (f32x4){0.f,0.f,0.f,0.f};
      __builtin_amdgcn_s_setprio(1);
      #pragma unroll
      for (int kk=0;kk<6;kk++){
        short8 b0 = *(const short8*)&Ks[fr*KP + kk*32 + kq*8];
        short8 b1 = *(const short8*)&Ks[(16+fr)*KP + kk*32 + kq*8];
        s0 = __builtin_amdgcn_mfma_f32_16x16x32_bf16(qf[kk], b0, s0, 0,0,0);
        s1 = __builtin_amdgcn_mfma_f32_16x16x32_bf16(qf[kk], b1, s1, 0,0,0);
      }
      __builtin_amdgcn_s_setprio(0);

      const bool full = (j0 + 31 <= q0 + w*16);
      float x0[4], x1[4];
      int okl = 1;
      #pragma unroll
      for (int j=0;j<4;j++){
        float a  = s0[j]*scl, c2 = s1[j]*scl;
        if (!full) {
          int qp = q0 + w*16 + kq*4 + j;
          if (j0 + fr      > qp) a  = -3e38f;
          if (j0 + 16 + fr > qp) c2 = -3e38f;
        }
        x0[j] = a; x1[j] = c2;
        okl &= (fmaxf(a, c2) <= mrow[j] + THR) ? 1 : 0;
      }
      if (!__all(okl)) {
        float tmax[4];
        #pragma unroll
        for (int j=0;j<4;j++) tmax[j] = fmaxf(x0[j], x1[j]);
        #pragma unroll
        for (int m=1;m<16;m<<=1){
          #pragma unroll
          for (int j=0;j<4;j++) tmax[j] = fmaxf(tmax[j], __shfl_xor(tmax[j], m, 64));
        }
        #pragma unroll
        for (int j=0;j<4;j++){
          float mn = fmaxf(mrow[j], tmax[j]);
          float corr = exp2f(mrow[j] - mn);
          mrow[j] = mn;
          lpart[j] *= corr;
          #pragma unroll
          for (int i=0;i<8;i++) acc_o[i][j] *= corr;
        }
      }
      float p0[4], p1[4];
      #pragma unroll
      for (int j=0;j<4;j++){
        p0[j] = exp2f(x0[j] - mrow[j]);
        p1[j] = exp2f(x1[j] - mrow[j]);
        lpart[j] += p0[j] + p1[j];
      }
      #pragma unroll
      for (int j=0;j<4;j++){
        unsigned pk;
        asm("v_cvt_pk_bf16_f32 %0, %1, %2" : "=v"(pk) : "v"(p0[j]), "v"(p1[j]));
        Ps[w][(kq*4+j)*VP + fr]      = (ushort_t)(pk & 0xFFFFu);
        Ps[w][(kq*4+j)*VP + 16 + fr] = (ushort_t)(pk >> 16);
      }
      short8 ap = *(const short8*)&Ps[w][fr*VP + kq*8];
      __builtin_amdgcn_s_setprio(1);
      #pragma unroll
      for (int v8=0; v8<8; v8++){
        short8 bv = *(const short8*)&Vs[(v8*16 + fr)*VP + kq*8];
        acc_o[v8] = __builtin_amdgcn_mfma_f32_16x16x32_bf16(ap, bv, acc_o[v8], 0,0,0);
      }
      __builtin_amdgcn_s_setprio(0);
      __syncthreads();
    }

    #pragma unroll
    for (int m=1;m<16;m<<=1){
      #pragma unroll
      for (int j=0;j<4;j++) lpart[j] += __shfl_xor(lpart[j], m, 64);
    }
    #pragma unroll
    for (int v8=0; v8<8; v8++){
      #pragma unroll
      for (int j=0;j<4;j++){
        int qg = q0 + w*16 + kq*4 + j;
        float o = acc_o[v8][j] / lpart[j];
        out[(size_t)(batch*Sc + qg)*(Hc*VDc) + h*VDc + v8*16 + fr] = f2bf(o);
      }
    }
  }
}

// ---------------- launcher ----------------
extern "C" void kernel_launch(void* const* d_in, const int* in_sizes, int n_in,
                              void* d_out, int out_size, void* d_ws, size_t ws_size,
                              hipStream_t stream) {
  (void)in_sizes; (void)n_in; (void)out_size; (void)ws_size;
  const float* hidden  = (const float*)d_in[0];
  const float* q_a_w   = (const float*)d_in[3];
  const float* q_a_ln  = (const float*)d_in[4];
  const float* q_b_w   = (const float*)d_in[5];
  const float* kv_a_w  = (const float*)d_in[6];
  const float* kv_a_ln = (const float*)d_in[7];
  const float* kv_b_w  = (const float*)d_in[8];
  const float* o_w     = (const float*)d_in[9];
  float* outp = (float*)d_out;

  char* ws = (char*)d_ws;
  size_t off = 0;
  auto alloc = [&](size_t n)->char*{ char* p = ws + off; off += (n + 255) & ~(size_t)255; return p; };
  ushort_t* hbf  = (ushort_t*)alloc((size_t)Bc*Sc*HIDc*2);      // hidden bf16; later o_w bf16
  // NOTE: wqa and wkva MUST be contiguous (fused q_a+ckv GEMM reads [wqa;wkva] as one B).
  ushort_t* wqa  = (ushort_t*)alloc((size_t)QLRc*HIDc*2);
  ushort_t* wkva = (ushort_t*)alloc((size_t)640*HIDc*2);        // directly follows wqa
  ushort_t* wqb  = (ushort_t*)alloc((size_t)Hc*QHDc*QLRc*2);
  ushort_t* wkvb = (ushort_t*)alloc((size_t)Hc*256*KVLRc*2);
  ushort_t* qa   = (ushort_t*)alloc((size_t)Bc*Sc*QLRc*2);
  ushort_t* qbf  = (ushort_t*)alloc((size_t)Bc*Sc*Hc*QHDc*2);
  ushort_t* ckv  = (ushort_t*)alloc((size_t)Bc*Sc*CKVS*2);      // stride 640
  ushort_t* kvbf = (ushort_t*)alloc((size_t)Bc*Sc*Hc*256*2);
  ushort_t* vtb  = (ushort_t*)alloc((size_t)Bc*Hc*VDc*Sc*2);    // V transposed [bh][vd][s]
  ushort_t* aout = wqa;   // alias: wqa+wkva+wqb free before attn

  const int M = Bc*Sc; // 4096

  // one batched convert: hidden + q_a_w + q_b_w + kv_a_w + kv_b_w
  conv_all<<<2048,256,0,stream>>>(hidden, q_a_w, q_b_w, kv_a_w, kv_b_w,
                                  hbf, wqa, wqb, wkva, wkvb);
  // fused q_a + ckv GEMM: [4096, 2176, 4096]
  gemm_qackv<<<(M/256)*((QLRc+CKVS)/128),512,0,stream>>>(hbf, wqa, qa, ckv);
  // merged RMSNorm (qa + ckv)
  rmsnorm2<<<2*M,256,0,stream>>>(qa, q_a_ln, ckv, kv_a_ln);
  // hbf free now -> convert o_w into it
  f32_to_bf16<<<2048,256,0,stream>>>(o_w, hbf, (long long)HIDc*HIDc);
  // fused q_b + kv_b launch: 768 + 512 = 1280 blocks
  gemm_qbkvb<<<1280,512,0,stream>>>(qa, wqb, qbf, ckv, wkvb, kvbf);
  // fused RoPE (inline sincos) + V transpose: one launch
  {
    constexpr int NQ = Bc*Sc*Hc*32, NK = Bc*Sc*32;
    constexpr int RB = (NQ + NK + 255) / 256;
    rope_vt<<<RB + (Sc/64)*(Bc*Hc),256,0,stream>>>(qbf, ckv, kvbf, vtb);
  }
  // attention (1024 uniform blocks, diagonal-paired)
  attn_fwd<<<dim3(Bc*Hc, 16),256,0,stream>>>(qbf, kvbf, ckv, vtb, aout);
  // out = attn @ o_w^T  [4096,4096,4096], f32 store — 256^2 tiles
  gemm256<false><<<(M/256)*(HIDc/256),512,0,stream>>>(aout, hbf, outp, M, HIDc, HIDc, HIDc);
}

// Round 16
// 644.655 us; speedup vs baseline: 1.1240x; 1.0036x over previous
//
#include <hip/hip_runtime.h>
#include <hip/hip_bf16.h>

typedef __attribute__((ext_vector_type(8))) short short8;
typedef __attribute__((ext_vector_type(4))) float f32x4;
typedef unsigned short ushort_t;

static constexpr int Bc = 2, Sc = 2048, HIDc = 4096, Hc = 32;
static constexpr int NOPEc = 128, ROPEc = 64, VDc = 128, QHDc = 192;
static constexpr int QLRc = 1536, KVLRc = 512;
static constexpr int CKVS = 640;   // padded ckv row stride (576 -> 640)

#define CDIV(a,b) (((a)+(b)-1)/(b))

__device__ __forceinline__ float bf2f(ushort_t u){
  union { unsigned u32; float f; } x; x.u32 = ((unsigned)u) << 16; return x.f;
}
__device__ __forceinline__ ushort_t f2bf(float f){
  union { float f; unsigned u32; } x; x.f = f;
  unsigned r = x.u32 + 0x7FFFu + ((x.u32 >> 16) & 1u);
  return (ushort_t)(r >> 16);
}
__device__ __forceinline__ void gload16(const void* g, void* l){
  __builtin_amdgcn_global_load_lds((const __attribute__((address_space(1))) void*)g,
                                   (__attribute__((address_space(3))) void*)l, 16, 0, 0);
}
// light barrier: LDS-ops-complete + raw s_barrier (leaves vmem loads in flight)
__device__ __forceinline__ void barrier_lds(){
  asm volatile("s_waitcnt lgkmcnt(0)" ::: "memory");
  __builtin_amdgcn_sched_barrier(0);
  __builtin_amdgcn_s_barrier();
  __builtin_amdgcn_sched_barrier(0);
}

// ---------------- f32 -> bf16 convert (vectorized, grid-stride) ----------------
__global__ __launch_bounds__(256)
void f32_to_bf16(const float* __restrict__ in, ushort_t* __restrict__ out, long long n){
  long long stride = (long long)gridDim.x * 256 * 4;
  for (long long i = ((long long)blockIdx.x*256 + threadIdx.x)*4; i < n; i += stride){
    float4 v = *(const float4*)(in + i);
    unsigned long long pk = (unsigned long long)f2bf(v.x)
                          | ((unsigned long long)f2bf(v.y) << 16)
                          | ((unsigned long long)f2bf(v.z) << 32)
                          | ((unsigned long long)f2bf(v.w) << 48);
    *(unsigned long long*)(out + i) = pk;
  }
}

// ---------------- batched 5-segment f32->bf16 (hidden + 4 weights) ----------------
__global__ __launch_bounds__(256)
void conv_all(const float* __restrict__ s0, const float* __restrict__ s1,
              const float* __restrict__ s2, const float* __restrict__ s3,
              const float* __restrict__ s4,
              ushort_t* __restrict__ d0, ushort_t* __restrict__ d1,
              ushort_t* __restrict__ d2, ushort_t* __restrict__ d3,
              ushort_t* __restrict__ d4){
  constexpr long long C0 = 16777216, C1 = 23068672, C2 = 32505856, C3 = 34865152, C4 = 39059456;
  long long stride = (long long)gridDim.x * 256 * 4;
  for (long long e = ((long long)blockIdx.x*256 + threadIdx.x)*4; e < C4; e += stride){
    const float* sp; ushort_t* dp; long long o;
    if      (e < C0){ sp = s0; dp = d0; o = e; }
    else if (e < C1){ sp = s1; dp = d1; o = e - C0; }
    else if (e < C2){ sp = s2; dp = d2; o = e - C1; }
    else if (e < C3){ sp = s3; dp = d3; o = e - C2; }
    else            { sp = s4; dp = d4; o = e - C3; }
    float4 v = *(const float4*)(sp + o);
    unsigned long long pk = (unsigned long long)f2bf(v.x)
                          | ((unsigned long long)f2bf(v.y) << 16)
                          | ((unsigned long long)f2bf(v.z) << 32)
                          | ((unsigned long long)f2bf(v.w) << 48);
    *(unsigned long long*)(dp + o) = pk;
  }
}

// ======== GEMM 256x256 tile, BK=64, 8 waves, dbuf LDS, SINGLE-barrier K-loop ======
template<bool OUTBF>
__global__ __launch_bounds__(512, 2)
void gemm256(const ushort_t* __restrict__ A, const ushort_t* __restrict__ Bw,
             void* __restrict__ Cp, int M, int N, int K, int lda)
{
  __shared__ __attribute__((aligned(16))) ushort_t sm[65536];
  const int tid = threadIdx.x, lane = tid & 63, w = tid >> 6;
  const int wr = w >> 2, wc = w & 3;
  const int fr = lane & 15, kq = lane >> 4;

  const int nwg = gridDim.x, nx = N >> 8;
  const int bid = blockIdx.x;
  const int swz = (bid & 7) * (nwg >> 3) + (bid >> 3);
  const int m0 = (swz / nx) << 8, n0 = (swz % nx) << 8;

  f32x4 acc[8][4];
  #pragma unroll
  for (int m=0;m<8;m++)
    #pragma unroll
    for (int n=0;n<4;n++) acc[m][n] = (f32x4){0.f,0.f,0.f,0.f};

  const int srow = tid >> 3;
  const int gch  = (tid & 7) ^ (srow & 7);

  auto stage = [&](int c, int kt){
    const int k0 = kt << 6;
    ushort_t* Al = sm + c*16384;
    ushort_t* Bl = sm + 32768 + c*16384;
    const ushort_t* Ag = A  + (size_t)(m0 + srow)*lda + k0 + gch*8;
    const ushort_t* Bg = Bw + (size_t)(n0 + srow)*K   + k0 + gch*8;
    #pragma unroll
    for (int i=0;i<4;i++) gload16(Ag + (size_t)(i*64)*lda, Al + i*4096 + tid*8);
    #pragma unroll
    for (int i=0;i<4;i++) gload16(Bg + (size_t)(i*64)*K,   Bl + i*4096 + tid*8);
  };

  auto compute = [&](int c){
    const ushort_t* Al = sm + c*16384;
    const ushort_t* Bl = sm + 32768 + c*16384;
    const int s = fr & 7;
    short8 bfr[4][2];
    #pragma unroll
    for (int n=0;n<4;n++){
      const int row = wc*64 + n*16 + fr;
      bfr[n][0] = *(const short8*)(Bl + row*64 + ((kq    ) ^ s)*8);
      bfr[n][1] = *(const short8*)(Bl + row*64 + ((kq + 4) ^ s)*8);
    }
    #pragma unroll
    for (int m=0;m<8;m++){
      const int row = wr*128 + m*16 + fr;
      short8 a0 = *(const short8*)(Al + row*64 + ((kq    ) ^ s)*8);
      short8 a1 = *(const short8*)(Al + row*64 + ((kq + 4) ^ s)*8);
      #pragma unroll
      for (int n=0;n<4;n++){
        acc[m][n] = __builtin_amdgcn_mfma_f32_16x16x32_bf16(a0, bfr[n][0], acc[m][n], 0,0,0);
        acc[m][n] = __builtin_amdgcn_mfma_f32_16x16x32_bf16(a1, bfr[n][1], acc[m][n], 0,0,0);
      }
    }
  };

  const int nkt = K >> 6;
  stage(0, 0);
  stage(1, 1);
  asm volatile("s_waitcnt vmcnt(8)" ::: "memory");
  __builtin_amdgcn_s_barrier();
  __builtin_amdgcn_sched_barrier(0);

  int cur = 0;
  for (int kt = 0; kt < nkt; ++kt){
    compute(cur);
    asm volatile("s_waitcnt vmcnt(0)" ::: "memory"); // next tile's loads (1 tile old)
    __builtin_amdgcn_s_barrier();                    // collective: resident + read-done
    __builtin_amdgcn_sched_barrier(0);
    if (kt + 2 < nkt) stage(cur, kt + 2);            // overwrite fully-consumed buffer
    cur ^= 1;
  }

  const int rb = m0 + wr*128 + kq*4;
  const int cb = n0 + wc*64 + fr;
  #pragma unroll
  for (int m=0;m<8;m++)
    #pragma unroll
    for (int n=0;n<4;n++){
      const int col = cb + n*16;
      #pragma unroll
      for (int j=0;j<4;j++){
        const int row = rb + m*16 + j;
        float v = acc[m][n][j];
        if (OUTBF) ((ushort_t*)Cp)[(size_t)row*N + col] = f2bf(v);
        else       ((float*)  Cp)[(size_t)row*N + col] = v;
      }
    }
}

// ======== Fused q_a+ckv GEMM: C[4096,2176] = hidden @ [wqa;wkva]^T, single-barrier ===
__global__ __launch_bounds__(512, 2)
void gemm_qackv(const ushort_t* __restrict__ A, const ushort_t* __restrict__ Bw,
                ushort_t* __restrict__ qa, ushort_t* __restrict__ ckv)
{
  constexpr int N = QLRc + CKVS;   // 2176
  constexpr int K = HIDc, lda = HIDc;
  __shared__ __attribute__((aligned(16))) ushort_t sm[49152];
  const int tid = threadIdx.x, lane = tid & 63, w = tid >> 6;
  const int wr = w >> 1, wc = w & 1;
  const int fr = lane & 15, kq = lane >> 4;

  const int nwg = gridDim.x, nx = N >> 7;   // 17
  const int bid = blockIdx.x;
  const int swz = (bid & 7) * (nwg >> 3) + (bid >> 3);
  const int m0 = (swz / nx) << 8, n0 = (swz % nx) << 7;

  f32x4 acc[4][4];
  #pragma unroll
  for (int m=0;m<4;m++)
    #pragma unroll
    for (int n=0;n<4;n++) acc[m][n] = (f32x4){0.f,0.f,0.f,0.f};

  const int srow = tid >> 3;
  const int gch  = (tid & 7) ^ (srow & 7);

  auto stage = [&](int c, int kt){
    const int k0 = kt << 6;
    ushort_t* Al = sm + c*16384;
    ushort_t* Bl = sm + 32768 + c*8192;
    const ushort_t* Ag = A  + (size_t)(m0 + srow)*lda + k0 + gch*8;
    const ushort_t* Bg = Bw + (size_t)(n0 + srow)*K   + k0 + gch*8;
    #pragma unroll
    for (int i=0;i<4;i++) gload16(Ag + (size_t)(i*64)*lda, Al + i*4096 + tid*8);
    #pragma unroll
    for (int i=0;i<2;i++) gload16(Bg + (size_t)(i*64)*K,   Bl + i*4096 + tid*8);
  };

  auto compute = [&](int c){
    const ushort_t* Al = sm + c*16384;
    const ushort_t* Bl = sm + 32768 + c*8192;
    const int s = fr & 7;
    short8 bfr[4][2];
    #pragma unroll
    for (int n=0;n<4;n++){
      const int row = wc*64 + n*16 + fr;
      bfr[n][0] = *(const short8*)(Bl + row*64 + ((kq    ) ^ s)*8);
      bfr[n][1] = *(const short8*)(Bl + row*64 + ((kq + 4) ^ s)*8);
    }
    #pragma unroll
    for (int m=0;m<4;m++){
      const int row = wr*64 + m*16 + fr;
      short8 a0 = *(const short8*)(Al + row*64 + ((kq    ) ^ s)*8);
      short8 a1 = *(const short8*)(Al + row*64 + ((kq + 4) ^ s)*8);
      #pragma unroll
      for (int n=0;n<4;n++){
        acc[m][n] = __builtin_amdgcn_mfma_f32_16x16x32_bf16(a0, bfr[n][0], acc[m][n], 0,0,0);
        acc[m][n] = __builtin_amdgcn_mfma_f32_16x16x32_bf16(a1, bfr[n][1], acc[m][n], 0,0,0);
      }
    }
  };

  const int nkt = K >> 6;
  stage(0, 0);
  stage(1, 1);
  asm volatile("s_waitcnt vmcnt(6)" ::: "memory");
  __builtin_amdgcn_s_barrier();
  __builtin_amdgcn_sched_barrier(0);

  int cur = 0;
  for (int kt = 0; kt < nkt; ++kt){
    compute(cur);
    asm volatile("s_waitcnt vmcnt(0)" ::: "memory");
    __builtin_amdgcn_s_barrier();
    __builtin_amdgcn_sched_barrier(0);
    if (kt + 2 < nkt) stage(cur, kt + 2);
    cur ^= 1;
  }

  const int rb = m0 + wr*64 + kq*4;
  const int cb = n0 + wc*64 + fr;
  #pragma unroll
  for (int m=0;m<4;m++)
    #pragma unroll
    for (int n=0;n<4;n++){
      const int col = cb + n*16;
      #pragma unroll
      for (int j=0;j<4;j++){
        const int row = rb + m*16 + j;
        const ushort_t v = f2bf(acc[m][n][j]);
        if (col < QLRc) qa [(size_t)row*QLRc + col]          = v;
        else            ckv[(size_t)row*CKVS + (col - QLRc)] = v;
      }
    }
}

// ======== Fused q_b + kv_b launch, single-barrier K-loops ========
__global__ __launch_bounds__(512, 2)
void gemm_qbkvb(const ushort_t* __restrict__ qa,  const ushort_t* __restrict__ wqb,
                ushort_t* __restrict__ qbf,
                const ushort_t* __restrict__ ckv, const ushort_t* __restrict__ wkvb,
                ushort_t* __restrict__ kvbf)
{
  __shared__ __attribute__((aligned(16))) ushort_t sm[65536];
  const int tid = threadIdx.x, lane = tid & 63, w = tid >> 6;
  const int fr = lane & 15, kq = lane >> 4;
  const int s = fr & 7;

  if ((int)blockIdx.x < 768) {
    // ---- q_b: C[4096,6144] = qa @ wqb^T, K=1536, 256x128 tile ----
    constexpr int N = Hc*QHDc, K = QLRc, lda = QLRc;
    const int wr = w >> 1, wc = w & 1;
    const int nwg = 768, nx = N >> 7;      // 48
    const int bid = blockIdx.x;
    const int swz = (bid & 7) * (nwg >> 3) + (bid >> 3);
    const int m0 = (swz / nx) << 8, n0 = (swz % nx) << 7;

    f32x4 acc[4][4];
    #pragma unroll
    for (int m=0;m<4;m++)
      #pragma unroll
      for (int n=0;n<4;n++) acc[m][n] = (f32x4){0.f,0.f,0.f,0.f};

    const int srow = tid >> 3;
    const int gch  = (tid & 7) ^ (srow & 7);

    auto stage = [&](int c, int kt){
      const int k0 = kt << 6;
      ushort_t* Al = sm + c*16384;
      ushort_t* Bl = sm + 32768 + c*8192;
      const ushort_t* Ag = qa  + (size_t)(m0 + srow)*lda + k0 + gch*8;
      const ushort_t* Bg = wqb + (size_t)(n0 + srow)*K   + k0 + gch*8;
      #pragma unroll
      for (int i=0;i<4;i++) gload16(Ag + (size_t)(i*64)*lda, Al + i*4096 + tid*8);
      #pragma unroll
      for (int i=0;i<2;i++) gload16(Bg + (size_t)(i*64)*K,   Bl + i*4096 + tid*8);
    };
    auto compute = [&](int c){
      const ushort_t* Al = sm + c*16384;
      const ushort_t* Bl = sm + 32768 + c*8192;
      short8 bfr[4][2];
      #pragma unroll
      for (int n=0;n<4;n++){
        const int row = wc*64 + n*16 + fr;
        bfr[n][0] = *(const short8*)(Bl + row*64 + ((kq    ) ^ s)*8);
        bfr[n][1] = *(const short8*)(Bl + row*64 + ((kq + 4) ^ s)*8);
      }
      #pragma unroll
      for (int m=0;m<4;m++){
        const int row = wr*64 + m*16 + fr;
        short8 a0 = *(const short8*)(Al + row*64 + ((kq    ) ^ s)*8);
        short8 a1 = *(const short8*)(Al + row*64 + ((kq + 4) ^ s)*8);
        #pragma unroll
        for (int n=0;n<4;n++){
          acc[m][n] = __builtin_amdgcn_mfma_f32_16x16x32_bf16(a0, bfr[n][0], acc[m][n], 0,0,0);
          acc[m][n] = __builtin_amdgcn_mfma_f32_16x16x32_bf16(a1, bfr[n][1], acc[m][n], 0,0,0);
        }
      }
    };

    const int nkt = K >> 6;
    stage(0, 0);
    stage(1, 1);
    asm volatile("s_waitcnt vmcnt(6)" ::: "memory");
    __builtin_amdgcn_s_barrier();
    __builtin_amdgcn_sched_barrier(0);

    int cur = 0;
    for (int kt = 0; kt < nkt; ++kt){
      compute(cur);
      asm volatile("s_waitcnt vmcnt(0)" ::: "memory");
      __builtin_amdgcn_s_barrier();
      __builtin_amdgcn_sched_barrier(0);
      if (kt + 2 < nkt) stage(cur, kt + 2);
      cur ^= 1;
    }

    const int rb = m0 + wr*64 + kq*4;
    const int cb = n0 + wc*64 + fr;
    #pragma unroll
    for (int m=0;m<4;m++)
      #pragma unroll
      for (int n=0;n<4;n++){
        const int col = cb + n*16;
        #pragma unroll
        for (int j=0;j<4;j++){
          const int row = rb + m*16 + j;
          qbf[(size_t)row*N + col] = f2bf(acc[m][n][j]);
        }
      }
  } else {
    // ---- kv_b: C[4096,8192] = ckv @ wkvb^T, K=512, lda=640, 256x256 tile ----
    constexpr int N = Hc*256, K = KVLRc, lda = CKVS;
    const int wr = w >> 2, wc = w & 3;
    const int nwg = 512, nx = N >> 8;      // 32
    const int bid = (int)blockIdx.x - 768;
    const int swz = (bid & 7) * (nwg >> 3) + (bid >> 3);
    const int m0 = (swz / nx) << 8, n0 = (swz % nx) << 8;

    f32x4 acc[8][4];
    #pragma unroll
    for (int m=0;m<8;m++)
      #pragma unroll
      for (int n=0;n<4;n++) acc[m][n] = (f32x4){0.f,0.f,0.f,0.f};

    const int srow = tid >> 3;
    const int gch  = (tid & 7) ^ (srow & 7);

    auto stage = [&](int c, int kt){
      const int k0 = kt << 6;
      ushort_t* Al = sm + c*16384;
      ushort_t* Bl = sm + 32768 + c*16384;
      const ushort_t* Ag = ckv  + (size_t)(m0 + srow)*lda + k0 + gch*8;
      const ushort_t* Bg = wkvb + (size_t)(n0 + srow)*K   + k0 + gch*8;
      #pragma unroll
      for (int i=0;i<4;i++) gload16(Ag + (size_t)(i*64)*lda, Al + i*4096 + tid*8);
      #pragma unroll
      for (int i=0;i<4;i++) gload16(Bg + (size_t)(i*64)*K,   Bl + i*4096 + tid*8);
    };
    auto compute = [&](int c){
      const ushort_t* Al = sm + c*16384;
      const ushort_t* Bl = sm + 32768 + c*16384;
      short8 bfr[4][2];
      #pragma unroll
      for (int n=0;n<4;n++){
        const int row = wc*64 + n*16 + fr;
        bfr[n][0] = *(const short8*)(Bl + row*64 + ((kq    ) ^ s)*8);
        bfr[n][1] = *(const short8*)(Bl + row*64 + ((kq + 4) ^ s)*8);
      }
      #pragma unroll
      for (int m=0;m<8;m++){
        const int row = wr*128 + m*16 + fr;
        short8 a0 = *(const short8*)(Al + row*64 + ((kq    ) ^ s)*8);
        short8 a1 = *(const short8*)(Al + row*64 + ((kq + 4) ^ s)*8);
        #pragma unroll
        for (int n=0;n<4;n++){
          acc[m][n] = __builtin_amdgcn_mfma_f32_16x16x32_bf16(a0, bfr[n][0], acc[m][n], 0,0,0);
          acc[m][n] = __builtin_amdgcn_mfma_f32_16x16x32_bf16(a1, bfr[n][1], acc[m][n], 0,0,0);
        }
      }
    };

    const int nkt = K >> 6;
    stage(0, 0);
    stage(1, 1);
    asm volatile("s_waitcnt vmcnt(8)" ::: "memory");
    __builtin_amdgcn_s_barrier();
    __builtin_amdgcn_sched_barrier(0);

    int cur = 0;
    for (int kt = 0; kt < nkt; ++kt){
      compute(cur);
      asm volatile("s_waitcnt vmcnt(0)" ::: "memory");
      __builtin_amdgcn_s_barrier();
      __builtin_amdgcn_sched_barrier(0);
      if (kt + 2 < nkt) stage(cur, kt + 2);
      cur ^= 1;
    }

    const int rb = m0 + wr*128 + kq*4;
    const int cb = n0 + wc*64 + fr;
    #pragma unroll
    for (int m=0;m<8;m++)
      #pragma unroll
      for (int n=0;n<4;n++){
        const int col = cb + n*16;
        #pragma unroll
        for (int j=0;j<4;j++){
          const int row = rb + m*16 + j;
          kvbf[(size_t)row*N + col] = f2bf(acc[m][n][j]);
        }
      }
  }
}

// ---------------- merged RMSNorm (qa rows then ckv rows) ----------------
__global__ __launch_bounds__(256)
void rmsnorm2(ushort_t* __restrict__ xa, const float* __restrict__ wa,
              ushort_t* __restrict__ xb, const float* __restrict__ wb){
  const int row = blockIdx.x;
  ushort_t* p; const float* w; int D;
  if (row < Bc*Sc){ p = xa + (size_t)row*QLRc; w = wa; D = QLRc; }
  else            { p = xb + (size_t)(row - Bc*Sc)*CKVS; w = wb; D = KVLRc; }
  float ss = 0.f;
  for (int c = threadIdx.x*8; c < D; c += 2048) {
    short8 v = *(const short8*)(p + c);
    #pragma unroll
    for (int j=0;j<8;j++){ float f = bf2f((ushort_t)v[j]); ss += f*f; }
  }
  #pragma unroll
  for (int m=1;m<64;m<<=1) ss += __shfl_xor(ss, m, 64);
  __shared__ float red[4];
  if ((threadIdx.x & 63)==0) red[threadIdx.x>>6] = ss;
  __syncthreads();
  float tot = red[0]+red[1]+red[2]+red[3];
  float inv = rsqrtf(tot/(float)D + 1e-6f);
  for (int c = threadIdx.x*8; c < D; c += 2048) {
    short8 v = *(const short8*)(p + c);
    short8 o;
    #pragma unroll
    for (int j=0;j<8;j++) o[j] = (short)f2bf(bf2f((ushort_t)v[j]) * inv * w[c+j]);
    *(short8*)(p + c) = o;
  }
}

// ------- fused RoPE (inline sincos) + V transpose, one launch -------
__global__ __launch_bounds__(256)
void rope_vt(ushort_t* __restrict__ q, ushort_t* __restrict__ ckv,
             const ushort_t* __restrict__ kv, ushort_t* __restrict__ vt){
  constexpr int NQ = Bc*Sc*Hc*32;
  constexpr int NK = Bc*Sc*32;
  constexpr int RB = (NQ + NK + 255) / 256;   // rope blocks
  __shared__ __attribute__((aligned(16))) ushort_t L[64][136];

  if ((int)blockIdx.x < RB) {
    int i = blockIdx.x*256 + threadIdx.x;
    int p, t; ushort_t* base;
    if (i < NQ) {
      p = i & 31;
      int h = (i >> 5) & (Hc-1);
      int bs = i >> 10;
      t = bs & (Sc-1);
      base = q + (size_t)bs*Hc*QHDc + h*QHDc + NOPEc + 2*p;
    } else {
      int k = i - NQ;
      if (k >= NK) return;
      p = k & 31;
      int bs = k >> 5;
      t = bs & (Sc-1);
      base = ckv + (size_t)bs*CKVS + 512 + 2*p;
    }
    float invf = exp2f(-(float)p * (13.287712379549449f / 32.f)); // 10000^(-p/32)
    float ang = (float)t * invf;
    float s, c;
    sincosf(ang, &s, &c);
    unsigned u = *(const unsigned*)base;
    float a = bf2f((ushort_t)(u & 0xFFFFu)), bb = bf2f((ushort_t)(u >> 16));
    unsigned o = (unsigned)f2bf(a*c - bb*s) | ((unsigned)f2bf(bb*c + a*s) << 16);
    *(unsigned*)base = o;
    return;
  }

  const int vb = (int)blockIdx.x - RB;
  const int s0 = (vb & 31) * 64;
  const int bh = vb >> 5;
  const int batch = bh >> 5, h = bh & 31;
  #pragma unroll
  for (int i = 0; i < 4; i++) {
    int chunk = i*256 + threadIdx.x;
    int r = chunk >> 4;
    int c = (chunk & 15) * 8;
    short8 v = *(const short8*)(kv + ((size_t)(batch*Sc + s0 + r)*Hc + h)*256 + 128 + c);
    *(short8*)&L[r][c] = v;
  }
  __syncthreads();
  #pragma unroll
  for (int i = 0; i < 4; i++) {
    int chunk = i*256 + threadIdx.x;
    int vd = chunk >> 3;
    int sc2 = (chunk & 7) * 8;
    short8 o;
    #pragma unroll
    for (int j=0;j<8;j++) o[j] = (short)L[sc2+j][vd];
    *(short8*)(vt + ((size_t)bh*VDc + vd)*Sc + s0 + sc2) = o;
  }
}

// ---------------- Flash attention (causal), 4 waves, light barriers ----------------
// Structure identical to the proven 211us kernel; the two __syncthreads per KV-tile
// are replaced with {lgkmcnt(0); s_barrier} so the T14 prefetch global loads stay
// in flight across the PV-side barrier (no collective vmcnt(0) drain per iter).
__global__ __launch_bounds__(256)
void attn_fwd(const ushort_t* __restrict__ qb, const ushort_t* __restrict__ kvb,
              const ushort_t* __restrict__ ckv, const ushort_t* __restrict__ vt,
              ushort_t* __restrict__ out)
{
  constexpr int KP = 200, VP = 40;
  __shared__ __attribute__((aligned(16))) ushort_t Ks[32*KP];
  __shared__ __attribute__((aligned(16))) ushort_t Vs[128*VP];
  __shared__ __attribute__((aligned(16))) ushort_t Ps[4][16*VP];
  const int tid = threadIdx.x, lane = tid & 63, w = tid >> 6;
  const int fr = lane & 15, kq = lane >> 4;
  const int y = (int)blockIdx.y;
  const int bh = blockIdx.x, batch = bh >> 5, h = bh & 31;

  const float scl = 0.07216878364870323f * 1.4426950408889634f;
  const float THR = 8.0f;

  const int ksr = tid >> 3, ksub = tid & 7;
  const int vvd = tid >> 1, vsub = tid & 1;

  const ushort_t* kbase  = kvb + ((size_t)batch*Sc + ksr)*((size_t)Hc*256) + (size_t)h*256;
  const ushort_t* pebase = ckv + (size_t)(batch*Sc + ksr)*CKVS + 512;
  const ushort_t* vbase  = vt + ((size_t)bh*VDc + vvd)*Sc;

  for (int seg = 0; seg < 2; ++seg) {
    const int qt = seg == 0 ? (31 - y) : y;
    const int q0 = qt * 64;

    const int qrow = q0 + w*16 + fr;
    const ushort_t* qptr = qb + ((size_t)(batch*Sc + qrow)*Hc + h)*QHDc;
    short8 qf[6];
    #pragma unroll
    for (int kk=0;kk<6;kk++) qf[kk] = *(const short8*)(qptr + kk*32 + kq*8);

    f32x4 acc_o[8];
    #pragma unroll
    for (int i=0;i<8;i++) acc_o[i] = (f32x4){0.f,0.f,0.f,0.f};
    float mrow[4]  = {-3e38f,-3e38f,-3e38f,-3e38f};
    float lpart[4] = {0.f,0.f,0.f,0.f};

    const int ktiles = q0/32 + 2;

    short8 kreg[3], vreg[2];
    {
      #pragma unroll
      for (int i=0;i<3;i++){
        int c = (ksub*3 + i)*8;
        kreg[i] = (c < 128) ? *(const short8*)(kbase + c)
                            : *(const short8*)(pebase + (c - 128));
      }
      #pragma unroll
      for (int i=0;i<2;i++) vreg[i] = *(const short8*)(vbase + (vsub*2+i)*8);
    }

    for (int kt = 0; kt < ktiles; kt++) {
      const int j0 = kt*32;
      // publish staged tile (compiler waits the in-flight global loads here, per-wave)
      #pragma unroll
      for (int i=0;i<3;i++) *(short8*)&Ks[ksr*KP + (ksub*3 + i)*8] = kreg[i];
      #pragma unroll
      for (int i=0;i<2;i++) *(short8*)&Vs[vvd*VP + (vsub*2 + i)*8] = vreg[i];
      barrier_lds();                         // ds_writes committed; no vmem drain

      if (kt + 1 < ktiles) {
        const size_t roff = (size_t)(j0 + 32);
        #pragma unroll
        for (int i=0;i<3;i++){
          int c = (ksub*3 + i)*8;
          kreg[i] = (c < 128) ? *(const short8*)(kbase + roff*((size_t)Hc*256) + c)
                              : *(const short8*)(pebase + roff*CKVS + (c - 128));
        }
        #pragma unroll
        for (int i=0;i<2;i++) vreg[i] = *(const short8*)(vbase + roff + (vsub*2+i)*8);
      }

      f32x4 s0 = (f32x4){0.f,0.f,0.f,0.f}, s1 = (f32x4){0.f,0.f,0.f,0.f};
      __builtin_amdgcn_s_setprio(1);
      #pragma unroll
      for (int kk=0;kk<6;kk++){
        short8 b0 = *(const short8*)&Ks[fr*KP + kk*32 + kq*8];
        short8 b1 = *(const short8*)&Ks[(16+fr)*KP + kk*32 + kq*8];
        s0 = __builtin_amdgcn_mfma_f32_16x16x32_bf16(qf[kk], b0, s0, 0,0,0);
        s1 = __builtin_amdgcn_mfma_f32_16x16x32_bf16(qf[kk], b1, s1, 0,0,0);
      }
      __builtin_amdgcn_s_setprio(0);

      const bool full = (j0 + 31 <= q0 + w*16);
      float x0[4], x1[4];
      int okl = 1;
      #pragma unroll
      for (int j=0;j<4;j++){
        float a  = s0[j]*scl, c2 = s1[j]*scl;
        if (!full) {
          int qp = q0 + w*16 + kq*4 + j;
          if (j0 + fr      > qp) a  = -3e38f;
          if (j0 + 16 + fr > qp) c2 = -3e38f;
        }
        x0[j] = a; x1[j] = c2;
        okl &= (fmaxf(a, c2) <= mrow[j] + THR) ? 1 : 0;
      }
      if (!__all(okl)) {
        float tmax[4];
        #pragma unroll
        for (int j=0;j<4;j++) tmax[j] = fmaxf(x0[j], x1[j]);
        #pragma unroll
        for (int m=1;m<16;m<<=1){
          #pragma unroll
          for (int j=0;j<4;j++) tmax[j] = fmaxf(tmax[j], __shfl_xor(tmax[j], m, 64));
        }
        #pragma unroll
        for (int j=0;j<4;j++){
          float mn = fmaxf(mrow[j], tmax[j]);
          float corr = exp2f(mrow[j] - mn);
          mrow[j] = mn;
          lpart[j] *= corr;
          #pragma unroll
          for (int i=0;i<8;i++) acc_o[i][j] *= corr;
        }
      }
      float p0[4], p1[4];
      #pragma unroll
      for (int j=0;j<4;j++){
        p0[j] = exp2f(x0[j] - mrow[j]);
        p1[j] = exp2f(x1[j] - mrow[j]);
        lpart[j] += p0[j] + p1[j];
      }
      #pragma unroll
      for (int j=0;j<4;j++){
        unsigned pk;
        asm("v_cvt_pk_bf16_f32 %0, %1, %2" : "=v"(pk) : "v"(p0[j]), "v"(p1[j]));
        Ps[w][(kq*4+j)*VP + fr]      = (ushort_t)(pk & 0xFFFFu);
        Ps[w][(kq*4+j)*VP + 16 + fr] = (ushort_t)(pk >> 16);
      }
      short8 ap = *(const short8*)&Ps[w][fr*VP + kq*8];
      __builtin_amdgcn_s_setprio(1);
      #pragma unroll
      for (int v8=0; v8<8; v8++){
        short8 bv = *(const short8*)&Vs[(v8*16 + fr)*VP + kq*8];
        acc_o[v8] = __builtin_amdgcn_mfma_f32_16x16x32_bf16(ap, bv, acc_o[v8], 0,0,0);
      }
      __builtin_amdgcn_s_setprio(0);
      barrier_lds();                         // reads done; prefetch stays in flight
    }

    #pragma unroll
    for (int m=1;m<16;m<<=1){
      #pragma unroll
      for (int j=0;j<4;j++) lpart[j] += __shfl_xor(lpart[j], m, 64);
    }
    #pragma unroll
    for (int v8=0; v8<8; v8++){
      #pragma unroll
      for (int j=0;j<4;j++){
        int qg = q0 + w*16 + kq*4 + j;
        float o = acc_o[v8][j] / lpart[j];
        out[(size_t)(batch*Sc + qg)*(Hc*VDc) + h*VDc + v8*16 + fr] = f2bf(o);
      }
    }
  }
}

// ---------------- launcher ----------------
extern "C" void kernel_launch(void* const* d_in, const int* in_sizes, int n_in,
                              void* d_out, int out_size, void* d_ws, size_t ws_size,
                              hipStream_t stream) {
  (void)in_sizes; (void)n_in; (void)out_size; (void)ws_size;
  const float* hidden  = (const float*)d_in[0];
  const float* q_a_w   = (const float*)d_in[3];
  const float* q_a_ln  = (const float*)d_in[4];
  const float* q_b_w   = (const float*)d_in[5];
  const float* kv_a_w  = (const float*)d_in[6];
  const float* kv_a_ln = (const float*)d_in[7];
  const float* kv_b_w  = (const float*)d_in[8];
  const float* o_w     = (const float*)d_in[9];
  float* outp = (float*)d_out;

  char* ws = (char*)d_ws;
  size_t off = 0;
  auto alloc = [&](size_t n)->char*{ char* p = ws + off; off += (n + 255) & ~(size_t)255; return p; };
  ushort_t* hbf  = (ushort_t*)alloc((size_t)Bc*Sc*HIDc*2);      // hidden bf16; later o_w bf16
  // NOTE: wqa and wkva MUST be contiguous (fused q_a+ckv GEMM reads [wqa;wkva] as one B).
  ushort_t* wqa  = (ushort_t*)alloc((size_t)QLRc*HIDc*2);
  ushort_t* wkva = (ushort_t*)alloc((size_t)640*HIDc*2);        // directly follows wqa
  ushort_t* wqb  = (ushort_t*)alloc((size_t)Hc*QHDc*QLRc*2);
  ushort_t* wkvb = (ushort_t*)alloc((size_t)Hc*256*KVLRc*2);
  ushort_t* qa   = (ushort_t*)alloc((size_t)Bc*Sc*QLRc*2);
  ushort_t* qbf  = (ushort_t*)alloc((size_t)Bc*Sc*Hc*QHDc*2);
  ushort_t* ckv  = (ushort_t*)alloc((size_t)Bc*Sc*CKVS*2);      // stride 640
  ushort_t* kvbf = (ushort_t*)alloc((size_t)Bc*Sc*Hc*256*2);
  ushort_t* vtb  = (ushort_t*)alloc((size_t)Bc*Hc*VDc*Sc*2);    // V transposed [bh][vd][s]
  ushort_t* aout = wqa;   // alias: wqa+wkva+wqb free before attn

  const int M = Bc*Sc; // 4096

  // one batched convert: hidden + q_a_w + q_b_w + kv_a_w + kv_b_w
  conv_all<<<2048,256,0,stream>>>(hidden, q_a_w, q_b_w, kv_a_w, kv_b_w,
                                  hbf, wqa, wqb, wkva, wkvb);
  // fused q_a + ckv GEMM: [4096, 2176, 4096]
  gemm_qackv<<<(M/256)*((QLRc+CKVS)/128),512,0,stream>>>(hbf, wqa, qa, ckv);
  // merged RMSNorm (qa + ckv)
  rmsnorm2<<<2*M,256,0,stream>>>(qa, q_a_ln, ckv, kv_a_ln);
  // hbf free now -> convert o_w into it
  f32_to_bf16<<<2048,256,0,stream>>>(o_w, hbf, (long long)HIDc*HIDc);
  // fused q_b + kv_b launch: 768 + 512 = 1280 blocks
  gemm_qbkvb<<<1280,512,0,stream>>>(qa, wqb, qbf, ckv, wkvb, kvbf);
  // fused RoPE (inline sincos) + V transpose: one launch
  {
    constexpr int NQ = Bc*Sc*Hc*32, NK = Bc*Sc*32;
    constexpr int RB = (NQ + NK + 255) / 256;
    rope_vt<<<RB + (Sc/64)*(Bc*Hc),256,0,stream>>>(qbf, ckv, kvbf, vtb);
  }
  // attention (1024 uniform blocks, diagonal-paired, light barriers)
  attn_fwd<<<dim3(Bc*Hc, 16),256,0,stream>>>(qbf, kvbf, ckv, vtb, aout);
  // out = attn @ o_w^T  [4096,4096,4096], f32 store — 256^2 tiles
  gemm256<false><<<(M/256)*(HIDc/256),512,0,stream>>>(aout, hbf, outp, M, HIDc, HIDc, HIDc);
}